// Round 10
// baseline (1453.439 us; speedup 1.0000x reference)
//
#include <hip/hip_runtime.h>
#include <hip/hip_bf16.h>

typedef __attribute__((ext_vector_type(4))) float f32x4;
typedef __attribute__((ext_vector_type(8))) short short8;

#define DEVFN __device__ __forceinline__

static constexpr int Bn = 16, Tn = 512, Sn = 512, Vn = 10000, En = 512, Hn = 1024, Ln = 6;
static constexpr int Mn = Bn * Tn;  // 8192 token rows
static constexpr float kScale = 0.70710678118654752440f;

DEVFN float bf2f(__hip_bfloat16 x) { return __bfloat162float(x); }
DEVFN __hip_bfloat16 f2bf(float x) { return __float2bfloat16(x); }

struct bf16x4 { __hip_bfloat16 x, y, z, w; };

// async global -> LDS, 16B per lane (wave-uniform LDS base + lane*16 layout)
DEVFN void gload_lds16(const short* g, short* l) {
    __builtin_amdgcn_global_load_lds((const __attribute__((address_space(1))) void*)g,
                                     (__attribute__((address_space(3))) void*)l, 16, 0, 0);
}

// ---------------- small prep kernels ----------------

__global__ void padfill_kernel(__hip_bfloat16* p) {
    p[threadIdx.x] = f2bf(1.0f);  // PAD_VAL as float, per torch code
}

// embedded[b,t,:] = tok_emb[tgt[b,t],:] + pos_emb[t,:]  (bf16)
// embA = kScale*(embedded + b_ah2e)                      (bf16, for embE precompute)
__global__ void embed_kernel(const int* __restrict__ tgt, const float* __restrict__ tok,
                             const float* __restrict__ pos, const float* __restrict__ bah,
                             __hip_bfloat16* __restrict__ out, __hip_bfloat16* __restrict__ outA) {
    int row = blockIdx.x;              // 0..8191
    int t = row & (Tn - 1);
    int v = tgt[row];
    const float* tr = tok + (long)v * En;
    const float* pr = pos + (long)t * En;
    int e = threadIdx.x * 4;           // block 128 covers 512
    float4 a = *(const float4*)(tr + e);
    float4 b = *(const float4*)(pr + e);
    float4 bb = *(const float4*)(bah + e);
    bf16x4 o{f2bf(a.x + b.x), f2bf(a.y + b.y), f2bf(a.z + b.z), f2bf(a.w + b.w)};
    *(bf16x4*)(out + (long)row * En + e) = o;
    bf16x4 oa{f2bf(kScale * (a.x + b.x + bb.x)), f2bf(kScale * (a.y + b.y + bb.y)),
              f2bf(kScale * (a.z + b.z + bb.z)), f2bf(kScale * (a.w + b.w + bb.w))};
    *(bf16x4*)(outA + (long)row * En + e) = oa;
}

// dst[c][r] = bf16(src[r][c]); src is [R][C] f32. grid(ceil(C/32), ceil(R/32), Z), block(32,8)
__global__ void transpose_f32_bf16(const float* __restrict__ src, __hip_bfloat16* __restrict__ dst,
                                   int R, int C, long sZi, long sZo) {
    __shared__ float tile[32][33];
    src += (long)blockIdx.z * sZi;
    dst += (long)blockIdx.z * sZo;
    int c0 = blockIdx.x * 32, r0 = blockIdx.y * 32;
    for (int i = threadIdx.y; i < 32; i += 8) {
        int r = r0 + i, c = c0 + threadIdx.x;
        tile[i][threadIdx.x] = (r < R && c < C) ? src[(long)r * C + c] : 0.f;
    }
    __syncthreads();
    for (int i = threadIdx.y; i < 32; i += 8) {
        int c = c0 + i, r = r0 + threadIdx.x;
        if (c < C && r < R) dst[(long)c * R + r] = f2bf(tile[threadIdx.x][i]);
    }
}

// f32 -> bf16 convert (n divisible by 4)
__global__ void convert_bf16_kernel(const float* __restrict__ src, __hip_bfloat16* __restrict__ dst,
                                    long n4) {
    long i = (long)blockIdx.x * blockDim.x + threadIdx.x;
    if (i >= n4) return;
    long j = i * 4;
    float4 v = *(const float4*)(src + j);
    bf16x4 o{f2bf(v.x), f2bf(v.y), f2bf(v.z), f2bf(v.w)};
    *(bf16x4*)(dst + j) = o;
}

// Coalesced conv-weight pack for layer l, a/g interleaved in 16-col blocks for fused GLU.
// One block per packed output row c (grid 2048): coalesced float4 read of the 3072-f32
// source row into LDS, stride-3 gather (3 coprime 32 -> no systematic bank conflict),
// coalesced bf16x4 writes.  wp[c][tap*H+i] = bf16(conv_w[l][o(c)][i][tap]).
__global__ __launch_bounds__(256) void wpack2_kernel(const float* __restrict__ convw,
                                                     __hip_bfloat16* __restrict__ wp, int l) {
    __shared__ float row[3 * Hn];
    int c = blockIdx.x;                        // 0..2047 packed col
    int grp = c >> 5, w = c & 31;
    int o = (w < 16) ? grp * 16 + w : Hn + grp * 16 + (w - 16);
    const float* src = convw + ((long)(l * 2 * Hn + o)) * (Hn * 3);
#pragma unroll
    for (int j = 0; j < 3; ++j) {
        int idx = (j * 256 + threadIdx.x) * 4;
        *(float4*)&row[idx] = *(const float4*)(src + idx);
    }
    __syncthreads();
    __hip_bfloat16* dst = wp + (long)c * (3 * Hn);
#pragma unroll
    for (int j = 0; j < 3; ++j) {
        int kk = (j * 256 + threadIdx.x) * 4;   // 4-chunk never crosses a tap boundary (1024%4==0)
        int tap = kk >> 10;
        int i = kk & (Hn - 1);
        bf16x4 v{f2bf(row[i * 3 + tap]), f2bf(row[(i + 1) * 3 + tap]),
                 f2bf(row[(i + 2) * 3 + tap]), f2bf(row[(i + 3) * 3 + tap])};
        *(bf16x4*)(dst + kk) = v;
    }
}

// row softmax over S=512; writes bf16 (next GEMM input) + optional f32 (final attention)
__global__ __launch_bounds__(256) void softmax_kernel(const float* __restrict__ energy,
                                                      float* __restrict__ attn_f32,
                                                      __hip_bfloat16* __restrict__ attn_bf) {
    int row = blockIdx.x;  // 0..8191
    const float* e = energy + (long)row * Sn;
    int tid = threadIdx.x;
    float v0 = e[tid], v1 = e[tid + 256];
    float m = fmaxf(v0, v1);
    for (int off = 32; off; off >>= 1) m = fmaxf(m, __shfl_xor(m, off));
    __shared__ float redm[4];
    __shared__ float reds[4];
    int lane = tid & 63, w = tid >> 6;
    if (lane == 0) redm[w] = m;
    __syncthreads();
    m = fmaxf(fmaxf(redm[0], redm[1]), fmaxf(redm[2], redm[3]));
    float x0 = __expf(v0 - m), x1 = __expf(v1 - m);
    float s = x0 + x1;
    for (int off = 32; off; off >>= 1) s += __shfl_xor(s, off);
    if (lane == 0) reds[w] = s;
    __syncthreads();
    s = reds[0] + reds[1] + reds[2] + reds[3];
    float inv = 1.f / s;
    long base = (long)row * Sn;
    if (attn_f32) {
        attn_f32[base + tid] = x0 * inv;
        attn_f32[base + tid + 256] = x1 * inv;
    }
    attn_bf[base + tid] = f2bf(x0 * inv);
    attn_bf[base + tid + 256] = f2bf(x1 * inv);
}

// ---------------- 128x128 2-phase GEMM ----------------
// C[M,N] = A[M,K] @ Bw[N,K]^T.  EPI: 0: x=acc+bias; 2: x=((acc+bias+R1)*s1+R2)*s2;
// 3: x=acc*s1 + R1f[idx].  R1/R2/R1f batch-offset by z*cZ.
template <int EPI, bool OUTF32, bool NBOUND>
__global__ __launch_bounds__(256) void gemm_bf16(
    const __hip_bfloat16* __restrict__ A, const __hip_bfloat16* __restrict__ Bw,
    const float* __restrict__ bias, void* __restrict__ Cout,
    const __hip_bfloat16* __restrict__ R1, const __hip_bfloat16* __restrict__ R2,
    const float* __restrict__ R1f, const __hip_bfloat16* __restrict__ padrow,
    int M, int N, int K, long aZ, long bZ, long cZ, float s1, float s2) {
    __shared__ alignas(16) short As[2][128 * 32];
    __shared__ alignas(16) short Bs[2][128 * 32];
    const int tid = threadIdx.x;
    const int lane = tid & 63;
    const int wid = tid >> 6;
    const int wr = wid >> 1, wc = wid & 1;
    const int m0 = blockIdx.y * 128, n0 = blockIdx.x * 128;
    const short* Ag = (const short*)A + (long)blockIdx.z * aZ;
    const short* Bg = (const short*)Bw + (long)blockIdx.z * bZ;
    const short* pad = (const short*)padrow;

    f32x4 acc[4][4] = {};

    const int rc = tid >> 2;
    const int k8 = (tid & 3) * 8;

    auto stage = [&](int buf, int k0) {
#pragma unroll
        for (int j = 0; j < 2; ++j) {
            int r = rc + j * 64;
            const short* asrc = Ag + (long)(m0 + r) * K + k0 + k8;
            gload_lds16(asrc, &As[buf][r * 32 + k8]);
            int n = n0 + r;
            const short* bsrc = (NBOUND && n >= N) ? (pad + k8) : (Bg + (long)n * K + k0 + k8);
            gload_lds16(bsrc, &Bs[buf][r * 32 + k8]);
        }
    };

    stage(0, 0);
    __syncthreads();

    int cur = 0;
    for (int k0 = 0; k0 < K; k0 += 32) {
        if (k0 + 32 < K) stage(cur ^ 1, k0 + 32);
        const int rsel = lane & 15, hi = (lane >> 4) * 8;
        short8 af[4], bg[4];
#pragma unroll
        for (int mi = 0; mi < 4; ++mi)
            af[mi] = *(const short8*)&As[cur][(wr * 64 + mi * 16 + rsel) * 32 + hi];
#pragma unroll
        for (int ni = 0; ni < 4; ++ni)
            bg[ni] = *(const short8*)&Bs[cur][(wc * 64 + ni * 16 + rsel) * 32 + hi];
#pragma unroll
        for (int mi = 0; mi < 4; ++mi)
#pragma unroll
            for (int ni = 0; ni < 4; ++ni)
                acc[mi][ni] = __builtin_amdgcn_mfma_f32_16x16x32_bf16(af[mi], bg[ni], acc[mi][ni], 0, 0, 0);
        __syncthreads();
        cur ^= 1;
    }

    const int rsel = lane & 15, rg = (lane >> 4) * 4;
    float* Cf = (float*)Cout + (long)blockIdx.z * cZ;
    __hip_bfloat16* Cb = (__hip_bfloat16*)Cout + (long)blockIdx.z * cZ;
    const __hip_bfloat16* R1z = R1 + (long)blockIdx.z * cZ;
    const __hip_bfloat16* R2z = R2 + (long)blockIdx.z * cZ;
    const float* R1fz = R1f + (long)blockIdx.z * cZ;
#pragma unroll
    for (int ni = 0; ni < 4; ++ni) {
        int col = n0 + wc * 64 + ni * 16 + rsel;
        if (NBOUND && col >= N) continue;
        float bi = (EPI != 3 && bias) ? bias[col] : 0.f;
#pragma unroll
        for (int mi = 0; mi < 4; ++mi) {
            int row = m0 + wr * 64 + mi * 16 + rg;
            f32x4 v = acc[mi][ni];
#pragma unroll
            for (int q = 0; q < 4; ++q) {
                long idx = (long)(row + q) * N + col;
                float x;
                if (EPI == 3) x = v[q] * s1 + R1fz[idx];
                else {
                    x = v[q] + bi;
                    if (EPI >= 1) x = (x + bf2f(R1z[idx])) * s1;
                    if (EPI >= 2) x = (x + bf2f(R2z[idx])) * s2;
                }
                if (OUTF32) Cf[idx] = x;
                else Cb[idx] = f2bf(x);
            }
        }
    }
}

// ---------------- 256x256 4-phase deep-pipeline GEMM (conv + fc_out) ----------------
// T1 XCD-swizzle + T2 LDS-swizzle (both-sides involution) + T3/T4 fine-phase counted
// vmcnt + T5 setprio. 8 waves (2Mx4N), BK=64. Per K-tile: 4 quadrant phases, each
// {stage 1 half-tile (2 DMA) ; [phase0: vmcnt(2)+barrier] ; ds_read quadrant frags ;
//  setprio(1) 16 MFMA setprio(0) ; barrier}. Staging of tile t+1 spread A0,A1,B0,B1
// across t's phases; vmcnt(2) at phase0 drains exactly tile t's 8 older loads.
// GLUE: fused GLU epilogue (a/g interleaved 16-col blocks via wpack).
template <bool OUTF32, bool GLUE, bool IM2COL, bool NBOUND>
__global__ __launch_bounds__(512, 2) void gemm256(
    const __hip_bfloat16* __restrict__ A, const __hip_bfloat16* __restrict__ Bw,
    const float* __restrict__ bias, void* __restrict__ Cout,
    const __hip_bfloat16* __restrict__ padrow, int M, int N, int K) {
    __shared__ alignas(16) short As[2][256 * 64];
    __shared__ alignas(16) short Bs[2][256 * 64];
    const int tid = threadIdx.x;
    const int lane = tid & 63;
    const int wid = tid >> 6;
    const int wr = wid >> 2, wc = wid & 3;
    const int nwg = gridDim.x * gridDim.y;
    const int orig = blockIdx.y * gridDim.x + blockIdx.x;
    const int qd = nwg >> 3, rd = nwg & 7, xc = orig & 7, loc = orig >> 3;
    const int bid = (xc < rd ? xc * (qd + 1) : rd * (qd + 1) + (xc - rd) * qd) + loc;
    const int n0 = (bid % gridDim.x) * 256, m0 = (bid / gridDim.x) * 256;
    const short* Ag = (const short*)A;
    const short* Bg = (const short*)Bw;
    const short* pad = (const short*)padrow;

    f32x4 acc[8][4] = {};

    const int srow_l = tid >> 3;
    const int scol = ((tid & 7) ^ (srow_l & 7)) * 8;
    const int sdst = (tid >> 3) * 64 + (tid & 7) * 8;

    // half: rows [half*128, half*128+128) = j in {2*half, 2*half+1}
    auto stageA = [&](int buf, int kt, int half) {
        const int k0 = kt * 64;
#pragma unroll
        for (int j = half * 2; j < half * 2 + 2; ++j) {
            const int row = j * 64 + srow_l;
            const short* asrc;
            if (IM2COL) {
                int m = m0 + row;
                int t = m & (Tn - 1);
                int tap = k0 >> 10;
                int tau = t - 2 + tap;
                int kcol = (k0 & (Hn - 1)) + scol;
                asrc = (tau >= 0) ? (Ag + (long)(m - 2 + tap) * Hn + kcol) : (pad + scol);
            } else {
                asrc = Ag + (long)(m0 + row) * K + k0 + scol;
            }
            gload_lds16(asrc, &As[buf][j * 4096 + sdst]);
        }
    };
    auto stageB = [&](int buf, int kt, int half) {
        const int k0 = kt * 64;
#pragma unroll
        for (int j = half * 2; j < half * 2 + 2; ++j) {
            const int row = j * 64 + srow_l;
            int n = n0 + row;
            const short* bsrc = (NBOUND && n >= N) ? (pad + scol) : (Bg + (long)n * K + k0 + scol);
            gload_lds16(bsrc, &Bs[buf][j * 4096 + sdst]);
        }
    };

    const int rsel = lane & 15, hi = (lane >> 4) * 8;
    const int xorc = (rsel & 7) << 3;

    // prologue: all 4 half-tiles of tile 0 (8 loads/thread), order A0,A1,B0,B1
    stageA(0, 0, 0); stageA(0, 0, 1); stageB(0, 0, 0); stageB(0, 0, 1);

    const int NT = K >> 6;
    for (int t = 0; t < NT; ++t) {
        const int cur = t & 1;
        const int nxt = cur ^ 1;
        const bool pf = (t + 1 < NT);
        short8 af[4][2], bg0[2][2], bg1[2][2];

        // ---- phase 0: quadrant (mh0, nh0) ----
        if (pf) {
            stageA(nxt, t + 1, 0);
            asm volatile("s_waitcnt vmcnt(2)" ::: "memory");   // drain tile t's 8 older loads
        } else {
            asm volatile("s_waitcnt vmcnt(0)" ::: "memory");
        }
        __builtin_amdgcn_s_barrier();                           // tile t visible to all waves
        __builtin_amdgcn_sched_barrier(0);
#pragma unroll
        for (int i = 0; i < 4; ++i) {
            const int row = wr * 128 + 0 * 64 + i * 16 + rsel;
#pragma unroll
            for (int ks = 0; ks < 2; ++ks)
                af[i][ks] = *(const short8*)&As[cur][row * 64 + ((ks * 32 + hi) ^ xorc)];
        }
#pragma unroll
        for (int i = 0; i < 2; ++i) {
            const int row = wc * 64 + 0 * 32 + i * 16 + rsel;
#pragma unroll
            for (int ks = 0; ks < 2; ++ks)
                bg0[i][ks] = *(const short8*)&Bs[cur][row * 64 + ((ks * 32 + hi) ^ xorc)];
        }
        __builtin_amdgcn_s_setprio(1);
#pragma unroll
        for (int i = 0; i < 4; ++i)
#pragma unroll
            for (int jn = 0; jn < 2; ++jn)
#pragma unroll
                for (int ks = 0; ks < 2; ++ks)
                    acc[i][jn] = __builtin_amdgcn_mfma_f32_16x16x32_bf16(af[i][ks], bg0[jn][ks], acc[i][jn], 0, 0, 0);
        __builtin_amdgcn_s_setprio(0);
        __builtin_amdgcn_s_barrier();
        __builtin_amdgcn_sched_barrier(0);

        // ---- phase 1: quadrant (mh0, nh1) ----
        if (pf) stageA(nxt, t + 1, 1);
#pragma unroll
        for (int i = 0; i < 2; ++i) {
            const int row = wc * 64 + 1 * 32 + i * 16 + rsel;
#pragma unroll
            for (int ks = 0; ks < 2; ++ks)
                bg1[i][ks] = *(const short8*)&Bs[cur][row * 64 + ((ks * 32 + hi) ^ xorc)];
        }
        __builtin_amdgcn_s_setprio(1);
#pragma unroll
        for (int i = 0; i < 4; ++i)
#pragma unroll
            for (int jn = 0; jn < 2; ++jn)
#pragma unroll
                for (int ks = 0; ks < 2; ++ks)
                    acc[i][2 + jn] = __builtin_amdgcn_mfma_f32_16x16x32_bf16(af[i][ks], bg1[jn][ks], acc[i][2 + jn], 0, 0, 0);
        __builtin_amdgcn_s_setprio(0);
        __builtin_amdgcn_s_barrier();
        __builtin_amdgcn_sched_barrier(0);

        // ---- phase 2: quadrant (mh1, nh0) ----
        if (pf) stageB(nxt, t + 1, 0);
#pragma unroll
        for (int i = 0; i < 4; ++i) {
            const int row = wr * 128 + 1 * 64 + i * 16 + rsel;
#pragma unroll
            for (int ks = 0; ks < 2; ++ks)
                af[i][ks] = *(const short8*)&As[cur][row * 64 + ((ks * 32 + hi) ^ xorc)];
        }
        __builtin_amdgcn_s_setprio(1);
#pragma unroll
        for (int i = 0; i < 4; ++i)
#pragma unroll
            for (int jn = 0; jn < 2; ++jn)
#pragma unroll
                for (int ks = 0; ks < 2; ++ks)
                    acc[4 + i][jn] = __builtin_amdgcn_mfma_f32_16x16x32_bf16(af[i][ks], bg0[jn][ks], acc[4 + i][jn], 0, 0, 0);
        __builtin_amdgcn_s_setprio(0);
        __builtin_amdgcn_s_barrier();
        __builtin_amdgcn_sched_barrier(0);

        // ---- phase 3: quadrant (mh1, nh1) ----
        if (pf) stageB(nxt, t + 1, 1);
        __builtin_amdgcn_s_setprio(1);
#pragma unroll
        for (int i = 0; i < 4; ++i)
#pragma unroll
            for (int jn = 0; jn < 2; ++jn)
#pragma unroll
                for (int ks = 0; ks < 2; ++ks)
                    acc[4 + i][2 + jn] = __builtin_amdgcn_mfma_f32_16x16x32_bf16(af[i][ks], bg1[jn][ks], acc[4 + i][2 + jn], 0, 0, 0);
        __builtin_amdgcn_s_setprio(0);
        __builtin_amdgcn_s_barrier();
        __builtin_amdgcn_sched_barrier(0);
    }

    const int rg = (lane >> 4) * 4;
    if (GLUE) {
        __hip_bfloat16* Cb = (__hip_bfloat16*)Cout;
        const int No = N >> 1;
#pragma unroll
        for (int p = 0; p < 2; ++p) {
            int jcol = ((n0 + wc * 64) >> 1) + p * 16 + rsel;
            float ba = bias[jcol];
            float bgv = bias[Hn + jcol];
#pragma unroll
            for (int mi = 0; mi < 8; ++mi) {
                int row = m0 + wr * 128 + mi * 16 + rg;
                f32x4 va = acc[mi][2 * p], vg = acc[mi][2 * p + 1];
#pragma unroll
                for (int q = 0; q < 4; ++q) {
                    float a = va[q] + ba;
                    float g = vg[q] + bgv;
                    Cb[(long)(row + q) * No + jcol] = f2bf(a * (1.f / (1.f + __expf(-g))));
                }
            }
        }
        return;
    }
    float* Cf = (float*)Cout;
    __hip_bfloat16* Cb = (__hip_bfloat16*)Cout;
#pragma unroll
    for (int ni = 0; ni < 4; ++ni) {
        int col = n0 + wc * 64 + ni * 16 + rsel;
        if (NBOUND && col >= N) continue;
        float bi = bias ? bias[col] : 0.f;
#pragma unroll
        for (int mi = 0; mi < 8; ++mi) {
            int row = m0 + wr * 128 + mi * 16 + rg;
            f32x4 v = acc[mi][ni];
#pragma unroll
            for (int q = 0; q < 4; ++q) {
                long idx = (long)(row + q) * N + col;
                float x = v[q] + bi;
                if (OUTF32) Cf[idx] = x;
                else Cb[idx] = f2bf(x);
            }
        }
    }
}

// ---------------- launcher ----------------

extern "C" void kernel_launch(void* const* d_in, const int* in_sizes, int n_in,
                              void* d_out, int out_size, void* d_ws, size_t ws_size,
                              hipStream_t stream) {
    const int* tgt = (const int*)d_in[0];
    const float* enc_conved = (const float*)d_in[1];
    const float* enc_combined = (const float*)d_in[2];
    const float* tok_emb = (const float*)d_in[3];
    const float* pos_emb = (const float*)d_in[4];
    const float* w_e2h = (const float*)d_in[5];
    const float* b_e2h = (const float*)d_in[6];
    const float* w_h2e = (const float*)d_in[7];
    const float* b_h2e = (const float*)d_in[8];
    const float* w_ah2e = (const float*)d_in[9];
    const float* b_ah2e = (const float*)d_in[10];
    const float* w_ae2h = (const float*)d_in[11];
    const float* b_ae2h = (const float*)d_in[12];
    const float* w_fc = (const float*)d_in[13];
    const float* b_fc = (const float*)d_in[14];
    const float* conv_w = (const float*)d_in[15];
    const float* conv_b = (const float*)d_in[16];

    char* ws = (char*)d_ws;
    size_t off = 0;
    auto alloc = [&](size_t bytes) { size_t r = off; off = (off + bytes + 255) & ~(size_t)255; return r; };
    __hip_bfloat16* emb    = (__hip_bfloat16*)(ws + alloc((size_t)Mn * En * 2));
    __hip_bfloat16* embA   = (__hip_bfloat16*)(ws + alloc((size_t)Mn * En * 2));
    __hip_bfloat16* convin = (__hip_bfloat16*)(ws + alloc((size_t)Mn * Hn * 2));
    __hip_bfloat16* conved = (__hip_bfloat16*)(ws + alloc((size_t)Mn * Hn * 2));
    size_t o_en = alloc((size_t)Mn * Sn * 4);
    float* energy = (float*)(ws + o_en);
    __hip_bfloat16* encm = (__hip_bfloat16*)(ws + o_en);   // overlay: prep-only bf16(enc_combined)
    __hip_bfloat16* attnbf = (__hip_bfloat16*)(ws + alloc((size_t)Mn * Sn * 2));
    __hip_bfloat16* wT_e2h = (__hip_bfloat16*)(ws + alloc((size_t)Hn * En * 2));
    __hip_bfloat16* wT_h2e = (__hip_bfloat16*)(ws + alloc((size_t)En * Hn * 2));
    __hip_bfloat16* wT_ae2h= (__hip_bfloat16*)(ws + alloc((size_t)Hn * En * 2));
    __hip_bfloat16* wbAH   = (__hip_bfloat16*)(ws + alloc((size_t)Hn * En * 2));   // w_ah2e bf16 [H,E]
    __hip_bfloat16* wT_fc  = (__hip_bfloat16*)(ws + alloc((size_t)Vn * En * 2));
    __hip_bfloat16* encc   = (__hip_bfloat16*)(ws + alloc((size_t)Bn * Sn * En * 2));
    __hip_bfloat16* encAH  = (__hip_bfloat16*)(ws + alloc((size_t)Bn * Sn * Hn * 2));
    __hip_bfloat16* encCW  = (__hip_bfloat16*)(ws + alloc((size_t)Bn * Hn * Sn * 2));
    float* embE            = (float*)(ws + alloc((size_t)Mn * Sn * 4));
    __hip_bfloat16* padrow = (__hip_bfloat16*)(ws + alloc(256));
    __hip_bfloat16* wpack  = (__hip_bfloat16*)(ws + alloc((size_t)2 * Hn * 3 * Hn * 2)); // per-layer, warm
    __hip_bfloat16* tmpE = conved;  // overlay: conved dead after last update GEMM

    float* out = (float*)d_out;
    float* attn_out = out + (long)Mn * Vn;
    const long bSq = (long)Sn * Sn;
    const long bSH = (long)Sn * Hn;

    dim3 tb(32, 8);
    const __hip_bfloat16* nb = nullptr;
    const float* nf = nullptr;

    // ---- prep ----
    padfill_kernel<<<1, 128, 0, stream>>>(padrow);
    embed_kernel<<<Mn, 128, 0, stream>>>(tgt, tok_emb, pos_emb, b_ah2e, emb, embA);
    transpose_f32_bf16<<<dim3(Hn / 32, En / 32, 1), tb, 0, stream>>>(w_e2h, wT_e2h, En, Hn, 0, 0);
    transpose_f32_bf16<<<dim3(En / 32, Hn / 32, 1), tb, 0, stream>>>(w_h2e, wT_h2e, Hn, En, 0, 0);
    transpose_f32_bf16<<<dim3(Hn / 32, En / 32, 1), tb, 0, stream>>>(w_ae2h, wT_ae2h, En, Hn, 0, 0);
    transpose_f32_bf16<<<dim3((Vn + 31) / 32, En / 32, 1), tb, 0, stream>>>(w_fc, wT_fc, En, Vn, 0, 0);
    convert_bf16_kernel<<<((long)Hn * En / 4 + 255) / 256, 256, 0, stream>>>(w_ah2e, wbAH, (long)Hn * En / 4);
    convert_bf16_kernel<<<((long)Bn * Sn * En / 4 + 255) / 256, 256, 0, stream>>>(enc_conved, encc, (long)Bn * Sn * En / 4);
    convert_bf16_kernel<<<((long)Bn * Sn * En / 4 + 255) / 256, 256, 0, stream>>>(enc_combined, encm, (long)Bn * Sn * En / 4);

    // encAH[b][s][h] = encc[b] @ w_ah2e^T   (layer-invariant attention factor)
    gemm_bf16<0, false, false><<<dim3(Hn / 128, Sn / 128, Bn), 256, 0, stream>>>(
        encc, wbAH, nullptr, encAH, nb, nb, nf, padrow, Sn, Hn, En, bSq, 0, bSH, 1.f, 1.f);
    // encCW[b][h][s] = (enc_combined[b] @ w_ae2h)^T
    gemm_bf16<0, false, false><<<dim3(Sn / 128, Hn / 128, Bn), 256, 0, stream>>>(
        wT_ae2h, encm, nullptr, encCW, nb, nb, nf, padrow, Hn, Sn, En, 0, bSq, bSH, 1.f, 1.f);
    // embE[b][t][s] = embA[b] @ encc[b]^T   (f32; kScale folded into embA)
    gemm_bf16<0, true, false><<<dim3(Sn / 128, Tn / 128, Bn), 256, 0, stream>>>(
        embA, encc, nullptr, embE, nb, nb, nf, padrow, Tn, Sn, En, bSq, bSq, bSq, 1.f, 1.f);
    // conv_input = embedded @ emb2hid + b       [8192,1024]
    gemm_bf16<0, false, false><<<dim3(Hn / 128, Mn / 128, 1), 256, 0, stream>>>(
        emb, wT_e2h, b_e2h, convin, nb, nb, nf, padrow, Mn, Hn, En, 0, 0, 0, 1.f, 1.f);

    for (int l = 0; l < Ln; ++l) {
        // pack conv weight for THIS layer just before use (keeps B-panel L2/L3-warm)
        wpack2_kernel<<<2 * Hn, 256, 0, stream>>>(conv_w, wpack, l);
        // conved = GLU(im2col(conv_input) @ wpack^T + conv_b[l])   [8192,1024] fused
        gemm256<false, true, true, false><<<dim3(2 * Hn / 256, Mn / 256, 1), 512, 0, stream>>>(
            convin, wpack, conv_b + (long)l * 2 * Hn, conved, padrow, Mn, 2 * Hn, 3 * Hn);
        // energy[b] = kScale * conved[b] @ encAH[b]^T(B-layout) + embE[b]   (f32)
        gemm_bf16<3, true, false><<<dim3(Sn / 128, Tn / 128, Bn), 256, 0, stream>>>(
            conved, encAH, nullptr, energy, nb, nb, embE, padrow,
            Tn, Sn, Hn, (long)Tn * Hn, bSH, bSq, kScale, 1.f);
        // attention = softmax(energy)  (f32 out only needed from the LAST layer)
        softmax_kernel<<<Mn, 256, 0, stream>>>(energy, (l == Ln - 1) ? attn_out : nullptr, attnbf);
        // conv_input = ((attn @ encCW + b_ae2h + conved)*s + conv_input)*s
        gemm_bf16<2, false, false><<<dim3(Hn / 128, Tn / 128, Bn), 256, 0, stream>>>(
            attnbf, encCW, b_ae2h, convin, conved, convin, nf, padrow,
            Tn, Hn, Sn, bSq, bSH, (long)Tn * Hn, kScale, kScale);
    }

    // conved = conv_input @ hid2emb + b   [8192,512]  (tmpE overlays conved)
    gemm_bf16<0, false, false><<<dim3(En / 128, Mn / 128, 1), 256, 0, stream>>>(
        convin, wT_h2e, b_h2e, tmpE, nb, nb, nf, padrow, Mn, En, Hn, 0, 0, 0, 1.f, 1.f);
    // output = conved @ fc_out + b        [8192,10000] f32, N-bounded  (256² 4-phase)
    gemm256<true, false, false, true><<<dim3((Vn + 255) / 256, Mn / 256, 1), 512, 0, stream>>>(
        tmpE, wT_fc, b_fc, out, padrow, Mn, Vn, En);
}

// Round 11
// 1302.996 us; speedup vs baseline: 1.1155x; 1.1155x over previous
//
#include <hip/hip_runtime.h>
#include <hip/hip_bf16.h>

typedef __attribute__((ext_vector_type(4))) float f32x4;
typedef __attribute__((ext_vector_type(8))) short short8;

#define DEVFN __device__ __forceinline__

static constexpr int Bn = 16, Tn = 512, Sn = 512, Vn = 10000, En = 512, Hn = 1024, Ln = 6;
static constexpr int Mn = Bn * Tn;  // 8192 token rows
static constexpr int TP = Tn + 2;   // padded sequence rows (2 causal PAD rows)
static constexpr float kScale = 0.70710678118654752440f;

DEVFN float bf2f(__hip_bfloat16 x) { return __bfloat162float(x); }
DEVFN __hip_bfloat16 f2bf(float x) { return __float2bfloat16(x); }

struct bf16x4 { __hip_bfloat16 x, y, z, w; };

// async global -> LDS, 16B per lane (wave-uniform LDS base + lane*16 layout)
DEVFN void gload_lds16(const short* g, short* l) {
    __builtin_amdgcn_global_load_lds((const __attribute__((address_space(1))) void*)g,
                                     (__attribute__((address_space(3))) void*)l, 16, 0, 0);
}

// ---------------- small prep kernels ----------------

__global__ void padfill_kernel(__hip_bfloat16* p) {
    p[threadIdx.x] = f2bf(1.0f);  // PAD_VAL as float, per torch code
}

// fill the 2 causal PAD rows of each padded sequence in convinP with 1.0
__global__ void padrows_kernel(__hip_bfloat16* convinP) {
    int row = blockIdx.x;                 // 0..31: (b, which)
    long base = ((long)(row >> 1) * TP + (row & 1)) * Hn;
    int e = threadIdx.x * 4;              // 256 threads x 4 = 1024
    bf16x4 v{f2bf(1.f), f2bf(1.f), f2bf(1.f), f2bf(1.f)};
    *(bf16x4*)(convinP + base + e) = v;
}

// embedded[b,t,:] = tok_emb[tgt[b,t],:] + pos_emb[t,:]  (bf16)
// embA = kScale*(embedded + b_ah2e)                      (bf16, for embE precompute)
__global__ void embed_kernel(const int* __restrict__ tgt, const float* __restrict__ tok,
                             const float* __restrict__ pos, const float* __restrict__ bah,
                             __hip_bfloat16* __restrict__ out, __hip_bfloat16* __restrict__ outA) {
    int row = blockIdx.x;              // 0..8191
    int t = row & (Tn - 1);
    int v = tgt[row];
    const float* tr = tok + (long)v * En;
    const float* pr = pos + (long)t * En;
    int e = threadIdx.x * 4;           // block 128 covers 512
    float4 a = *(const float4*)(tr + e);
    float4 b = *(const float4*)(pr + e);
    float4 bb = *(const float4*)(bah + e);
    bf16x4 o{f2bf(a.x + b.x), f2bf(a.y + b.y), f2bf(a.z + b.z), f2bf(a.w + b.w)};
    *(bf16x4*)(out + (long)row * En + e) = o;
    bf16x4 oa{f2bf(kScale * (a.x + b.x + bb.x)), f2bf(kScale * (a.y + b.y + bb.y)),
              f2bf(kScale * (a.z + b.z + bb.z)), f2bf(kScale * (a.w + b.w + bb.w))};
    *(bf16x4*)(outA + (long)row * En + e) = oa;
}

// dst[c][r] = bf16(src[r][c]); src is [R][C] f32. grid(ceil(C/32), ceil(R/32), Z), block(32,8)
__global__ void transpose_f32_bf16(const float* __restrict__ src, __hip_bfloat16* __restrict__ dst,
                                   int R, int C, long sZi, long sZo) {
    __shared__ float tile[32][33];
    src += (long)blockIdx.z * sZi;
    dst += (long)blockIdx.z * sZo;
    int c0 = blockIdx.x * 32, r0 = blockIdx.y * 32;
    for (int i = threadIdx.y; i < 32; i += 8) {
        int r = r0 + i, c = c0 + threadIdx.x;
        tile[i][threadIdx.x] = (r < R && c < C) ? src[(long)r * C + c] : 0.f;
    }
    __syncthreads();
    for (int i = threadIdx.y; i < 32; i += 8) {
        int c = c0 + i, r = r0 + threadIdx.x;
        if (c < C && r < R) dst[(long)c * R + r] = f2bf(tile[threadIdx.x][i]);
    }
}

// f32 -> bf16 convert (n divisible by 4)
__global__ void convert_bf16_kernel(const float* __restrict__ src, __hip_bfloat16* __restrict__ dst,
                                    long n4) {
    long i = (long)blockIdx.x * blockDim.x + threadIdx.x;
    if (i >= n4) return;
    long j = i * 4;
    float4 v = *(const float4*)(src + j);
    bf16x4 o{f2bf(v.x), f2bf(v.y), f2bf(v.z), f2bf(v.w)};
    *(bf16x4*)(dst + j) = o;
}

// Coalesced conv-weight pack for layer l, a/g interleaved in 16-col blocks for fused GLU.
// One block per packed output row c (grid 2048): coalesced float4 read of the 3072-f32
// source row into LDS, stride-3 gather, coalesced bf16x4 writes.
// wp[c][tap*H+i] = bf16(conv_w[l][o(c)][i][tap]).
__global__ __launch_bounds__(256) void wpack2_kernel(const float* __restrict__ convw,
                                                     __hip_bfloat16* __restrict__ wp, int l) {
    __shared__ float row[3 * Hn];
    int c = blockIdx.x;                        // 0..2047 packed col
    int grp = c >> 5, w = c & 31;
    int o = (w < 16) ? grp * 16 + w : Hn + grp * 16 + (w - 16);
    const float* src = convw + ((long)(l * 2 * Hn + o)) * (Hn * 3);
#pragma unroll
    for (int j = 0; j < 3; ++j) {
        int idx = (j * 256 + threadIdx.x) * 4;
        *(float4*)&row[idx] = *(const float4*)(src + idx);
    }
    __syncthreads();
    __hip_bfloat16* dst = wp + (long)c * (3 * Hn);
#pragma unroll
    for (int j = 0; j < 3; ++j) {
        int kk = (j * 256 + threadIdx.x) * 4;   // 4-chunk never crosses a tap boundary
        int tap = kk >> 10;
        int i = kk & (Hn - 1);
        bf16x4 v{f2bf(row[i * 3 + tap]), f2bf(row[(i + 1) * 3 + tap]),
                 f2bf(row[(i + 2) * 3 + tap]), f2bf(row[(i + 3) * 3 + tap])};
        *(bf16x4*)(dst + kk) = v;
    }
}

// row softmax over S=512; writes bf16 (next GEMM input) + optional f32 (final attention)
__global__ __launch_bounds__(256) void softmax_kernel(const float* __restrict__ energy,
                                                      float* __restrict__ attn_f32,
                                                      __hip_bfloat16* __restrict__ attn_bf) {
    int row = blockIdx.x;  // 0..8191
    const float* e = energy + (long)row * Sn;
    int tid = threadIdx.x;
    float v0 = e[tid], v1 = e[tid + 256];
    float m = fmaxf(v0, v1);
    for (int off = 32; off; off >>= 1) m = fmaxf(m, __shfl_xor(m, off));
    __shared__ float redm[4];
    __shared__ float reds[4];
    int lane = tid & 63, w = tid >> 6;
    if (lane == 0) redm[w] = m;
    __syncthreads();
    m = fmaxf(fmaxf(redm[0], redm[1]), fmaxf(redm[2], redm[3]));
    float x0 = __expf(v0 - m), x1 = __expf(v1 - m);
    float s = x0 + x1;
    for (int off = 32; off; off >>= 1) s += __shfl_xor(s, off);
    if (lane == 0) reds[w] = s;
    __syncthreads();
    s = reds[0] + reds[1] + reds[2] + reds[3];
    float inv = 1.f / s;
    long base = (long)row * Sn;
    if (attn_f32) {
        attn_f32[base + tid] = x0 * inv;
        attn_f32[base + tid + 256] = x1 * inv;
    }
    attn_bf[base + tid] = f2bf(x0 * inv);
    attn_bf[base + tid + 256] = f2bf(x1 * inv);
}

// ---------------- 128x128 2-phase GEMM ----------------
// C[M,N] = A[M,K] @ Bw[N,K]^T.  EPI: 0: x=acc+bias; 2: x=((acc+bias+R1)*s1+R2)*s2;
// 3: x=acc*s1 + R1f[idx].  C/R2 batch stride cZ; R1/R1f batch stride r1Z.
template <int EPI, bool OUTF32, bool NBOUND>
__global__ __launch_bounds__(256) void gemm_bf16(
    const __hip_bfloat16* __restrict__ A, const __hip_bfloat16* __restrict__ Bw,
    const float* __restrict__ bias, void* __restrict__ Cout,
    const __hip_bfloat16* __restrict__ R1, const __hip_bfloat16* __restrict__ R2,
    const float* __restrict__ R1f, const __hip_bfloat16* __restrict__ padrow,
    int M, int N, int K, long aZ, long bZ, long cZ, long r1Z, float s1, float s2) {
    __shared__ alignas(16) short As[2][128 * 32];
    __shared__ alignas(16) short Bs[2][128 * 32];
    const int tid = threadIdx.x;
    const int lane = tid & 63;
    const int wid = tid >> 6;
    const int wr = wid >> 1, wc = wid & 1;
    const int m0 = blockIdx.y * 128, n0 = blockIdx.x * 128;
    const short* Ag = (const short*)A + (long)blockIdx.z * aZ;
    const short* Bg = (const short*)Bw + (long)blockIdx.z * bZ;
    const short* pad = (const short*)padrow;

    f32x4 acc[4][4] = {};

    const int rc = tid >> 2;
    const int k8 = (tid & 3) * 8;

    auto stage = [&](int buf, int k0) {
#pragma unroll
        for (int j = 0; j < 2; ++j) {
            int r = rc + j * 64;
            const short* asrc = Ag + (long)(m0 + r) * K + k0 + k8;
            gload_lds16(asrc, &As[buf][r * 32 + k8]);
            int n = n0 + r;
            const short* bsrc = (NBOUND && n >= N) ? (pad + k8) : (Bg + (long)n * K + k0 + k8);
            gload_lds16(bsrc, &Bs[buf][r * 32 + k8]);
        }
    };

    stage(0, 0);
    __syncthreads();

    int cur = 0;
    for (int k0 = 0; k0 < K; k0 += 32) {
        if (k0 + 32 < K) stage(cur ^ 1, k0 + 32);
        const int rsel = lane & 15, hi = (lane >> 4) * 8;
        short8 af[4], bg[4];
#pragma unroll
        for (int mi = 0; mi < 4; ++mi)
            af[mi] = *(const short8*)&As[cur][(wr * 64 + mi * 16 + rsel) * 32 + hi];
#pragma unroll
        for (int ni = 0; ni < 4; ++ni)
            bg[ni] = *(const short8*)&Bs[cur][(wc * 64 + ni * 16 + rsel) * 32 + hi];
#pragma unroll
        for (int mi = 0; mi < 4; ++mi)
#pragma unroll
            for (int ni = 0; ni < 4; ++ni)
                acc[mi][ni] = __builtin_amdgcn_mfma_f32_16x16x32_bf16(af[mi], bg[ni], acc[mi][ni], 0, 0, 0);
        __syncthreads();
        cur ^= 1;
    }

    const int rsel = lane & 15, rg = (lane >> 4) * 4;
    float* Cf = (float*)Cout + (long)blockIdx.z * cZ;
    __hip_bfloat16* Cb = (__hip_bfloat16*)Cout + (long)blockIdx.z * cZ;
    const __hip_bfloat16* R1z = R1 + (long)blockIdx.z * r1Z;
    const __hip_bfloat16* R2z = R2 + (long)blockIdx.z * cZ;
    const float* R1fz = R1f + (long)blockIdx.z * r1Z;
#pragma unroll
    for (int ni = 0; ni < 4; ++ni) {
        int col = n0 + wc * 64 + ni * 16 + rsel;
        if (NBOUND && col >= N) continue;
        float bi = (EPI != 3 && bias) ? bias[col] : 0.f;
#pragma unroll
        for (int mi = 0; mi < 4; ++mi) {
            int row = m0 + wr * 64 + mi * 16 + rg;
            f32x4 v = acc[mi][ni];
#pragma unroll
            for (int q = 0; q < 4; ++q) {
                long idx = (long)(row + q) * N + col;
                float x;
                if (EPI == 3) x = v[q] * s1 + R1fz[idx];
                else {
                    x = v[q] + bi;
                    if (EPI >= 1) x = (x + bf2f(R1z[idx])) * s1;
                    if (EPI >= 2) x = (x + bf2f(R2z[idx])) * s2;
                }
                if (OUTF32) Cf[idx] = x;
                else Cb[idx] = f2bf(x);
            }
        }
    }
}

// ---------------- conv+GLU kernel: tap-dedup'd staging ----------------
// C = GLU(im2col(convinP) @ wpack^T + b). 256x256 tile, 8 waves (2Mx4N), BK=32 over H.
// Per kk-tile: stage A ONCE as a 384-row panel (128-row halo covers tap shifts; causal
// pads are real rows in the padded convinP buffer) + 3 B tap-panels; acc += sum_tap
// A[r+tap-2] @ B_tap via shifted LDS read rows. Staged bytes/block 2.30 MB vs 3.07 MB
// for virtual-K im2col. Swizzle for 32-col rows: slot ^= (row>>1)&3 (2-way = free).
// Coarse 2-barrier loop with counted vmcnt(9) (round-9 proven pattern).
__global__ __launch_bounds__(512) void conv_glu_kernel(
    const __hip_bfloat16* __restrict__ Ain,   // convinP [16][514][1024]
    const __hip_bfloat16* __restrict__ Bw,    // wpack [2048][3072]
    const float* __restrict__ bias, __hip_bfloat16* __restrict__ Cout,
    const __hip_bfloat16* __restrict__ padrow) {
    __shared__ alignas(16) short As[2][384 * 32];      // 48 KB
    __shared__ alignas(16) short Bs[2][3 * 256 * 32];  // 96 KB
    const int tid = threadIdx.x;
    const int lane = tid & 63;
    const int wid = tid >> 6;
    const int wr = wid >> 2, wc = wid & 3;
    const int nwg = gridDim.x * gridDim.y;   // 256
    const int orig = blockIdx.y * gridDim.x + blockIdx.x;
    const int qd = nwg >> 3, rd = nwg & 7, xc = orig & 7, loc = orig >> 3;
    const int bid = (xc < rd ? xc * (qd + 1) : rd * (qd + 1) + (xc - rd) * qd) + loc;
    const int n0 = (bid % gridDim.x) * 256, m0 = (bid / gridDim.x) * 256;
    const short* Ag = (const short*)Ain;
    const short* Bg = (const short*)Bw;
    const short* pad = (const short*)padrow;
    const int p0 = (m0 >> 9) * TP + 2 + (m0 & 511);   // padded-space base row

    f32x4 acc[8][4] = {};

    const int srow = tid >> 2;                  // row within 128-row staging round
    const int skey = (tid >> 3) & 3;            // (row>>1)&3 (round base = 0 mod 8)
    const int scol = ((tid & 3) ^ skey) * 8;    // inverse-swizzled global col (elems)
    const int sdst = tid * 8;                   // linear LDS elems per round

    auto stageA = [&](int buf, int kt) {
        const int k0 = kt * 32;
#pragma unroll
        for (int j = 0; j < 3; ++j) {           // 384 rows = 3 rounds
            int prow = p0 - 128 + j * 128 + srow;
            const short* src = (prow >= 0) ? (Ag + (long)prow * Hn + k0 + scol) : (pad + scol);
            gload_lds16(src, &As[buf][j * 4096 + sdst]);
        }
    };
    auto stageB = [&](int buf, int kt) {
        const int k0 = kt * 32;
#pragma unroll
        for (int tap = 0; tap < 3; ++tap)
#pragma unroll
            for (int j = 0; j < 2; ++j) {       // 256 rows = 2 rounds per tap
                int row = j * 128 + srow;
                const short* src = Bg + (long)(n0 + row) * 3072 + tap * 1024 + k0 + scol;
                gload_lds16(src, &Bs[buf][tap * 8192 + j * 4096 + sdst]);
            }
    };

    const int rsel = lane & 15, hi = (lane >> 4) * 8;

    stageA(0, 0); stageB(0, 0);                 // 9 loads/thread in flight
    for (int t = 0; t < 32; ++t) {
        const int cur = t & 1;
        if (t + 1 < 32) {
            stageA(cur ^ 1, t + 1); stageB(cur ^ 1, t + 1);
            asm volatile("s_waitcnt vmcnt(9)" ::: "memory");   // tile t's 9 loads done
        } else {
            asm volatile("s_waitcnt vmcnt(0)" ::: "memory");
        }
        __builtin_amdgcn_s_barrier();
        __builtin_amdgcn_sched_barrier(0);
#pragma unroll
        for (int tap = 0; tap < 3; ++tap) {
            short8 bg[4];
#pragma unroll
            for (int ni = 0; ni < 4; ++ni) {
                int row = wc * 64 + ni * 16 + rsel;
                int xk = ((row >> 1) & 3) << 3;
                bg[ni] = *(const short8*)&Bs[cur][tap * 8192 + row * 32 + (hi ^ xk)];
            }
#pragma unroll
            for (int mh = 0; mh < 2; ++mh) {
                short8 af[4];
#pragma unroll
                for (int i = 0; i < 4; ++i) {
                    int row = 126 + tap + wr * 128 + mh * 64 + i * 16 + rsel;  // tap shift
                    int xk = ((row >> 1) & 3) << 3;
                    af[i] = *(const short8*)&As[cur][row * 32 + (hi ^ xk)];
                }
                __builtin_amdgcn_s_setprio(1);
#pragma unroll
                for (int i = 0; i < 4; ++i)
#pragma unroll
                    for (int ni = 0; ni < 4; ++ni)
                        acc[mh * 4 + i][ni] = __builtin_amdgcn_mfma_f32_16x16x32_bf16(
                            af[i], bg[ni], acc[mh * 4 + i][ni], 0, 0, 0);
                __builtin_amdgcn_s_setprio(0);
                __builtin_amdgcn_sched_barrier(0);
            }
        }
        __builtin_amdgcn_s_barrier();
        __builtin_amdgcn_sched_barrier(0);
    }

    // fused GLU epilogue: ni pairs (0,1) and (2,3) are (a,g) of the same 32-col group
    const int rg = (lane >> 4) * 4;
    const int No = Hn;
#pragma unroll
    for (int p = 0; p < 2; ++p) {
        int jcol = ((n0 + wc * 64) >> 1) + p * 16 + rsel;
        float ba = bias[jcol];
        float bgv = bias[Hn + jcol];
#pragma unroll
        for (int mi = 0; mi < 8; ++mi) {
            int row = m0 + wr * 128 + mi * 16 + rg;
            f32x4 va = acc[mi][2 * p], vg = acc[mi][2 * p + 1];
#pragma unroll
            for (int q = 0; q < 4; ++q) {
                float a = va[q] + ba;
                float g = vg[q] + bgv;
                Cout[(long)(row + q) * No + jcol] = f2bf(a * (1.f / (1.f + __expf(-g))));
            }
        }
    }
}

// ---------------- 256x256 coarse deep-pipeline GEMM (fc_out) ----------------
// Round-9 proven structure: stage all 8 -> vmcnt(8) -> barrier -> dedup'd frag reads
// -> 2 mh sections of 32 MFMA -> barrier.
template <bool OUTF32, bool NBOUND>
__global__ __launch_bounds__(512) void gemm256(
    const __hip_bfloat16* __restrict__ A, const __hip_bfloat16* __restrict__ Bw,
    const float* __restrict__ bias, void* __restrict__ Cout,
    const __hip_bfloat16* __restrict__ padrow, int M, int N, int K) {
    __shared__ alignas(16) short As[2][256 * 64];
    __shared__ alignas(16) short Bs[2][256 * 64];
    const int tid = threadIdx.x;
    const int lane = tid & 63;
    const int wid = tid >> 6;
    const int wr = wid >> 2, wc = wid & 3;
    const int nwg = gridDim.x * gridDim.y;
    const int orig = blockIdx.y * gridDim.x + blockIdx.x;
    const int qd = nwg >> 3, rd = nwg & 7, xc = orig & 7, loc = orig >> 3;
    const int bid = (xc < rd ? xc * (qd + 1) : rd * (qd + 1) + (xc - rd) * qd) + loc;
    const int n0 = (bid % gridDim.x) * 256, m0 = (bid / gridDim.x) * 256;
    const short* Ag = (const short*)A;
    const short* Bg = (const short*)Bw;
    const short* pad = (const short*)padrow;

    f32x4 acc[8][4] = {};

    const int srow_l = tid >> 3;
    const int scol = ((tid & 7) ^ (srow_l & 7)) * 8;
    const int sdst = (tid >> 3) * 64 + (tid & 7) * 8;

    auto stage = [&](int buf, int kt) {
        const int k0 = kt * 64;
#pragma unroll
        for (int j = 0; j < 4; ++j) {
            const int row = j * 64 + srow_l;
            const short* asrc = Ag + (long)(m0 + row) * K + k0 + scol;
            gload_lds16(asrc, &As[buf][j * 4096 + sdst]);
            int n = n0 + row;
            const short* bsrc = (NBOUND && n >= N) ? (pad + scol) : (Bg + (long)n * K + k0 + scol);
            gload_lds16(bsrc, &Bs[buf][j * 4096 + sdst]);
        }
    };

    const int rsel = lane & 15, hi = (lane >> 4) * 8;
    const int xorc = (rsel & 7) << 3;

    stage(0, 0);
    const int NT = K >> 6;
    for (int t = 0; t < NT; ++t) {
        const int cur = t & 1;
        if (t + 1 < NT) {
            stage(cur ^ 1, t + 1);
            asm volatile("s_waitcnt vmcnt(8)" ::: "memory");
        } else {
            asm volatile("s_waitcnt vmcnt(0)" ::: "memory");
        }
        __builtin_amdgcn_s_barrier();
        __builtin_amdgcn_sched_barrier(0);
        short8 bg[2][2][2];
#pragma unroll
        for (int nh = 0; nh < 2; ++nh)
#pragma unroll
            for (int i = 0; i < 2; ++i) {
                const int row = wc * 64 + nh * 32 + i * 16 + rsel;
#pragma unroll
                for (int ks = 0; ks < 2; ++ks)
                    bg[nh][i][ks] = *(const short8*)&Bs[cur][row * 64 + ((ks * 32 + hi) ^ xorc)];
            }
#pragma unroll
        for (int mh = 0; mh < 2; ++mh) {
            short8 af[4][2];
#pragma unroll
            for (int i = 0; i < 4; ++i) {
                const int row = wr * 128 + mh * 64 + i * 16 + rsel;
#pragma unroll
                for (int ks = 0; ks < 2; ++ks)
                    af[i][ks] = *(const short8*)&As[cur][row * 64 + ((ks * 32 + hi) ^ xorc)];
            }
            __builtin_amdgcn_s_setprio(1);
#pragma unroll
            for (int nh = 0; nh < 2; ++nh)
#pragma unroll
                for (int i = 0; i < 4; ++i)
#pragma unroll
                    for (int jn = 0; jn < 2; ++jn)
#pragma unroll
                        for (int ks = 0; ks < 2; ++ks)
                            acc[mh * 4 + i][nh * 2 + jn] = __builtin_amdgcn_mfma_f32_16x16x32_bf16(
                                af[i][ks], bg[nh][jn][ks], acc[mh * 4 + i][nh * 2 + jn], 0, 0, 0);
            __builtin_amdgcn_s_setprio(0);
            __builtin_amdgcn_sched_barrier(0);
        }
        __builtin_amdgcn_s_barrier();
        __builtin_amdgcn_sched_barrier(0);
    }

    const int rg = (lane >> 4) * 4;
    float* Cf = (float*)Cout;
    __hip_bfloat16* Cb = (__hip_bfloat16*)Cout;
#pragma unroll
    for (int ni = 0; ni < 4; ++ni) {
        int col = n0 + wc * 64 + ni * 16 + rsel;
        if (NBOUND && col >= N) continue;
        float bi = bias ? bias[col] : 0.f;
#pragma unroll
        for (int mi = 0; mi < 8; ++mi) {
            int row = m0 + wr * 128 + mi * 16 + rg;
            f32x4 v = acc[mi][ni];
#pragma unroll
            for (int q = 0; q < 4; ++q) {
                long idx = (long)(row + q) * N + col;
                float x = v[q] + bi;
                if (OUTF32) Cf[idx] = x;
                else Cb[idx] = f2bf(x);
            }
        }
    }
}

// ---------------- launcher ----------------

extern "C" void kernel_launch(void* const* d_in, const int* in_sizes, int n_in,
                              void* d_out, int out_size, void* d_ws, size_t ws_size,
                              hipStream_t stream) {
    const int* tgt = (const int*)d_in[0];
    const float* enc_conved = (const float*)d_in[1];
    const float* enc_combined = (const float*)d_in[2];
    const float* tok_emb = (const float*)d_in[3];
    const float* pos_emb = (const float*)d_in[4];
    const float* w_e2h = (const float*)d_in[5];
    const float* b_e2h = (const float*)d_in[6];
    const float* w_h2e = (const float*)d_in[7];
    const float* b_h2e = (const float*)d_in[8];
    const float* w_ah2e = (const float*)d_in[9];
    const float* b_ah2e = (const float*)d_in[10];
    const float* w_ae2h = (const float*)d_in[11];
    const float* b_ae2h = (const float*)d_in[12];
    const float* w_fc = (const float*)d_in[13];
    const float* b_fc = (const float*)d_in[14];
    const float* conv_w = (const float*)d_in[15];
    const float* conv_b = (const float*)d_in[16];

    char* ws = (char*)d_ws;
    size_t off = 0;
    auto alloc = [&](size_t bytes) { size_t r = off; off = (off + bytes + 255) & ~(size_t)255; return r; };
    __hip_bfloat16* emb    = (__hip_bfloat16*)(ws + alloc((size_t)Mn * En * 2));
    __hip_bfloat16* embA   = (__hip_bfloat16*)(ws + alloc((size_t)Mn * En * 2));
    __hip_bfloat16* convinP= (__hip_bfloat16*)(ws + alloc((size_t)Bn * TP * Hn * 2));  // padded
    __hip_bfloat16* conved = (__hip_bfloat16*)(ws + alloc((size_t)Mn * Hn * 2));
    size_t o_en = alloc((size_t)Mn * Sn * 4);
    float* energy = (float*)(ws + o_en);
    __hip_bfloat16* encm = (__hip_bfloat16*)(ws + o_en);   // overlay: prep-only bf16(enc_combined)
    __hip_bfloat16* attnbf = (__hip_bfloat16*)(ws + alloc((size_t)Mn * Sn * 2));
    __hip_bfloat16* wT_e2h = (__hip_bfloat16*)(ws + alloc((size_t)Hn * En * 2));
    __hip_bfloat16* wT_h2e = (__hip_bfloat16*)(ws + alloc((size_t)En * Hn * 2));
    __hip_bfloat16* wT_ae2h= (__hip_bfloat16*)(ws + alloc((size_t)Hn * En * 2));
    __hip_bfloat16* wbAH   = (__hip_bfloat16*)(ws + alloc((size_t)Hn * En * 2));
    __hip_bfloat16* wT_fc  = (__hip_bfloat16*)(ws + alloc((size_t)Vn * En * 2));
    __hip_bfloat16* encc   = (__hip_bfloat16*)(ws + alloc((size_t)Bn * Sn * En * 2));
    __hip_bfloat16* encAH  = (__hip_bfloat16*)(ws + alloc((size_t)Bn * Sn * Hn * 2));
    __hip_bfloat16* encCW  = (__hip_bfloat16*)(ws + alloc((size_t)Bn * Hn * Sn * 2));
    float* embE            = (float*)(ws + alloc((size_t)Mn * Sn * 4));
    __hip_bfloat16* padrow = (__hip_bfloat16*)(ws + alloc(256));
    __hip_bfloat16* wpack  = (__hip_bfloat16*)(ws + alloc((size_t)2 * Hn * 3 * Hn * 2)); // per-layer, warm
    __hip_bfloat16* tmpE = conved;  // overlay: conved dead after last update GEMM
    __hip_bfloat16* convinD = convinP + 2 * Hn;   // data rows base (skip 2 pads of batch 0)

    float* out = (float*)d_out;
    float* attn_out = out + (long)Mn * Vn;
    const long bSq = (long)Sn * Sn;
    const long bSH = (long)Sn * Hn;
    const long bTH = (long)Tn * Hn;
    const long bPH = (long)TP * Hn;   // padded per-batch stride

    dim3 tb(32, 8);
    const __hip_bfloat16* nb = nullptr;
    const float* nf = nullptr;

    // ---- prep ----
    padfill_kernel<<<1, 128, 0, stream>>>(padrow);
    padrows_kernel<<<2 * Bn, 256, 0, stream>>>(convinP);
    embed_kernel<<<Mn, 128, 0, stream>>>(tgt, tok_emb, pos_emb, b_ah2e, emb, embA);
    transpose_f32_bf16<<<dim3(Hn / 32, En / 32, 1), tb, 0, stream>>>(w_e2h, wT_e2h, En, Hn, 0, 0);
    transpose_f32_bf16<<<dim3(En / 32, Hn / 32, 1), tb, 0, stream>>>(w_h2e, wT_h2e, Hn, En, 0, 0);
    transpose_f32_bf16<<<dim3(Hn / 32, En / 32, 1), tb, 0, stream>>>(w_ae2h, wT_ae2h, En, Hn, 0, 0);
    transpose_f32_bf16<<<dim3((Vn + 31) / 32, En / 32, 1), tb, 0, stream>>>(w_fc, wT_fc, En, Vn, 0, 0);
    convert_bf16_kernel<<<((long)Hn * En / 4 + 255) / 256, 256, 0, stream>>>(w_ah2e, wbAH, (long)Hn * En / 4);
    convert_bf16_kernel<<<((long)Bn * Sn * En / 4 + 255) / 256, 256, 0, stream>>>(enc_conved, encc, (long)Bn * Sn * En / 4);
    convert_bf16_kernel<<<((long)Bn * Sn * En / 4 + 255) / 256, 256, 0, stream>>>(enc_combined, encm, (long)Bn * Sn * En / 4);

    // encAH[b][s][h] = encc[b] @ w_ah2e^T   (layer-invariant attention factor)
    gemm_bf16<0, false, false><<<dim3(Hn / 128, Sn / 128, Bn), 256, 0, stream>>>(
        encc, wbAH, nullptr, encAH, nb, nb, nf, padrow, Sn, Hn, En, bSq, 0, bSH, 0, 1.f, 1.f);
    // encCW[b][h][s] = (enc_combined[b] @ w_ae2h)^T
    gemm_bf16<0, false, false><<<dim3(Sn / 128, Hn / 128, Bn), 256, 0, stream>>>(
        wT_ae2h, encm, nullptr, encCW, nb, nb, nf, padrow, Hn, Sn, En, 0, bSq, bSH, 0, 1.f, 1.f);
    // embE[b][t][s] = embA[b] @ encc[b]^T   (f32; kScale folded into embA)
    gemm_bf16<0, true, false><<<dim3(Sn / 128, Tn / 128, Bn), 256, 0, stream>>>(
        embA, encc, nullptr, embE, nb, nb, nf, padrow, Tn, Sn, En, bSq, bSq, bSq, 0, 1.f, 1.f);
    // conv_input = embedded @ emb2hid + b   -> padded buffer (batched, rows +2)
    gemm_bf16<0, false, false><<<dim3(Hn / 128, Tn / 128, Bn), 256, 0, stream>>>(
        emb, wT_e2h, b_e2h, convinD, nb, nb, nf, padrow, Tn, Hn, En, (long)Tn * En, 0, bPH, 0, 1.f, 1.f);

    for (int l = 0; l < Ln; ++l) {
        // pack conv weight for THIS layer just before use (keeps B-panel L2/L3-warm)
        wpack2_kernel<<<2 * Hn, 256, 0, stream>>>(conv_w, wpack, l);
        // conved = GLU(conv(convinP) + conv_b[l])   [8192,1024], tap-dedup'd staging
        conv_glu_kernel<<<dim3(2 * Hn / 256, Mn / 256), 512, 0, stream>>>(
            convinP, wpack, conv_b + (long)l * 2 * Hn, conved, padrow);
        // energy[b] = kScale * conved[b] @ encAH[b]^T + embE[b]   (f32)
        gemm_bf16<3, true, false><<<dim3(Sn / 128, Tn / 128, Bn), 256, 0, stream>>>(
            conved, encAH, nullptr, energy, nb, nb, embE, padrow,
            Tn, Sn, Hn, bTH, bSH, bSq, bSq, kScale, 1.f);
        // attention = softmax(energy)  (f32 out only needed from the LAST layer)
        softmax_kernel<<<Mn, 256, 0, stream>>>(energy, (l == Ln - 1) ? attn_out : nullptr, attnbf);
        // conv_input = ((attn @ encCW + b_ae2h + conved)*s + conv_input)*s  (C/R2 padded)
        gemm_bf16<2, false, false><<<dim3(Hn / 128, Tn / 128, Bn), 256, 0, stream>>>(
            attnbf, encCW, b_ae2h, convinD, conved, convinD, nf, padrow,
            Tn, Hn, Sn, bSq, bSH, bPH, bTH, kScale, kScale);
    }

    // conved = conv_input @ hid2emb + b   [8192,512]  (A padded, batched; tmpE overlays conved)
    gemm_bf16<0, false, false><<<dim3(En / 128, Tn / 128, Bn), 256, 0, stream>>>(
        convinD, wT_h2e, b_h2e, tmpE, nb, nb, nf, padrow, Tn, En, Hn, bPH, 0, (long)Tn * En, 0, 1.f, 1.f);
    // output = conved @ fc_out + b        [8192,10000] f32, N-bounded  (256² coarse)
    gemm256<true, true><<<dim3((Vn + 255) / 256, Mn / 256), 512, 0, stream>>>(
        tmpE, wT_fc, b_fc, out, padrow, Mn, Vn, En);
}

// Round 12
// 1298.270 us; speedup vs baseline: 1.1195x; 1.0036x over previous
//
#include <hip/hip_runtime.h>
#include <hip/hip_bf16.h>

typedef __attribute__((ext_vector_type(4))) float f32x4;
typedef __attribute__((ext_vector_type(8))) short short8;

#define DEVFN __device__ __forceinline__

static constexpr int Bn = 16, Tn = 512, Sn = 512, Vn = 10000, En = 512, Hn = 1024, Ln = 6;
static constexpr int Mn = Bn * Tn;  // 8192 token rows
static constexpr int TP = Tn + 2;   // padded sequence rows (2 causal PAD rows)
static constexpr float kScale = 0.70710678118654752440f;

DEVFN float bf2f(__hip_bfloat16 x) { return __bfloat162float(x); }
DEVFN __hip_bfloat16 f2bf(float x) { return __float2bfloat16(x); }

struct bf16x4 { __hip_bfloat16 x, y, z, w; };

// async global -> LDS, 16B per lane (wave-uniform LDS base + lane*16 layout)
DEVFN void gload_lds16(const short* g, short* l) {
    __builtin_amdgcn_global_load_lds((const __attribute__((address_space(1))) void*)g,
                                     (__attribute__((address_space(3))) void*)l, 16, 0, 0);
}

// ---------------- small prep kernels ----------------

__global__ void padfill_kernel(__hip_bfloat16* p) {
    p[threadIdx.x] = f2bf(1.0f);  // PAD_VAL as float, per torch code
}

// fill the 2 causal PAD rows of each padded sequence in convinP with 1.0
__global__ void padrows_kernel(__hip_bfloat16* convinP) {
    int row = blockIdx.x;                 // 0..31: (b, which)
    long base = ((long)(row >> 1) * TP + (row & 1)) * Hn;
    int e = threadIdx.x * 4;              // 256 threads x 4 = 1024
    bf16x4 v{f2bf(1.f), f2bf(1.f), f2bf(1.f), f2bf(1.f)};
    *(bf16x4*)(convinP + base + e) = v;
}

// embedded[b,t,:] = tok_emb[tgt[b,t],:] + pos_emb[t,:]  (bf16)
// embA = kScale*(embedded + b_ah2e)                      (bf16, for embE precompute)
__global__ void embed_kernel(const int* __restrict__ tgt, const float* __restrict__ tok,
                             const float* __restrict__ pos, const float* __restrict__ bah,
                             __hip_bfloat16* __restrict__ out, __hip_bfloat16* __restrict__ outA) {
    int row = blockIdx.x;              // 0..8191
    int t = row & (Tn - 1);
    int v = tgt[row];
    const float* tr = tok + (long)v * En;
    const float* pr = pos + (long)t * En;
    int e = threadIdx.x * 4;           // block 128 covers 512
    float4 a = *(const float4*)(tr + e);
    float4 b = *(const float4*)(pr + e);
    float4 bb = *(const float4*)(bah + e);
    bf16x4 o{f2bf(a.x + b.x), f2bf(a.y + b.y), f2bf(a.z + b.z), f2bf(a.w + b.w)};
    *(bf16x4*)(out + (long)row * En + e) = o;
    bf16x4 oa{f2bf(kScale * (a.x + b.x + bb.x)), f2bf(kScale * (a.y + b.y + bb.y)),
              f2bf(kScale * (a.z + b.z + bb.z)), f2bf(kScale * (a.w + b.w + bb.w))};
    *(bf16x4*)(outA + (long)row * En + e) = oa;
}

// dst[c][r] = bf16(src[r][c]); src is [R][C] f32. grid(ceil(C/32), ceil(R/32), Z), block(32,8)
__global__ void transpose_f32_bf16(const float* __restrict__ src, __hip_bfloat16* __restrict__ dst,
                                   int R, int C, long sZi, long sZo) {
    __shared__ float tile[32][33];
    src += (long)blockIdx.z * sZi;
    dst += (long)blockIdx.z * sZo;
    int c0 = blockIdx.x * 32, r0 = blockIdx.y * 32;
    for (int i = threadIdx.y; i < 32; i += 8) {
        int r = r0 + i, c = c0 + threadIdx.x;
        tile[i][threadIdx.x] = (r < R && c < C) ? src[(long)r * C + c] : 0.f;
    }
    __syncthreads();
    for (int i = threadIdx.y; i < 32; i += 8) {
        int c = c0 + i, r = r0 + threadIdx.x;
        if (c < C && r < R) dst[(long)c * R + r] = f2bf(tile[threadIdx.x][i]);
    }
}

// f32 -> bf16 convert (n divisible by 4)
__global__ void convert_bf16_kernel(const float* __restrict__ src, __hip_bfloat16* __restrict__ dst,
                                    long n4) {
    long i = (long)blockIdx.x * blockDim.x + threadIdx.x;
    if (i >= n4) return;
    long j = i * 4;
    float4 v = *(const float4*)(src + j);
    bf16x4 o{f2bf(v.x), f2bf(v.y), f2bf(v.z), f2bf(v.w)};
    *(bf16x4*)(dst + j) = o;
}

// Coalesced conv-weight pack for layer l, a/g interleaved in 16-col blocks for fused GLU.
__global__ __launch_bounds__(256) void wpack2_kernel(const float* __restrict__ convw,
                                                     __hip_bfloat16* __restrict__ wp, int l) {
    __shared__ float row[3 * Hn];
    int c = blockIdx.x;                        // 0..2047 packed col
    int grp = c >> 5, w = c & 31;
    int o = (w < 16) ? grp * 16 + w : Hn + grp * 16 + (w - 16);
    const float* src = convw + ((long)(l * 2 * Hn + o)) * (Hn * 3);
#pragma unroll
    for (int j = 0; j < 3; ++j) {
        int idx = (j * 256 + threadIdx.x) * 4;
        *(float4*)&row[idx] = *(const float4*)(src + idx);
    }
    __syncthreads();
    __hip_bfloat16* dst = wp + (long)c * (3 * Hn);
#pragma unroll
    for (int j = 0; j < 3; ++j) {
        int kk = (j * 256 + threadIdx.x) * 4;   // 4-chunk never crosses a tap boundary
        int tap = kk >> 10;
        int i = kk & (Hn - 1);
        bf16x4 v{f2bf(row[i * 3 + tap]), f2bf(row[(i + 1) * 3 + tap]),
                 f2bf(row[(i + 2) * 3 + tap]), f2bf(row[(i + 3) * 3 + tap])};
        *(bf16x4*)(dst + kk) = v;
    }
}

// row softmax over S=512; writes bf16 (next GEMM input) + optional f32 (final attention)
__global__ __launch_bounds__(256) void softmax_kernel(const float* __restrict__ energy,
                                                      float* __restrict__ attn_f32,
                                                      __hip_bfloat16* __restrict__ attn_bf) {
    int row = blockIdx.x;  // 0..8191
    const float* e = energy + (long)row * Sn;
    int tid = threadIdx.x;
    float v0 = e[tid], v1 = e[tid + 256];
    float m = fmaxf(v0, v1);
    for (int off = 32; off; off >>= 1) m = fmaxf(m, __shfl_xor(m, off));
    __shared__ float redm[4];
    __shared__ float reds[4];
    int lane = tid & 63, w = tid >> 6;
    if (lane == 0) redm[w] = m;
    __syncthreads();
    m = fmaxf(fmaxf(redm[0], redm[1]), fmaxf(redm[2], redm[3]));
    float x0 = __expf(v0 - m), x1 = __expf(v1 - m);
    float s = x0 + x1;
    for (int off = 32; off; off >>= 1) s += __shfl_xor(s, off);
    if (lane == 0) reds[w] = s;
    __syncthreads();
    s = reds[0] + reds[1] + reds[2] + reds[3];
    float inv = 1.f / s;
    long base = (long)row * Sn;
    if (attn_f32) {
        attn_f32[base + tid] = x0 * inv;
        attn_f32[base + tid + 256] = x1 * inv;
    }
    attn_bf[base + tid] = f2bf(x0 * inv);
    attn_bf[base + tid + 256] = f2bf(x1 * inv);
}

// ---------------- 128x128 counted-vmcnt GEMM ----------------
// C[M,N] = A[M,K] @ Bw[N,K]^T. gemm256's proven coarse loop at 128^2 geometry:
// per K-tile {stage(nxt) 4 loads ; vmcnt(4) ; s_barrier ; frags+MFMA ; s_barrier}
// -- tile t+1's loads stay in flight across tile t's compute (no forced drain).
// EPI: 0: x=acc+bias; 2: x=((acc+bias+R1)*s1+R2)*s2; 3: x=acc*s1+R1f[idx].
template <int EPI, bool OUTF32, bool NBOUND>
__global__ __launch_bounds__(256) void gemm_bf16(
    const __hip_bfloat16* __restrict__ A, const __hip_bfloat16* __restrict__ Bw,
    const float* __restrict__ bias, void* __restrict__ Cout,
    const __hip_bfloat16* __restrict__ R1, const __hip_bfloat16* __restrict__ R2,
    const float* __restrict__ R1f, const __hip_bfloat16* __restrict__ padrow,
    int M, int N, int K, long aZ, long bZ, long cZ, long r1Z, float s1, float s2) {
    __shared__ alignas(16) short As[2][128 * 32];
    __shared__ alignas(16) short Bs[2][128 * 32];
    const int tid = threadIdx.x;
    const int lane = tid & 63;
    const int wid = tid >> 6;
    const int wr = wid >> 1, wc = wid & 1;
    const int m0 = blockIdx.y * 128, n0 = blockIdx.x * 128;
    const short* Ag = (const short*)A + (long)blockIdx.z * aZ;
    const short* Bg = (const short*)Bw + (long)blockIdx.z * bZ;
    const short* pad = (const short*)padrow;

    f32x4 acc[4][4] = {};

    const int rc = tid >> 2;
    const int k8 = (tid & 3) * 8;

    auto stage = [&](int buf, int k0) {
#pragma unroll
        for (int j = 0; j < 2; ++j) {
            int r = rc + j * 64;
            const short* asrc = Ag + (long)(m0 + r) * K + k0 + k8;
            gload_lds16(asrc, &As[buf][r * 32 + k8]);
            int n = n0 + r;
            const short* bsrc = (NBOUND && n >= N) ? (pad + k8) : (Bg + (long)n * K + k0 + k8);
            gload_lds16(bsrc, &Bs[buf][r * 32 + k8]);
        }
    };

    const int rsel = lane & 15, hi = (lane >> 4) * 8;

    stage(0, 0);
    const int NT = K >> 5;
    for (int t = 0; t < NT; ++t) {
        const int cur = t & 1;
        if (t + 1 < NT) {
            stage(cur ^ 1, (t + 1) * 32);                       // 4 loads, stay in flight
            asm volatile("s_waitcnt vmcnt(4)" ::: "memory");    // tile t's 4 loads done
        } else {
            asm volatile("s_waitcnt vmcnt(0)" ::: "memory");
        }
        __builtin_amdgcn_s_barrier();                           // tile t visible to all waves
        __builtin_amdgcn_sched_barrier(0);
        short8 af[4], bg[4];
#pragma unroll
        for (int mi = 0; mi < 4; ++mi)
            af[mi] = *(const short8*)&As[cur][(wr * 64 + mi * 16 + rsel) * 32 + hi];
#pragma unroll
        for (int ni = 0; ni < 4; ++ni)
            bg[ni] = *(const short8*)&Bs[cur][(wc * 64 + ni * 16 + rsel) * 32 + hi];
        __builtin_amdgcn_s_setprio(1);
#pragma unroll
        for (int mi = 0; mi < 4; ++mi)
#pragma unroll
            for (int ni = 0; ni < 4; ++ni)
                acc[mi][ni] = __builtin_amdgcn_mfma_f32_16x16x32_bf16(af[mi], bg[ni], acc[mi][ni], 0, 0, 0);
        __builtin_amdgcn_s_setprio(0);
        __builtin_amdgcn_s_barrier();                           // reads of cur done before reuse
        __builtin_amdgcn_sched_barrier(0);
    }

    const int rg = (lane >> 4) * 4;
    float* Cf = (float*)Cout + (long)blockIdx.z * cZ;
    __hip_bfloat16* Cb = (__hip_bfloat16*)Cout + (long)blockIdx.z * cZ;
    const __hip_bfloat16* R1z = R1 + (long)blockIdx.z * r1Z;
    const __hip_bfloat16* R2z = R2 + (long)blockIdx.z * cZ;
    const float* R1fz = R1f + (long)blockIdx.z * r1Z;
#pragma unroll
    for (int ni = 0; ni < 4; ++ni) {
        int col = n0 + wc * 64 + ni * 16 + rsel;
        if (NBOUND && col >= N) continue;
        float bi = (EPI != 3 && bias) ? bias[col] : 0.f;
#pragma unroll
        for (int mi = 0; mi < 4; ++mi) {
            int row = m0 + wr * 64 + mi * 16 + rg;
            f32x4 v = acc[mi][ni];
#pragma unroll
            for (int q = 0; q < 4; ++q) {
                long idx = (long)(row + q) * N + col;
                float x;
                if (EPI == 3) x = v[q] * s1 + R1fz[idx];
                else {
                    x = v[q] + bi;
                    if (EPI >= 1) x = (x + bf2f(R1z[idx])) * s1;
                    if (EPI >= 2) x = (x + bf2f(R2z[idx])) * s2;
                }
                if (OUTF32) Cf[idx] = x;
                else Cb[idx] = f2bf(x);
            }
        }
    }
}

// ---------------- conv+GLU kernel: tap-dedup'd staging ----------------
// C = GLU(im2col(convinP) @ wpack^T + b). 256x256 tile, 8 waves (2Mx4N), BK=32 over H.
// Stage A once (384-row panel incl. halo) + 3 B tap-panels; acc += sum_tap shifted-A @ B_tap.
// Coarse 2-barrier loop with counted vmcnt(9).
__global__ __launch_bounds__(512) void conv_glu_kernel(
    const __hip_bfloat16* __restrict__ Ain,   // convinP [16][514][1024]
    const __hip_bfloat16* __restrict__ Bw,    // wpack [2048][3072]
    const float* __restrict__ bias, __hip_bfloat16* __restrict__ Cout,
    const __hip_bfloat16* __restrict__ padrow) {
    __shared__ alignas(16) short As[2][384 * 32];      // 48 KB
    __shared__ alignas(16) short Bs[2][3 * 256 * 32];  // 96 KB
    const int tid = threadIdx.x;
    const int lane = tid & 63;
    const int wid = tid >> 6;
    const int wr = wid >> 2, wc = wid & 3;
    const int nwg = gridDim.x * gridDim.y;   // 256
    const int orig = blockIdx.y * gridDim.x + blockIdx.x;
    const int qd = nwg >> 3, rd = nwg & 7, xc = orig & 7, loc = orig >> 3;
    const int bid = (xc < rd ? xc * (qd + 1) : rd * (qd + 1) + (xc - rd) * qd) + loc;
    const int n0 = (bid % gridDim.x) * 256, m0 = (bid / gridDim.x) * 256;
    const short* Ag = (const short*)Ain;
    const short* Bg = (const short*)Bw;
    const short* pad = (const short*)padrow;
    const int p0 = (m0 >> 9) * TP + 2 + (m0 & 511);   // padded-space base row

    f32x4 acc[8][4] = {};

    const int srow = tid >> 2;                  // row within 128-row staging round
    const int skey = (tid >> 3) & 3;            // (row>>1)&3 (round base = 0 mod 8)
    const int scol = ((tid & 3) ^ skey) * 8;    // inverse-swizzled global col (elems)
    const int sdst = tid * 8;                   // linear LDS elems per round

    auto stageA = [&](int buf, int kt) {
        const int k0 = kt * 32;
#pragma unroll
        for (int j = 0; j < 3; ++j) {           // 384 rows = 3 rounds
            int prow = p0 - 128 + j * 128 + srow;
            const short* src = (prow >= 0) ? (Ag + (long)prow * Hn + k0 + scol) : (pad + scol);
            gload_lds16(src, &As[buf][j * 4096 + sdst]);
        }
    };
    auto stageB = [&](int buf, int kt) {
        const int k0 = kt * 32;
#pragma unroll
        for (int tap = 0; tap < 3; ++tap)
#pragma unroll
            for (int j = 0; j < 2; ++j) {       // 256 rows = 2 rounds per tap
                int row = j * 128 + srow;
                const short* src = Bg + (long)(n0 + row) * 3072 + tap * 1024 + k0 + scol;
                gload_lds16(src, &Bs[buf][tap * 8192 + j * 4096 + sdst]);
            }
    };

    const int rsel = lane & 15, hi = (lane >> 4) * 8;

    stageA(0, 0); stageB(0, 0);                 // 9 loads/thread in flight
    for (int t = 0; t < 32; ++t) {
        const int cur = t & 1;
        if (t + 1 < 32) {
            stageA(cur ^ 1, t + 1); stageB(cur ^ 1, t + 1);
            asm volatile("s_waitcnt vmcnt(9)" ::: "memory");   // tile t's 9 loads done
        } else {
            asm volatile("s_waitcnt vmcnt(0)" ::: "memory");
        }
        __builtin_amdgcn_s_barrier();
        __builtin_amdgcn_sched_barrier(0);
#pragma unroll
        for (int tap = 0; tap < 3; ++tap) {
            short8 bg[4];
#pragma unroll
            for (int ni = 0; ni < 4; ++ni) {
                int row = wc * 64 + ni * 16 + rsel;
                int xk = ((row >> 1) & 3) << 3;
                bg[ni] = *(const short8*)&Bs[cur][tap * 8192 + row * 32 + (hi ^ xk)];
            }
#pragma unroll
            for (int mh = 0; mh < 2; ++mh) {
                short8 af[4];
#pragma unroll
                for (int i = 0; i < 4; ++i) {
                    int row = 126 + tap + wr * 128 + mh * 64 + i * 16 + rsel;  // tap shift
                    int xk = ((row >> 1) & 3) << 3;
                    af[i] = *(const short8*)&As[cur][row * 32 + (hi ^ xk)];
                }
                __builtin_amdgcn_s_setprio(1);
#pragma unroll
                for (int i = 0; i < 4; ++i)
#pragma unroll
                    for (int ni = 0; ni < 4; ++ni)
                        acc[mh * 4 + i][ni] = __builtin_amdgcn_mfma_f32_16x16x32_bf16(
                            af[i], bg[ni], acc[mh * 4 + i][ni], 0, 0, 0);
                __builtin_amdgcn_s_setprio(0);
                __builtin_amdgcn_sched_barrier(0);
            }
        }
        __builtin_amdgcn_s_barrier();
        __builtin_amdgcn_sched_barrier(0);
    }

    // fused GLU epilogue: ni pairs (0,1) and (2,3) are (a,g) of the same 32-col group
    const int rg = (lane >> 4) * 4;
    const int No = Hn;
#pragma unroll
    for (int p = 0; p < 2; ++p) {
        int jcol = ((n0 + wc * 64) >> 1) + p * 16 + rsel;
        float ba = bias[jcol];
        float bgv = bias[Hn + jcol];
#pragma unroll
        for (int mi = 0; mi < 8; ++mi) {
            int row = m0 + wr * 128 + mi * 16 + rg;
            f32x4 va = acc[mi][2 * p], vg = acc[mi][2 * p + 1];
#pragma unroll
            for (int q = 0; q < 4; ++q) {
                float a = va[q] + ba;
                float g = vg[q] + bgv;
                Cout[(long)(row + q) * No + jcol] = f2bf(a * (1.f / (1.f + __expf(-g))));
            }
        }
    }
}

// ---------------- 256x256 coarse deep-pipeline GEMM (fc_out) ----------------
template <bool OUTF32, bool NBOUND>
__global__ __launch_bounds__(512) void gemm256(
    const __hip_bfloat16* __restrict__ A, const __hip_bfloat16* __restrict__ Bw,
    const float* __restrict__ bias, void* __restrict__ Cout,
    const __hip_bfloat16* __restrict__ padrow, int M, int N, int K) {
    __shared__ alignas(16) short As[2][256 * 64];
    __shared__ alignas(16) short Bs[2][256 * 64];
    const int tid = threadIdx.x;
    const int lane = tid & 63;
    const int wid = tid >> 6;
    const int wr = wid >> 2, wc = wid & 3;
    const int nwg = gridDim.x * gridDim.y;
    const int orig = blockIdx.y * gridDim.x + blockIdx.x;
    const int qd = nwg >> 3, rd = nwg & 7, xc = orig & 7, loc = orig >> 3;
    const int bid = (xc < rd ? xc * (qd + 1) : rd * (qd + 1) + (xc - rd) * qd) + loc;
    const int n0 = (bid % gridDim.x) * 256, m0 = (bid / gridDim.x) * 256;
    const short* Ag = (const short*)A;
    const short* Bg = (const short*)Bw;
    const short* pad = (const short*)padrow;

    f32x4 acc[8][4] = {};

    const int srow_l = tid >> 3;
    const int scol = ((tid & 7) ^ (srow_l & 7)) * 8;
    const int sdst = (tid >> 3) * 64 + (tid & 7) * 8;

    auto stage = [&](int buf, int kt) {
        const int k0 = kt * 64;
#pragma unroll
        for (int j = 0; j < 4; ++j) {
            const int row = j * 64 + srow_l;
            const short* asrc = Ag + (long)(m0 + row) * K + k0 + scol;
            gload_lds16(asrc, &As[buf][j * 4096 + sdst]);
            int n = n0 + row;
            const short* bsrc = (NBOUND && n >= N) ? (pad + scol) : (Bg + (long)n * K + k0 + scol);
            gload_lds16(bsrc, &Bs[buf][j * 4096 + sdst]);
        }
    };

    const int rsel = lane & 15, hi = (lane >> 4) * 8;
    const int xorc = (rsel & 7) << 3;

    stage(0, 0);
    const int NT = K >> 6;
    for (int t = 0; t < NT; ++t) {
        const int cur = t & 1;
        if (t + 1 < NT) {
            stage(cur ^ 1, t + 1);
            asm volatile("s_waitcnt vmcnt(8)" ::: "memory");
        } else {
            asm volatile("s_waitcnt vmcnt(0)" ::: "memory");
        }
        __builtin_amdgcn_s_barrier();
        __builtin_amdgcn_sched_barrier(0);
        short8 bg[2][2][2];
#pragma unroll
        for (int nh = 0; nh < 2; ++nh)
#pragma unroll
            for (int i = 0; i < 2; ++i) {
                const int row = wc * 64 + nh * 32 + i * 16 + rsel;
#pragma unroll
                for (int ks = 0; ks < 2; ++ks)
                    bg[nh][i][ks] = *(const short8*)&Bs[cur][row * 64 + ((ks * 32 + hi) ^ xorc)];
            }
#pragma unroll
        for (int mh = 0; mh < 2; ++mh) {
            short8 af[4][2];
#pragma unroll
            for (int i = 0; i < 4; ++i) {
                const int row = wr * 128 + mh * 64 + i * 16 + rsel;
#pragma unroll
                for (int ks = 0; ks < 2; ++ks)
                    af[i][ks] = *(const short8*)&As[cur][row * 64 + ((ks * 32 + hi) ^ xorc)];
            }
            __builtin_amdgcn_s_setprio(1);
#pragma unroll
            for (int nh = 0; nh < 2; ++nh)
#pragma unroll
                for (int i = 0; i < 4; ++i)
#pragma unroll
                    for (int jn = 0; jn < 2; ++jn)
#pragma unroll
                        for (int ks = 0; ks < 2; ++ks)
                            acc[mh * 4 + i][nh * 2 + jn] = __builtin_amdgcn_mfma_f32_16x16x32_bf16(
                                af[i][ks], bg[nh][jn][ks], acc[mh * 4 + i][nh * 2 + jn], 0, 0, 0);
            __builtin_amdgcn_s_setprio(0);
            __builtin_amdgcn_sched_barrier(0);
        }
        __builtin_amdgcn_s_barrier();
        __builtin_amdgcn_sched_barrier(0);
    }

    const int rg = (lane >> 4) * 4;
    float* Cf = (float*)Cout;
    __hip_bfloat16* Cb = (__hip_bfloat16*)Cout;
#pragma unroll
    for (int ni = 0; ni < 4; ++ni) {
        int col = n0 + wc * 64 + ni * 16 + rsel;
        if (NBOUND && col >= N) continue;
        float bi = bias ? bias[col] : 0.f;
#pragma unroll
        for (int mi = 0; mi < 8; ++mi) {
            int row = m0 + wr * 128 + mi * 16 + rg;
            f32x4 v = acc[mi][ni];
#pragma unroll
            for (int q = 0; q < 4; ++q) {
                long idx = (long)(row + q) * N + col;
                float x = v[q] + bi;
                if (OUTF32) Cf[idx] = x;
                else Cb[idx] = f2bf(x);
            }
        }
    }
}

// ---------------- launcher ----------------

extern "C" void kernel_launch(void* const* d_in, const int* in_sizes, int n_in,
                              void* d_out, int out_size, void* d_ws, size_t ws_size,
                              hipStream_t stream) {
    const int* tgt = (const int*)d_in[0];
    const float* enc_conved = (const float*)d_in[1];
    const float* enc_combined = (const float*)d_in[2];
    const float* tok_emb = (const float*)d_in[3];
    const float* pos_emb = (const float*)d_in[4];
    const float* w_e2h = (const float*)d_in[5];
    const float* b_e2h = (const float*)d_in[6];
    const float* w_h2e = (const float*)d_in[7];
    const float* b_h2e = (const float*)d_in[8];
    const float* w_ah2e = (const float*)d_in[9];
    const float* b_ah2e = (const float*)d_in[10];
    const float* w_ae2h = (const float*)d_in[11];
    const float* b_ae2h = (const float*)d_in[12];
    const float* w_fc = (const float*)d_in[13];
    const float* b_fc = (const float*)d_in[14];
    const float* conv_w = (const float*)d_in[15];
    const float* conv_b = (const float*)d_in[16];

    char* ws = (char*)d_ws;
    size_t off = 0;
    auto alloc = [&](size_t bytes) { size_t r = off; off = (off + bytes + 255) & ~(size_t)255; return r; };
    __hip_bfloat16* emb    = (__hip_bfloat16*)(ws + alloc((size_t)Mn * En * 2));
    __hip_bfloat16* embA   = (__hip_bfloat16*)(ws + alloc((size_t)Mn * En * 2));
    __hip_bfloat16* convinP= (__hip_bfloat16*)(ws + alloc((size_t)Bn * TP * Hn * 2));  // padded
    __hip_bfloat16* conved = (__hip_bfloat16*)(ws + alloc((size_t)Mn * Hn * 2));
    size_t o_en = alloc((size_t)Mn * Sn * 4);
    float* energy = (float*)(ws + o_en);
    __hip_bfloat16* encm = (__hip_bfloat16*)(ws + o_en);   // overlay: prep-only bf16(enc_combined)
    __hip_bfloat16* attnbf = (__hip_bfloat16*)(ws + alloc((size_t)Mn * Sn * 2));
    __hip_bfloat16* wT_e2h = (__hip_bfloat16*)(ws + alloc((size_t)Hn * En * 2));
    __hip_bfloat16* wT_h2e = (__hip_bfloat16*)(ws + alloc((size_t)En * Hn * 2));
    __hip_bfloat16* wT_ae2h= (__hip_bfloat16*)(ws + alloc((size_t)Hn * En * 2));
    __hip_bfloat16* wbAH   = (__hip_bfloat16*)(ws + alloc((size_t)Hn * En * 2));
    __hip_bfloat16* wT_fc  = (__hip_bfloat16*)(ws + alloc((size_t)Vn * En * 2));
    __hip_bfloat16* encc   = (__hip_bfloat16*)(ws + alloc((size_t)Bn * Sn * En * 2));
    __hip_bfloat16* encAH  = (__hip_bfloat16*)(ws + alloc((size_t)Bn * Sn * Hn * 2));
    __hip_bfloat16* encCW  = (__hip_bfloat16*)(ws + alloc((size_t)Bn * Hn * Sn * 2));
    float* embE            = (float*)(ws + alloc((size_t)Mn * Sn * 4));
    __hip_bfloat16* padrow = (__hip_bfloat16*)(ws + alloc(256));
    __hip_bfloat16* wpack  = (__hip_bfloat16*)(ws + alloc((size_t)2 * Hn * 3 * Hn * 2)); // per-layer, warm
    __hip_bfloat16* tmpE = conved;  // overlay: conved dead after last update GEMM
    __hip_bfloat16* convinD = convinP + 2 * Hn;   // data rows base (skip 2 pads of batch 0)

    float* out = (float*)d_out;
    float* attn_out = out + (long)Mn * Vn;
    const long bSq = (long)Sn * Sn;
    const long bSH = (long)Sn * Hn;
    const long bTH = (long)Tn * Hn;
    const long bPH = (long)TP * Hn;   // padded per-batch stride

    dim3 tb(32, 8);
    const __hip_bfloat16* nb = nullptr;
    const float* nf = nullptr;

    // ---- prep ----
    padfill_kernel<<<1, 128, 0, stream>>>(padrow);
    padrows_kernel<<<2 * Bn, 256, 0, stream>>>(convinP);
    embed_kernel<<<Mn, 128, 0, stream>>>(tgt, tok_emb, pos_emb, b_ah2e, emb, embA);
    transpose_f32_bf16<<<dim3(Hn / 32, En / 32, 1), tb, 0, stream>>>(w_e2h, wT_e2h, En, Hn, 0, 0);
    transpose_f32_bf16<<<dim3(En / 32, Hn / 32, 1), tb, 0, stream>>>(w_h2e, wT_h2e, Hn, En, 0, 0);
    transpose_f32_bf16<<<dim3(Hn / 32, En / 32, 1), tb, 0, stream>>>(w_ae2h, wT_ae2h, En, Hn, 0, 0);
    transpose_f32_bf16<<<dim3((Vn + 31) / 32, En / 32, 1), tb, 0, stream>>>(w_fc, wT_fc, En, Vn, 0, 0);
    convert_bf16_kernel<<<((long)Hn * En / 4 + 255) / 256, 256, 0, stream>>>(w_ah2e, wbAH, (long)Hn * En / 4);
    convert_bf16_kernel<<<((long)Bn * Sn * En / 4 + 255) / 256, 256, 0, stream>>>(enc_conved, encc, (long)Bn * Sn * En / 4);
    convert_bf16_kernel<<<((long)Bn * Sn * En / 4 + 255) / 256, 256, 0, stream>>>(enc_combined, encm, (long)Bn * Sn * En / 4);

    // encAH[b][s][h] = encc[b] @ w_ah2e^T   (layer-invariant attention factor)
    gemm_bf16<0, false, false><<<dim3(Hn / 128, Sn / 128, Bn), 256, 0, stream>>>(
        encc, wbAH, nullptr, encAH, nb, nb, nf, padrow, Sn, Hn, En, bSq, 0, bSH, 0, 1.f, 1.f);
    // encCW[b][h][s] = (enc_combined[b] @ w_ae2h)^T
    gemm_bf16<0, false, false><<<dim3(Sn / 128, Hn / 128, Bn), 256, 0, stream>>>(
        wT_ae2h, encm, nullptr, encCW, nb, nb, nf, padrow, Hn, Sn, En, 0, bSq, bSH, 0, 1.f, 1.f);
    // embE[b][t][s] = embA[b] @ encc[b]^T   (f32; kScale folded into embA)
    gemm_bf16<0, true, false><<<dim3(Sn / 128, Tn / 128, Bn), 256, 0, stream>>>(
        embA, encc, nullptr, embE, nb, nb, nf, padrow, Tn, Sn, En, bSq, bSq, bSq, 0, 1.f, 1.f);
    // conv_input = embedded @ emb2hid + b   -> padded buffer (batched, rows +2)
    gemm_bf16<0, false, false><<<dim3(Hn / 128, Tn / 128, Bn), 256, 0, stream>>>(
        emb, wT_e2h, b_e2h, convinD, nb, nb, nf, padrow, Tn, Hn, En, (long)Tn * En, 0, bPH, 0, 1.f, 1.f);

    for (int l = 0; l < Ln; ++l) {
        // pack conv weight for THIS layer just before use (keeps B-panel L2/L3-warm)
        wpack2_kernel<<<2 * Hn, 256, 0, stream>>>(conv_w, wpack, l);
        // conved = GLU(conv(convinP) + conv_b[l])   [8192,1024], tap-dedup'd staging
        conv_glu_kernel<<<dim3(2 * Hn / 256, Mn / 256), 512, 0, stream>>>(
            convinP, wpack, conv_b + (long)l * 2 * Hn, conved, padrow);
        // energy[b] = kScale * conved[b] @ encAH[b]^T + embE[b]   (f32)
        gemm_bf16<3, true, false><<<dim3(Sn / 128, Tn / 128, Bn), 256, 0, stream>>>(
            conved, encAH, nullptr, energy, nb, nb, embE, padrow,
            Tn, Sn, Hn, bTH, bSH, bSq, bSq, kScale, 1.f);
        // attention = softmax(energy)  (f32 out only needed from the LAST layer)
        softmax_kernel<<<Mn, 256, 0, stream>>>(energy, (l == Ln - 1) ? attn_out : nullptr, attnbf);
        // conv_input = ((attn @ encCW + b_ae2h + conved)*s + conv_input)*s  (C/R2 padded)
        gemm_bf16<2, false, false><<<dim3(Hn / 128, Tn / 128, Bn), 256, 0, stream>>>(
            attnbf, encCW, b_ae2h, convinD, conved, convinD, nf, padrow,
            Tn, Hn, Sn, bSq, bSH, bPH, bTH, kScale, kScale);
    }

    // conved = conv_input @ hid2emb + b   [8192,512]  (A padded, batched; tmpE overlays conved)
    gemm_bf16<0, false, false><<<dim3(En / 128, Tn / 128, Bn), 256, 0, stream>>>(
        convinD, wT_h2e, b_h2e, tmpE, nb, nb, nf, padrow, Tn, En, Hn, bPH, 0, (long)Tn * En, 0, 1.f, 1.f);
    // output = conved @ fc_out + b        [8192,10000] f32, N-bounded  (256² coarse)
    gemm256<true, true><<<dim3((Vn + 255) / 256, Mn / 256), 512, 0, stream>>>(
        tmpE, wT_fc, b_fc, out, padrow, Mn, Vn, En);
}

// Round 13
// 1254.664 us; speedup vs baseline: 1.1584x; 1.0348x over previous
//
#include <hip/hip_runtime.h>
#include <hip/hip_bf16.h>

typedef __attribute__((ext_vector_type(4))) float f32x4;
typedef __attribute__((ext_vector_type(8))) short short8;

#define DEVFN __device__ __forceinline__

static constexpr int Bn = 16, Tn = 512, Sn = 512, Vn = 10000, En = 512, Hn = 1024, Ln = 6;
static constexpr int Mn = Bn * Tn;  // 8192 token rows
static constexpr int TP = Tn + 2;   // padded sequence rows (2 causal PAD rows)
static constexpr float kScale = 0.70710678118654752440f;

DEVFN float bf2f(__hip_bfloat16 x) { return __bfloat162float(x); }
DEVFN __hip_bfloat16 f2bf(float x) { return __float2bfloat16(x); }

struct bf16x4 { __hip_bfloat16 x, y, z, w; };

// async global -> LDS, 16B per lane (wave-uniform LDS base + lane*16 layout)
DEVFN void gload_lds16(const short* g, short* l) {
    __builtin_amdgcn_global_load_lds((const __attribute__((address_space(1))) void*)g,
                                     (__attribute__((address_space(3))) void*)l, 16, 0, 0);
}

// ---------------- small prep kernels ----------------

__global__ void padfill_kernel(__hip_bfloat16* p) {
    p[threadIdx.x] = f2bf(1.0f);  // PAD_VAL as float, per torch code
}

// fill the 2 causal PAD rows of each padded sequence in convinP with 1.0
__global__ void padrows_kernel(__hip_bfloat16* convinP) {
    int row = blockIdx.x;                 // 0..31: (b, which)
    long base = ((long)(row >> 1) * TP + (row & 1)) * Hn;
    int e = threadIdx.x * 4;              // 256 threads x 4 = 1024
    bf16x4 v{f2bf(1.f), f2bf(1.f), f2bf(1.f), f2bf(1.f)};
    *(bf16x4*)(convinP + base + e) = v;
}

// embedded[b,t,:] = tok_emb[tgt[b,t],:] + pos_emb[t,:]  (bf16)
// embA = kScale*(embedded + b_ah2e)                      (bf16, for embE precompute)
__global__ void embed_kernel(const int* __restrict__ tgt, const float* __restrict__ tok,
                             const float* __restrict__ pos, const float* __restrict__ bah,
                             __hip_bfloat16* __restrict__ out, __hip_bfloat16* __restrict__ outA) {
    int row = blockIdx.x;              // 0..8191
    int t = row & (Tn - 1);
    int v = tgt[row];
    const float* tr = tok + (long)v * En;
    const float* pr = pos + (long)t * En;
    int e = threadIdx.x * 4;           // block 128 covers 512
    float4 a = *(const float4*)(tr + e);
    float4 b = *(const float4*)(pr + e);
    float4 bb = *(const float4*)(bah + e);
    bf16x4 o{f2bf(a.x + b.x), f2bf(a.y + b.y), f2bf(a.z + b.z), f2bf(a.w + b.w)};
    *(bf16x4*)(out + (long)row * En + e) = o;
    bf16x4 oa{f2bf(kScale * (a.x + b.x + bb.x)), f2bf(kScale * (a.y + b.y + bb.y)),
              f2bf(kScale * (a.z + b.z + bb.z)), f2bf(kScale * (a.w + b.w + bb.w))};
    *(bf16x4*)(outA + (long)row * En + e) = oa;
}

// dst[c][r] = bf16(src[r][c]); src is [R][C] f32. grid(ceil(C/32), ceil(R/32), Z), block(32,8)
__global__ void transpose_f32_bf16(const float* __restrict__ src, __hip_bfloat16* __restrict__ dst,
                                   int R, int C, long sZi, long sZo) {
    __shared__ float tile[32][33];
    src += (long)blockIdx.z * sZi;
    dst += (long)blockIdx.z * sZo;
    int c0 = blockIdx.x * 32, r0 = blockIdx.y * 32;
    for (int i = threadIdx.y; i < 32; i += 8) {
        int r = r0 + i, c = c0 + threadIdx.x;
        tile[i][threadIdx.x] = (r < R && c < C) ? src[(long)r * C + c] : 0.f;
    }
    __syncthreads();
    for (int i = threadIdx.y; i < 32; i += 8) {
        int c = c0 + i, r = r0 + threadIdx.x;
        if (c < C && r < R) dst[(long)c * R + r] = f2bf(tile[threadIdx.x][i]);
    }
}

// f32 -> bf16 convert (n divisible by 4)
__global__ void convert_bf16_kernel(const float* __restrict__ src, __hip_bfloat16* __restrict__ dst,
                                    long n4) {
    long i = (long)blockIdx.x * blockDim.x + threadIdx.x;
    if (i >= n4) return;
    long j = i * 4;
    float4 v = *(const float4*)(src + j);
    bf16x4 o{f2bf(v.x), f2bf(v.y), f2bf(v.z), f2bf(v.w)};
    *(bf16x4*)(dst + j) = o;
}

// Coalesced conv-weight pack for layer l, a/g interleaved in 16-col blocks for fused GLU.
__global__ __launch_bounds__(256) void wpack2_kernel(const float* __restrict__ convw,
                                                     __hip_bfloat16* __restrict__ wp, int l) {
    __shared__ float row[3 * Hn];
    int c = blockIdx.x;                        // 0..2047 packed col
    int grp = c >> 5, w = c & 31;
    int o = (w < 16) ? grp * 16 + w : Hn + grp * 16 + (w - 16);
    const float* src = convw + ((long)(l * 2 * Hn + o)) * (Hn * 3);
#pragma unroll
    for (int j = 0; j < 3; ++j) {
        int idx = (j * 256 + threadIdx.x) * 4;
        *(float4*)&row[idx] = *(const float4*)(src + idx);
    }
    __syncthreads();
    __hip_bfloat16* dst = wp + (long)c * (3 * Hn);
#pragma unroll
    for (int j = 0; j < 3; ++j) {
        int kk = (j * 256 + threadIdx.x) * 4;   // 4-chunk never crosses a tap boundary
        int tap = kk >> 10;
        int i = kk & (Hn - 1);
        bf16x4 v{f2bf(row[i * 3 + tap]), f2bf(row[(i + 1) * 3 + tap]),
                 f2bf(row[(i + 2) * 3 + tap]), f2bf(row[(i + 3) * 3 + tap])};
        *(bf16x4*)(dst + kk) = v;
    }
}

// row softmax over S=512; writes bf16 (next GEMM input) + optional f32 (final attention)
__global__ __launch_bounds__(256) void softmax_kernel(const float* __restrict__ energy,
                                                      float* __restrict__ attn_f32,
                                                      __hip_bfloat16* __restrict__ attn_bf) {
    int row = blockIdx.x;  // 0..8191
    const float* e = energy + (long)row * Sn;
    int tid = threadIdx.x;
    float v0 = e[tid], v1 = e[tid + 256];
    float m = fmaxf(v0, v1);
    for (int off = 32; off; off >>= 1) m = fmaxf(m, __shfl_xor(m, off));
    __shared__ float redm[4];
    __shared__ float reds[4];
    int lane = tid & 63, w = tid >> 6;
    if (lane == 0) redm[w] = m;
    __syncthreads();
    m = fmaxf(fmaxf(redm[0], redm[1]), fmaxf(redm[2], redm[3]));
    float x0 = __expf(v0 - m), x1 = __expf(v1 - m);
    float s = x0 + x1;
    for (int off = 32; off; off >>= 1) s += __shfl_xor(s, off);
    if (lane == 0) reds[w] = s;
    __syncthreads();
    s = reds[0] + reds[1] + reds[2] + reds[3];
    float inv = 1.f / s;
    long base = (long)row * Sn;
    if (attn_f32) {
        attn_f32[base + tid] = x0 * inv;
        attn_f32[base + tid + 256] = x1 * inv;
    }
    attn_bf[base + tid] = f2bf(x0 * inv);
    attn_bf[base + tid + 256] = f2bf(x1 * inv);
}

// ---------------- 128x128 counted-vmcnt GEMM ----------------
// C[M,N] = A[M,K] @ Bw[N,K]^T. Per K-tile {stage(nxt); vmcnt(4); s_barrier;
// frags+MFMA; s_barrier}. EPI: 0: x=acc+bias; 2: x=((acc+bias+R1)*s1+R2)*s2;
// 3: x=acc*s1+R1f[idx].
template <int EPI, bool OUTF32, bool NBOUND>
__global__ __launch_bounds__(256) void gemm_bf16(
    const __hip_bfloat16* __restrict__ A, const __hip_bfloat16* __restrict__ Bw,
    const float* __restrict__ bias, void* __restrict__ Cout,
    const __hip_bfloat16* __restrict__ R1, const __hip_bfloat16* __restrict__ R2,
    const float* __restrict__ R1f, const __hip_bfloat16* __restrict__ padrow,
    int M, int N, int K, long aZ, long bZ, long cZ, long r1Z, float s1, float s2) {
    __shared__ alignas(16) short As[2][128 * 32];
    __shared__ alignas(16) short Bs[2][128 * 32];
    const int tid = threadIdx.x;
    const int lane = tid & 63;
    const int wid = tid >> 6;
    const int wr = wid >> 1, wc = wid & 1;
    const int m0 = blockIdx.y * 128, n0 = blockIdx.x * 128;
    const short* Ag = (const short*)A + (long)blockIdx.z * aZ;
    const short* Bg = (const short*)Bw + (long)blockIdx.z * bZ;
    const short* pad = (const short*)padrow;

    f32x4 acc[4][4] = {};

    const int rc = tid >> 2;
    const int k8 = (tid & 3) * 8;

    auto stage = [&](int buf, int k0) {
#pragma unroll
        for (int j = 0; j < 2; ++j) {
            int r = rc + j * 64;
            const short* asrc = Ag + (long)(m0 + r) * K + k0 + k8;
            gload_lds16(asrc, &As[buf][r * 32 + k8]);
            int n = n0 + r;
            const short* bsrc = (NBOUND && n >= N) ? (pad + k8) : (Bg + (long)n * K + k0 + k8);
            gload_lds16(bsrc, &Bs[buf][r * 32 + k8]);
        }
    };

    const int rsel = lane & 15, hi = (lane >> 4) * 8;

    stage(0, 0);
    const int NT = K >> 5;
    for (int t = 0; t < NT; ++t) {
        const int cur = t & 1;
        if (t + 1 < NT) {
            stage(cur ^ 1, (t + 1) * 32);                       // 4 loads, stay in flight
            asm volatile("s_waitcnt vmcnt(4)" ::: "memory");    // tile t's 4 loads done
        } else {
            asm volatile("s_waitcnt vmcnt(0)" ::: "memory");
        }
        __builtin_amdgcn_s_barrier();                           // tile t visible to all waves
        __builtin_amdgcn_sched_barrier(0);
        short8 af[4], bg[4];
#pragma unroll
        for (int mi = 0; mi < 4; ++mi)
            af[mi] = *(const short8*)&As[cur][(wr * 64 + mi * 16 + rsel) * 32 + hi];
#pragma unroll
        for (int ni = 0; ni < 4; ++ni)
            bg[ni] = *(const short8*)&Bs[cur][(wc * 64 + ni * 16 + rsel) * 32 + hi];
        __builtin_amdgcn_s_setprio(1);
#pragma unroll
        for (int mi = 0; mi < 4; ++mi)
#pragma unroll
            for (int ni = 0; ni < 4; ++ni)
                acc[mi][ni] = __builtin_amdgcn_mfma_f32_16x16x32_bf16(af[mi], bg[ni], acc[mi][ni], 0, 0, 0);
        __builtin_amdgcn_s_setprio(0);
        __builtin_amdgcn_s_barrier();                           // reads of cur done before reuse
        __builtin_amdgcn_sched_barrier(0);
    }

    const int rg = (lane >> 4) * 4;
    float* Cf = (float*)Cout + (long)blockIdx.z * cZ;
    __hip_bfloat16* Cb = (__hip_bfloat16*)Cout + (long)blockIdx.z * cZ;
    const __hip_bfloat16* R1z = R1 + (long)blockIdx.z * r1Z;
    const __hip_bfloat16* R2z = R2 + (long)blockIdx.z * cZ;
    const float* R1fz = R1f + (long)blockIdx.z * r1Z;
#pragma unroll
    for (int ni = 0; ni < 4; ++ni) {
        int col = n0 + wc * 64 + ni * 16 + rsel;
        if (NBOUND && col >= N) continue;
        float bi = (EPI != 3 && bias) ? bias[col] : 0.f;
#pragma unroll
        for (int mi = 0; mi < 4; ++mi) {
            int row = m0 + wr * 64 + mi * 16 + rg;
            f32x4 v = acc[mi][ni];
#pragma unroll
            for (int q = 0; q < 4; ++q) {
                long idx = (long)(row + q) * N + col;
                float x;
                if (EPI == 3) x = v[q] * s1 + R1fz[idx];
                else {
                    x = v[q] + bi;
                    if (EPI >= 1) x = (x + bf2f(R1z[idx])) * s1;
                    if (EPI >= 2) x = (x + bf2f(R2z[idx])) * s2;
                }
                if (OUTF32) Cf[idx] = x;
                else Cb[idx] = f2bf(x);
            }
        }
    }
}

// ---------------- conv+GLU kernel: tap-dedup'd staging ----------------
// C = GLU(im2col(convinP) @ wpack^T + b). 256x256 tile, 8 waves (2Mx4N), BK=32 over H.
// Stage A once (384-row panel incl. halo) + 3 B tap-panels; acc += sum_tap shifted-A @ B_tap.
// Coarse 2-barrier loop with counted vmcnt(9).
// NO XCD swizzle: natural order gives XCD = linear_id % 8 = n_blk (gridDim.x == 8),
// so each XCD's 32 concurrent CUs share ONE 1.5 MB wpack slice -> L2-resident B.
__global__ __launch_bounds__(512) void conv_glu_kernel(
    const __hip_bfloat16* __restrict__ Ain,   // convinP [16][514][1024]
    const __hip_bfloat16* __restrict__ Bw,    // wpack [2048][3072]
    const float* __restrict__ bias, __hip_bfloat16* __restrict__ Cout,
    const __hip_bfloat16* __restrict__ padrow) {
    __shared__ alignas(16) short As[2][384 * 32];      // 48 KB
    __shared__ alignas(16) short Bs[2][3 * 256 * 32];  // 96 KB
    const int tid = threadIdx.x;
    const int lane = tid & 63;
    const int wid = tid >> 6;
    const int wr = wid >> 2, wc = wid & 3;
    const int n0 = blockIdx.x * 256, m0 = blockIdx.y * 256;   // natural order (B L2-locality)
    const short* Ag = (const short*)Ain;
    const short* Bg = (const short*)Bw;
    const short* pad = (const short*)padrow;
    const int p0 = (m0 >> 9) * TP + 2 + (m0 & 511);   // padded-space base row

    f32x4 acc[8][4] = {};

    const int srow = tid >> 2;                  // row within 128-row staging round
    const int skey = (tid >> 3) & 3;            // (row>>1)&3 (round base = 0 mod 8)
    const int scol = ((tid & 3) ^ skey) * 8;    // inverse-swizzled global col (elems)
    const int sdst = tid * 8;                   // linear LDS elems per round

    auto stageA = [&](int buf, int kt) {
        const int k0 = kt * 32;
#pragma unroll
        for (int j = 0; j < 3; ++j) {           // 384 rows = 3 rounds
            int prow = p0 - 128 + j * 128 + srow;
            const short* src = (prow >= 0) ? (Ag + (long)prow * Hn + k0 + scol) : (pad + scol);
            gload_lds16(src, &As[buf][j * 4096 + sdst]);
        }
    };
    auto stageB = [&](int buf, int kt) {
        const int k0 = kt * 32;
#pragma unroll
        for (int tap = 0; tap < 3; ++tap)
#pragma unroll
            for (int j = 0; j < 2; ++j) {       // 256 rows = 2 rounds per tap
                int row = j * 128 + srow;
                const short* src = Bg + (long)(n0 + row) * 3072 + tap * 1024 + k0 + scol;
                gload_lds16(src, &Bs[buf][tap * 8192 + j * 4096 + sdst]);
            }
    };

    const int rsel = lane & 15, hi = (lane >> 4) * 8;

    stageA(0, 0); stageB(0, 0);                 // 9 loads/thread in flight
    for (int t = 0; t < 32; ++t) {
        const int cur = t & 1;
        if (t + 1 < 32) {
            stageA(cur ^ 1, t + 1); stageB(cur ^ 1, t + 1);
            asm volatile("s_waitcnt vmcnt(9)" ::: "memory");   // tile t's 9 loads done
        } else {
            asm volatile("s_waitcnt vmcnt(0)" ::: "memory");
        }
        __builtin_amdgcn_s_barrier();
        __builtin_amdgcn_sched_barrier(0);
#pragma unroll
        for (int tap = 0; tap < 3; ++tap) {
            short8 bg[4];
#pragma unroll
            for (int ni = 0; ni < 4; ++ni) {
                int row = wc * 64 + ni * 16 + rsel;
                int xk = ((row >> 1) & 3) << 3;
                bg[ni] = *(const short8*)&Bs[cur][tap * 8192 + row * 32 + (hi ^ xk)];
            }
#pragma unroll
            for (int mh = 0; mh < 2; ++mh) {
                short8 af[4];
#pragma unroll
                for (int i = 0; i < 4; ++i) {
                    int row = 126 + tap + wr * 128 + mh * 64 + i * 16 + rsel;  // tap shift
                    int xk = ((row >> 1) & 3) << 3;
                    af[i] = *(const short8*)&As[cur][row * 32 + (hi ^ xk)];
                }
                __builtin_amdgcn_s_setprio(1);
#pragma unroll
                for (int i = 0; i < 4; ++i)
#pragma unroll
                    for (int ni = 0; ni < 4; ++ni)
                        acc[mh * 4 + i][ni] = __builtin_amdgcn_mfma_f32_16x16x32_bf16(
                            af[i], bg[ni], acc[mh * 4 + i][ni], 0, 0, 0);
                __builtin_amdgcn_s_setprio(0);
                __builtin_amdgcn_sched_barrier(0);
            }
        }
        __builtin_amdgcn_s_barrier();
        __builtin_amdgcn_sched_barrier(0);
    }

    // fused GLU epilogue: ni pairs (0,1) and (2,3) are (a,g) of the same 32-col group
    const int rg = (lane >> 4) * 4;
    const int No = Hn;
#pragma unroll
    for (int p = 0; p < 2; ++p) {
        int jcol = ((n0 + wc * 64) >> 1) + p * 16 + rsel;
        float ba = bias[jcol];
        float bgv = bias[Hn + jcol];
#pragma unroll
        for (int mi = 0; mi < 8; ++mi) {
            int row = m0 + wr * 128 + mi * 16 + rg;
            f32x4 va = acc[mi][2 * p], vg = acc[mi][2 * p + 1];
#pragma unroll
            for (int q = 0; q < 4; ++q) {
                float a = va[q] + ba;
                float g = vg[q] + bgv;
                Cout[(long)(row + q) * No + jcol] = f2bf(a * (1.f / (1.f + __expf(-g))));
            }
        }
    }
}

// ---------------- 256x256 coarse deep-pipeline GEMM (fc_out) ----------------
// NO XCD swizzle: gridDim.x = 40 (40%8==0) -> natural XCD = n_blk%8, B-slice 1.3 MB L2-fit.
template <bool OUTF32, bool NBOUND>
__global__ __launch_bounds__(512) void gemm256(
    const __hip_bfloat16* __restrict__ A, const __hip_bfloat16* __restrict__ Bw,
    const float* __restrict__ bias, void* __restrict__ Cout,
    const __hip_bfloat16* __restrict__ padrow, int M, int N, int K) {
    __shared__ alignas(16) short As[2][256 * 64];
    __shared__ alignas(16) short Bs[2][256 * 64];
    const int tid = threadIdx.x;
    const int lane = tid & 63;
    const int wid = tid >> 6;
    const int wr = wid >> 2, wc = wid & 3;
    const int n0 = blockIdx.x * 256, m0 = blockIdx.y * 256;   // natural order
    const short* Ag = (const short*)A;
    const short* Bg = (const short*)Bw;
    const short* pad = (const short*)padrow;

    f32x4 acc[8][4] = {};

    const int srow_l = tid >> 3;
    const int scol = ((tid & 7) ^ (srow_l & 7)) * 8;
    const int sdst = (tid >> 3) * 64 + (tid & 7) * 8;

    auto stage = [&](int buf, int kt) {
        const int k0 = kt * 64;
#pragma unroll
        for (int j = 0; j < 4; ++j) {
            const int row = j * 64 + srow_l;
            const short* asrc = Ag + (long)(m0 + row) * K + k0 + scol;
            gload_lds16(asrc, &As[buf][j * 4096 + sdst]);
            int n = n0 + row;
            const short* bsrc = (NBOUND && n >= N) ? (pad + scol) : (Bg + (long)n * K + k0 + scol);
            gload_lds16(bsrc, &Bs[buf][j * 4096 + sdst]);
        }
    };

    const int rsel = lane & 15, hi = (lane >> 4) * 8;
    const int xorc = (rsel & 7) << 3;

    stage(0, 0);
    const int NT = K >> 6;
    for (int t = 0; t < NT; ++t) {
        const int cur = t & 1;
        if (t + 1 < NT) {
            stage(cur ^ 1, t + 1);
            asm volatile("s_waitcnt vmcnt(8)" ::: "memory");
        } else {
            asm volatile("s_waitcnt vmcnt(0)" ::: "memory");
        }
        __builtin_amdgcn_s_barrier();
        __builtin_amdgcn_sched_barrier(0);
        short8 bg[2][2][2];
#pragma unroll
        for (int nh = 0; nh < 2; ++nh)
#pragma unroll
            for (int i = 0; i < 2; ++i) {
                const int row = wc * 64 + nh * 32 + i * 16 + rsel;
#pragma unroll
                for (int ks = 0; ks < 2; ++ks)
                    bg[nh][i][ks] = *(const short8*)&Bs[cur][row * 64 + ((ks * 32 + hi) ^ xorc)];
            }
#pragma unroll
        for (int mh = 0; mh < 2; ++mh) {
            short8 af[4][2];
#pragma unroll
            for (int i = 0; i < 4; ++i) {
                const int row = wr * 128 + mh * 64 + i * 16 + rsel;
#pragma unroll
                for (int ks = 0; ks < 2; ++ks)
                    af[i][ks] = *(const short8*)&As[cur][row * 64 + ((ks * 32 + hi) ^ xorc)];
            }
            __builtin_amdgcn_s_setprio(1);
#pragma unroll
            for (int nh = 0; nh < 2; ++nh)
#pragma unroll
                for (int i = 0; i < 4; ++i)
#pragma unroll
                    for (int jn = 0; jn < 2; ++jn)
#pragma unroll
                        for (int ks = 0; ks < 2; ++ks)
                            acc[mh * 4 + i][nh * 2 + jn] = __builtin_amdgcn_mfma_f32_16x16x32_bf16(
                                af[i][ks], bg[nh][jn][ks], acc[mh * 4 + i][nh * 2 + jn], 0, 0, 0);
            __builtin_amdgcn_s_setprio(0);
            __builtin_amdgcn_sched_barrier(0);
        }
        __builtin_amdgcn_s_barrier();
        __builtin_amdgcn_sched_barrier(0);
    }

    const int rg = (lane >> 4) * 4;
    float* Cf = (float*)Cout;
    __hip_bfloat16* Cb = (__hip_bfloat16*)Cout;
#pragma unroll
    for (int ni = 0; ni < 4; ++ni) {
        int col = n0 + wc * 64 + ni * 16 + rsel;
        if (NBOUND && col >= N) continue;
        float bi = bias ? bias[col] : 0.f;
#pragma unroll
        for (int mi = 0; mi < 8; ++mi) {
            int row = m0 + wr * 128 + mi * 16 + rg;
            f32x4 v = acc[mi][ni];
#pragma unroll
            for (int q = 0; q < 4; ++q) {
                long idx = (long)(row + q) * N + col;
                float x = v[q] + bi;
                if (OUTF32) Cf[idx] = x;
                else Cb[idx] = f2bf(x);
            }
        }
    }
}

// ---------------- launcher ----------------

extern "C" void kernel_launch(void* const* d_in, const int* in_sizes, int n_in,
                              void* d_out, int out_size, void* d_ws, size_t ws_size,
                              hipStream_t stream) {
    const int* tgt = (const int*)d_in[0];
    const float* enc_conved = (const float*)d_in[1];
    const float* enc_combined = (const float*)d_in[2];
    const float* tok_emb = (const float*)d_in[3];
    const float* pos_emb = (const float*)d_in[4];
    const float* w_e2h = (const float*)d_in[5];
    const float* b_e2h = (const float*)d_in[6];
    const float* w_h2e = (const float*)d_in[7];
    const float* b_h2e = (const float*)d_in[8];
    const float* w_ah2e = (const float*)d_in[9];
    const float* b_ah2e = (const float*)d_in[10];
    const float* w_ae2h = (const float*)d_in[11];
    const float* b_ae2h = (const float*)d_in[12];
    const float* w_fc = (const float*)d_in[13];
    const float* b_fc = (const float*)d_in[14];
    const float* conv_w = (const float*)d_in[15];
    const float* conv_b = (const float*)d_in[16];

    char* ws = (char*)d_ws;
    size_t off = 0;
    auto alloc = [&](size_t bytes) { size_t r = off; off = (off + bytes + 255) & ~(size_t)255; return r; };
    __hip_bfloat16* emb    = (__hip_bfloat16*)(ws + alloc((size_t)Mn * En * 2));
    __hip_bfloat16* embA   = (__hip_bfloat16*)(ws + alloc((size_t)Mn * En * 2));
    __hip_bfloat16* convinP= (__hip_bfloat16*)(ws + alloc((size_t)Bn * TP * Hn * 2));  // padded
    __hip_bfloat16* conved = (__hip_bfloat16*)(ws + alloc((size_t)Mn * Hn * 2));
    size_t o_en = alloc((size_t)Mn * Sn * 4);
    float* energy = (float*)(ws + o_en);
    __hip_bfloat16* encm = (__hip_bfloat16*)(ws + o_en);   // overlay: prep-only bf16(enc_combined)
    __hip_bfloat16* attnbf = (__hip_bfloat16*)(ws + alloc((size_t)Mn * Sn * 2));
    __hip_bfloat16* wT_e2h = (__hip_bfloat16*)(ws + alloc((size_t)Hn * En * 2));
    __hip_bfloat16* wT_h2e = (__hip_bfloat16*)(ws + alloc((size_t)En * Hn * 2));
    __hip_bfloat16* wT_ae2h= (__hip_bfloat16*)(ws + alloc((size_t)Hn * En * 2));
    __hip_bfloat16* wbAH   = (__hip_bfloat16*)(ws + alloc((size_t)Hn * En * 2));
    __hip_bfloat16* wT_fc  = (__hip_bfloat16*)(ws + alloc((size_t)Vn * En * 2));
    __hip_bfloat16* encc   = (__hip_bfloat16*)(ws + alloc((size_t)Bn * Sn * En * 2));
    __hip_bfloat16* encAH  = (__hip_bfloat16*)(ws + alloc((size_t)Bn * Sn * Hn * 2));
    __hip_bfloat16* encCW  = (__hip_bfloat16*)(ws + alloc((size_t)Bn * Hn * Sn * 2));
    float* embE            = (float*)(ws + alloc((size_t)Mn * Sn * 4));
    __hip_bfloat16* padrow = (__hip_bfloat16*)(ws + alloc(256));
    __hip_bfloat16* wpack  = (__hip_bfloat16*)(ws + alloc((size_t)2 * Hn * 3 * Hn * 2)); // per-layer, warm
    __hip_bfloat16* tmpE = conved;  // overlay: conved dead after last update GEMM
    __hip_bfloat16* convinD = convinP + 2 * Hn;   // data rows base (skip 2 pads of batch 0)

    float* out = (float*)d_out;
    float* attn_out = out + (long)Mn * Vn;
    const long bSq = (long)Sn * Sn;
    const long bSH = (long)Sn * Hn;
    const long bTH = (long)Tn * Hn;
    const long bPH = (long)TP * Hn;   // padded per-batch stride

    dim3 tb(32, 8);
    const __hip_bfloat16* nb = nullptr;
    const float* nf = nullptr;

    // ---- prep ----
    padfill_kernel<<<1, 128, 0, stream>>>(padrow);
    padrows_kernel<<<2 * Bn, 256, 0, stream>>>(convinP);
    embed_kernel<<<Mn, 128, 0, stream>>>(tgt, tok_emb, pos_emb, b_ah2e, emb, embA);
    transpose_f32_bf16<<<dim3(Hn / 32, En / 32, 1), tb, 0, stream>>>(w_e2h, wT_e2h, En, Hn, 0, 0);
    transpose_f32_bf16<<<dim3(En / 32, Hn / 32, 1), tb, 0, stream>>>(w_h2e, wT_h2e, Hn, En, 0, 0);
    transpose_f32_bf16<<<dim3(Hn / 32, En / 32, 1), tb, 0, stream>>>(w_ae2h, wT_ae2h, En, Hn, 0, 0);
    transpose_f32_bf16<<<dim3((Vn + 31) / 32, En / 32, 1), tb, 0, stream>>>(w_fc, wT_fc, En, Vn, 0, 0);
    convert_bf16_kernel<<<((long)Hn * En / 4 + 255) / 256, 256, 0, stream>>>(w_ah2e, wbAH, (long)Hn * En / 4);
    convert_bf16_kernel<<<((long)Bn * Sn * En / 4 + 255) / 256, 256, 0, stream>>>(enc_conved, encc, (long)Bn * Sn * En / 4);
    convert_bf16_kernel<<<((long)Bn * Sn * En / 4 + 255) / 256, 256, 0, stream>>>(enc_combined, encm, (long)Bn * Sn * En / 4);

    // encAH[b][s][h] = encc[b] @ w_ah2e^T   (layer-invariant attention factor)
    gemm_bf16<0, false, false><<<dim3(Hn / 128, Sn / 128, Bn), 256, 0, stream>>>(
        encc, wbAH, nullptr, encAH, nb, nb, nf, padrow, Sn, Hn, En, bSq, 0, bSH, 0, 1.f, 1.f);
    // encCW[b][h][s] = (enc_combined[b] @ w_ae2h)^T
    gemm_bf16<0, false, false><<<dim3(Sn / 128, Hn / 128, Bn), 256, 0, stream>>>(
        wT_ae2h, encm, nullptr, encCW, nb, nb, nf, padrow, Hn, Sn, En, 0, bSq, bSH, 0, 1.f, 1.f);
    // embE[b][t][s] = embA[b] @ encc[b]^T   (f32; kScale folded into embA)
    gemm_bf16<0, true, false><<<dim3(Sn / 128, Tn / 128, Bn), 256, 0, stream>>>(
        embA, encc, nullptr, embE, nb, nb, nf, padrow, Tn, Sn, En, bSq, bSq, bSq, 0, 1.f, 1.f);
    // conv_input = embedded @ emb2hid + b   -> padded buffer (batched, rows +2)
    gemm_bf16<0, false, false><<<dim3(Hn / 128, Tn / 128, Bn), 256, 0, stream>>>(
        emb, wT_e2h, b_e2h, convinD, nb, nb, nf, padrow, Tn, Hn, En, (long)Tn * En, 0, bPH, 0, 1.f, 1.f);

    for (int l = 0; l < Ln; ++l) {
        // pack conv weight for THIS layer just before use (keeps B-panel L2/L3-warm)
        wpack2_kernel<<<2 * Hn, 256, 0, stream>>>(conv_w, wpack, l);
        // conved = GLU(conv(convinP) + conv_b[l])   [8192,1024], tap-dedup'd staging
        conv_glu_kernel<<<dim3(2 * Hn / 256, Mn / 256), 512, 0, stream>>>(
            convinP, wpack, conv_b + (long)l * 2 * Hn, conved, padrow);
        // energy[b] = kScale * conved[b] @ encAH[b]^T + embE[b]   (f32)
        gemm_bf16<3, true, false><<<dim3(Sn / 128, Tn / 128, Bn), 256, 0, stream>>>(
            conved, encAH, nullptr, energy, nb, nb, embE, padrow,
            Tn, Sn, Hn, bTH, bSH, bSq, bSq, kScale, 1.f);
        // attention = softmax(energy)  (f32 out only needed from the LAST layer)
        softmax_kernel<<<Mn, 256, 0, stream>>>(energy, (l == Ln - 1) ? attn_out : nullptr, attnbf);
        // conv_input = ((attn @ encCW + b_ae2h + conved)*s + conv_input)*s  (C/R2 padded)
        gemm_bf16<2, false, false><<<dim3(Hn / 128, Tn / 128, Bn), 256, 0, stream>>>(
            attnbf, encCW, b_ae2h, convinD, conved, convinD, nf, padrow,
            Tn, Hn, Sn, bSq, bSH, bPH, bTH, kScale, kScale);
    }

    // conved = conv_input @ hid2emb + b   [8192,512]  (A padded, batched; tmpE overlays conved)
    gemm_bf16<0, false, false><<<dim3(En / 128, Tn / 128, Bn), 256, 0, stream>>>(
        convinD, wT_h2e, b_h2e, tmpE, nb, nb, nf, padrow, Tn, En, Hn, bPH, 0, (long)Tn * En, 0, 1.f, 1.f);
    // output = conved @ fc_out + b        [8192,10000] f32, N-bounded  (256² coarse)
    gemm256<true, true><<<dim3((Vn + 255) / 256, Mn / 256), 512, 0, stream>>>(
        tmpE, wT_fc, b_fc, out, padrow, Mn, Vn, En);
}

// Round 14
// 1243.384 us; speedup vs baseline: 1.1689x; 1.0091x over previous
//
#include <hip/hip_runtime.h>
#include <hip/hip_bf16.h>

typedef __attribute__((ext_vector_type(4))) float f32x4;
typedef __attribute__((ext_vector_type(8))) short short8;

#define DEVFN __device__ __forceinline__

static constexpr int Bn = 16, Tn = 512, Sn = 512, Vn = 10000, En = 512, Hn = 1024, Ln = 6;
static constexpr int Mn = Bn * Tn;  // 8192 token rows
static constexpr int TP = Tn + 2;   // padded sequence rows (2 causal PAD rows)
static constexpr float kScale = 0.70710678118654752440f;

DEVFN float bf2f(__hip_bfloat16 x) { return __bfloat162float(x); }
DEVFN __hip_bfloat16 f2bf(float x) { return __float2bfloat16(x); }

struct bf16x4 { __hip_bfloat16 x, y, z, w; };

// async global -> LDS, 16B per lane (wave-uniform LDS base + lane*16 layout)
DEVFN void gload_lds16(const short* g, short* l) {
    __builtin_amdgcn_global_load_lds((const __attribute__((address_space(1))) void*)g,
                                     (__attribute__((address_space(3))) void*)l, 16, 0, 0);
}

// ---------------- small prep kernels ----------------

__global__ void padfill_kernel(__hip_bfloat16* p) {
    p[threadIdx.x] = f2bf(1.0f);  // PAD_VAL as float, per torch code
}

// fill the 2 causal PAD rows of each padded sequence in convinP with 1.0
__global__ void padrows_kernel(__hip_bfloat16* convinP) {
    int row = blockIdx.x;                 // 0..31: (b, which)
    long base = ((long)(row >> 1) * TP + (row & 1)) * Hn;
    int e = threadIdx.x * 4;              // 256 threads x 4 = 1024
    bf16x4 v{f2bf(1.f), f2bf(1.f), f2bf(1.f), f2bf(1.f)};
    *(bf16x4*)(convinP + base + e) = v;
}

// embedded[b,t,:] = tok_emb[tgt[b,t],:] + pos_emb[t,:]  (bf16)
// embA = kScale*(embedded + b_ah2e)                      (bf16, for embE precompute)
__global__ void embed_kernel(const int* __restrict__ tgt, const float* __restrict__ tok,
                             const float* __restrict__ pos, const float* __restrict__ bah,
                             __hip_bfloat16* __restrict__ out, __hip_bfloat16* __restrict__ outA) {
    int row = blockIdx.x;              // 0..8191
    int t = row & (Tn - 1);
    int v = tgt[row];
    const float* tr = tok + (long)v * En;
    const float* pr = pos + (long)t * En;
    int e = threadIdx.x * 4;           // block 128 covers 512
    float4 a = *(const float4*)(tr + e);
    float4 b = *(const float4*)(pr + e);
    float4 bb = *(const float4*)(bah + e);
    bf16x4 o{f2bf(a.x + b.x), f2bf(a.y + b.y), f2bf(a.z + b.z), f2bf(a.w + b.w)};
    *(bf16x4*)(out + (long)row * En + e) = o;
    bf16x4 oa{f2bf(kScale * (a.x + b.x + bb.x)), f2bf(kScale * (a.y + b.y + bb.y)),
              f2bf(kScale * (a.z + b.z + bb.z)), f2bf(kScale * (a.w + b.w + bb.w))};
    *(bf16x4*)(outA + (long)row * En + e) = oa;
}

// dst[c][r] = bf16(src[r][c]); src is [R][C] f32. grid(ceil(C/32), ceil(R/32), Z), block(32,8)
__global__ void transpose_f32_bf16(const float* __restrict__ src, __hip_bfloat16* __restrict__ dst,
                                   int R, int C, long sZi, long sZo) {
    __shared__ float tile[32][33];
    src += (long)blockIdx.z * sZi;
    dst += (long)blockIdx.z * sZo;
    int c0 = blockIdx.x * 32, r0 = blockIdx.y * 32;
    for (int i = threadIdx.y; i < 32; i += 8) {
        int r = r0 + i, c = c0 + threadIdx.x;
        tile[i][threadIdx.x] = (r < R && c < C) ? src[(long)r * C + c] : 0.f;
    }
    __syncthreads();
    for (int i = threadIdx.y; i < 32; i += 8) {
        int c = c0 + i, r = r0 + threadIdx.x;
        if (c < C && r < R) dst[(long)c * R + r] = f2bf(tile[threadIdx.x][i]);
    }
}

// f32 -> bf16 convert (n divisible by 4)
__global__ void convert_bf16_kernel(const float* __restrict__ src, __hip_bfloat16* __restrict__ dst,
                                    long n4) {
    long i = (long)blockIdx.x * blockDim.x + threadIdx.x;
    if (i >= n4) return;
    long j = i * 4;
    float4 v = *(const float4*)(src + j);
    bf16x4 o{f2bf(v.x), f2bf(v.y), f2bf(v.z), f2bf(v.w)};
    *(bf16x4*)(dst + j) = o;
}

// Coalesced conv-weight pack for layer l, a/g interleaved in 16-col blocks for fused GLU.
__global__ __launch_bounds__(256) void wpack2_kernel(const float* __restrict__ convw,
                                                     __hip_bfloat16* __restrict__ wp, int l) {
    __shared__ float row[3 * Hn];
    int c = blockIdx.x;                        // 0..2047 packed col
    int grp = c >> 5, w = c & 31;
    int o = (w < 16) ? grp * 16 + w : Hn + grp * 16 + (w - 16);
    const float* src = convw + ((long)(l * 2 * Hn + o)) * (Hn * 3);
#pragma unroll
    for (int j = 0; j < 3; ++j) {
        int idx = (j * 256 + threadIdx.x) * 4;
        *(float4*)&row[idx] = *(const float4*)(src + idx);
    }
    __syncthreads();
    __hip_bfloat16* dst = wp + (long)c * (3 * Hn);
#pragma unroll
    for (int j = 0; j < 3; ++j) {
        int kk = (j * 256 + threadIdx.x) * 4;   // 4-chunk never crosses a tap boundary
        int tap = kk >> 10;
        int i = kk & (Hn - 1);
        bf16x4 v{f2bf(row[i * 3 + tap]), f2bf(row[(i + 1) * 3 + tap]),
                 f2bf(row[(i + 2) * 3 + tap]), f2bf(row[(i + 3) * 3 + tap])};
        *(bf16x4*)(dst + kk) = v;
    }
}

// row softmax over S=512; writes bf16 (next GEMM input) + optional f32 (final attention)
__global__ __launch_bounds__(256) void softmax_kernel(const float* __restrict__ energy,
                                                      float* __restrict__ attn_f32,
                                                      __hip_bfloat16* __restrict__ attn_bf) {
    int row = blockIdx.x;  // 0..8191
    const float* e = energy + (long)row * Sn;
    int tid = threadIdx.x;
    float v0 = e[tid], v1 = e[tid + 256];
    float m = fmaxf(v0, v1);
    for (int off = 32; off; off >>= 1) m = fmaxf(m, __shfl_xor(m, off));
    __shared__ float redm[4];
    __shared__ float reds[4];
    int lane = tid & 63, w = tid >> 6;
    if (lane == 0) redm[w] = m;
    __syncthreads();
    m = fmaxf(fmaxf(redm[0], redm[1]), fmaxf(redm[2], redm[3]));
    float x0 = __expf(v0 - m), x1 = __expf(v1 - m);
    float s = x0 + x1;
    for (int off = 32; off; off >>= 1) s += __shfl_xor(s, off);
    if (lane == 0) reds[w] = s;
    __syncthreads();
    s = reds[0] + reds[1] + reds[2] + reds[3];
    float inv = 1.f / s;
    long base = (long)row * Sn;
    if (attn_f32) {
        attn_f32[base + tid] = x0 * inv;
        attn_f32[base + tid + 256] = x1 * inv;
    }
    attn_bf[base + tid] = f2bf(x0 * inv);
    attn_bf[base + tid + 256] = f2bf(x1 * inv);
}

// ---------------- 128x128 counted-vmcnt GEMM ----------------
// C[M,N] = A[M,K] @ Bw[N,K]^T. Per K-tile {stage(nxt); vmcnt(4); s_barrier;
// frags+MFMA; s_barrier}. EPI: 0: x=acc+bias; 2: x=((acc+bias+R1)*s1+R2)*s2;
// 3: x=acc*s1+R1f[idx].
template <int EPI, bool OUTF32, bool NBOUND>
__global__ __launch_bounds__(256) void gemm_bf16(
    const __hip_bfloat16* __restrict__ A, const __hip_bfloat16* __restrict__ Bw,
    const float* __restrict__ bias, void* __restrict__ Cout,
    const __hip_bfloat16* __restrict__ R1, const __hip_bfloat16* __restrict__ R2,
    const float* __restrict__ R1f, const __hip_bfloat16* __restrict__ padrow,
    int M, int N, int K, long aZ, long bZ, long cZ, long r1Z, float s1, float s2) {
    __shared__ alignas(16) short As[2][128 * 32];
    __shared__ alignas(16) short Bs[2][128 * 32];
    const int tid = threadIdx.x;
    const int lane = tid & 63;
    const int wid = tid >> 6;
    const int wr = wid >> 1, wc = wid & 1;
    const int m0 = blockIdx.y * 128, n0 = blockIdx.x * 128;
    const short* Ag = (const short*)A + (long)blockIdx.z * aZ;
    const short* Bg = (const short*)Bw + (long)blockIdx.z * bZ;
    const short* pad = (const short*)padrow;

    f32x4 acc[4][4] = {};

    const int rc = tid >> 2;
    const int k8 = (tid & 3) * 8;

    auto stage = [&](int buf, int k0) {
#pragma unroll
        for (int j = 0; j < 2; ++j) {
            int r = rc + j * 64;
            const short* asrc = Ag + (long)(m0 + r) * K + k0 + k8;
            gload_lds16(asrc, &As[buf][r * 32 + k8]);
            int n = n0 + r;
            const short* bsrc = (NBOUND && n >= N) ? (pad + k8) : (Bg + (long)n * K + k0 + k8);
            gload_lds16(bsrc, &Bs[buf][r * 32 + k8]);
        }
    };

    const int rsel = lane & 15, hi = (lane >> 4) * 8;

    stage(0, 0);
    const int NT = K >> 5;
    for (int t = 0; t < NT; ++t) {
        const int cur = t & 1;
        if (t + 1 < NT) {
            stage(cur ^ 1, (t + 1) * 32);                       // 4 loads, stay in flight
            asm volatile("s_waitcnt vmcnt(4)" ::: "memory");    // tile t's 4 loads done
        } else {
            asm volatile("s_waitcnt vmcnt(0)" ::: "memory");
        }
        __builtin_amdgcn_s_barrier();                           // tile t visible to all waves
        __builtin_amdgcn_sched_barrier(0);
        short8 af[4], bg[4];
#pragma unroll
        for (int mi = 0; mi < 4; ++mi)
            af[mi] = *(const short8*)&As[cur][(wr * 64 + mi * 16 + rsel) * 32 + hi];
#pragma unroll
        for (int ni = 0; ni < 4; ++ni)
            bg[ni] = *(const short8*)&Bs[cur][(wc * 64 + ni * 16 + rsel) * 32 + hi];
        __builtin_amdgcn_s_setprio(1);
#pragma unroll
        for (int mi = 0; mi < 4; ++mi)
#pragma unroll
            for (int ni = 0; ni < 4; ++ni)
                acc[mi][ni] = __builtin_amdgcn_mfma_f32_16x16x32_bf16(af[mi], bg[ni], acc[mi][ni], 0, 0, 0);
        __builtin_amdgcn_s_setprio(0);
        __builtin_amdgcn_s_barrier();                           // reads of cur done before reuse
        __builtin_amdgcn_sched_barrier(0);
    }

    const int rg = (lane >> 4) * 4;
    float* Cf = (float*)Cout + (long)blockIdx.z * cZ;
    __hip_bfloat16* Cb = (__hip_bfloat16*)Cout + (long)blockIdx.z * cZ;
    const __hip_bfloat16* R1z = R1 + (long)blockIdx.z * r1Z;
    const __hip_bfloat16* R2z = R2 + (long)blockIdx.z * cZ;
    const float* R1fz = R1f + (long)blockIdx.z * r1Z;
#pragma unroll
    for (int ni = 0; ni < 4; ++ni) {
        int col = n0 + wc * 64 + ni * 16 + rsel;
        if (NBOUND && col >= N) continue;
        float bi = (EPI != 3 && bias) ? bias[col] : 0.f;
#pragma unroll
        for (int mi = 0; mi < 4; ++mi) {
            int row = m0 + wr * 64 + mi * 16 + rg;
            f32x4 v = acc[mi][ni];
#pragma unroll
            for (int q = 0; q < 4; ++q) {
                long idx = (long)(row + q) * N + col;
                float x;
                if (EPI == 3) x = v[q] * s1 + R1fz[idx];
                else {
                    x = v[q] + bi;
                    if (EPI >= 1) x = (x + bf2f(R1z[idx])) * s1;
                    if (EPI >= 2) x = (x + bf2f(R2z[idx])) * s2;
                }
                if (OUTF32) Cf[idx] = x;
                else Cb[idx] = f2bf(x);
            }
        }
    }
}

// ---------------- 64x128 high-occupancy GEMM (grid-limited batched ops) ----------------
// Same counted-vmcnt coarse loop at 64x128 tile: 4 waves each own a 64x32 N-slice,
// acc[4][2], 24 KB LDS, 3 loads/thread/tile -> 2+ blocks/CU at grid 512 (TLP hiding).
// Used where the 128^2 grid would be only 256 blocks (1 block/CU, 1 wave/SIMD).
template <int EPI, bool OUTF32>
__global__ __launch_bounds__(256) void gemm64(
    const __hip_bfloat16* __restrict__ A, const __hip_bfloat16* __restrict__ Bw,
    const float* __restrict__ bias, void* __restrict__ Cout,
    const __hip_bfloat16* __restrict__ R1, const __hip_bfloat16* __restrict__ R2,
    const float* __restrict__ R1f,
    int N, int K, long aZ, long bZ, long cZ, long r1Z, float s1, float s2) {
    __shared__ alignas(16) short As[2][64 * 32];
    __shared__ alignas(16) short Bs[2][128 * 32];
    const int tid = threadIdx.x;
    const int lane = tid & 63;
    const int wid = tid >> 6;      // wave owns N-slice wid*32
    const int m0 = blockIdx.y * 64, n0 = blockIdx.x * 128;
    const short* Ag = (const short*)A + (long)blockIdx.z * aZ;
    const short* Bg = (const short*)Bw + (long)blockIdx.z * bZ;

    f32x4 acc[4][2] = {};

    const int rc = tid >> 2;       // 0..63
    const int k8 = (tid & 3) * 8;

    auto stage = [&](int buf, int k0) {
        gload_lds16(Ag + (long)(m0 + rc) * K + k0 + k8, &As[buf][rc * 32 + k8]);
#pragma unroll
        for (int j = 0; j < 2; ++j) {
            int r = j * 64 + rc;
            gload_lds16(Bg + (long)(n0 + r) * K + k0 + k8, &Bs[buf][r * 32 + k8]);
        }
    };

    const int rsel = lane & 15, hi = (lane >> 4) * 8;

    stage(0, 0);
    const int NT = K >> 5;
    for (int t = 0; t < NT; ++t) {
        const int cur = t & 1;
        if (t + 1 < NT) {
            stage(cur ^ 1, (t + 1) * 32);                       // 3 loads, stay in flight
            asm volatile("s_waitcnt vmcnt(3)" ::: "memory");    // tile t's 3 loads done
        } else {
            asm volatile("s_waitcnt vmcnt(0)" ::: "memory");
        }
        __builtin_amdgcn_s_barrier();
        __builtin_amdgcn_sched_barrier(0);
        short8 af[4], bg[2];
#pragma unroll
        for (int mi = 0; mi < 4; ++mi)
            af[mi] = *(const short8*)&As[cur][(mi * 16 + rsel) * 32 + hi];
#pragma unroll
        for (int ni = 0; ni < 2; ++ni)
            bg[ni] = *(const short8*)&Bs[cur][(wid * 32 + ni * 16 + rsel) * 32 + hi];
        __builtin_amdgcn_s_setprio(1);
#pragma unroll
        for (int mi = 0; mi < 4; ++mi)
#pragma unroll
            for (int ni = 0; ni < 2; ++ni)
                acc[mi][ni] = __builtin_amdgcn_mfma_f32_16x16x32_bf16(af[mi], bg[ni], acc[mi][ni], 0, 0, 0);
        __builtin_amdgcn_s_setprio(0);
        __builtin_amdgcn_s_barrier();
        __builtin_amdgcn_sched_barrier(0);
    }

    const int rg = (lane >> 4) * 4;
    float* Cf = (float*)Cout + (long)blockIdx.z * cZ;
    __hip_bfloat16* Cb = (__hip_bfloat16*)Cout + (long)blockIdx.z * cZ;
    const __hip_bfloat16* R1z = R1 + (long)blockIdx.z * r1Z;
    const __hip_bfloat16* R2z = R2 + (long)blockIdx.z * cZ;
    const float* R1fz = R1f + (long)blockIdx.z * r1Z;
#pragma unroll
    for (int ni = 0; ni < 2; ++ni) {
        int col = n0 + wid * 32 + ni * 16 + rsel;
        float bi = (EPI != 3 && bias) ? bias[col] : 0.f;
#pragma unroll
        for (int mi = 0; mi < 4; ++mi) {
            int row = m0 + mi * 16 + rg;
            f32x4 v = acc[mi][ni];
#pragma unroll
            for (int q = 0; q < 4; ++q) {
                long idx = (long)(row + q) * N + col;
                float x;
                if (EPI == 3) x = v[q] * s1 + R1fz[idx];
                else {
                    x = v[q] + bi;
                    if (EPI >= 1) x = (x + bf2f(R1z[idx])) * s1;
                    if (EPI >= 2) x = (x + bf2f(R2z[idx])) * s2;
                }
                if (OUTF32) Cf[idx] = x;
                else Cb[idx] = f2bf(x);
            }
        }
    }
}

// ---------------- conv+GLU kernel: tap-dedup'd staging ----------------
// C = GLU(im2col(convinP) @ wpack^T + b). 256x256 tile, 8 waves (2Mx4N), BK=32 over H.
// Stage A once (384-row panel incl. halo) + 3 B tap-panels; acc += sum_tap shifted-A @ B_tap.
// Coarse 2-barrier loop with counted vmcnt(9). NO XCD swizzle: natural order gives
// XCD = linear_id % 8 = n_blk (gridDim.x == 8) -> L2-resident B slice per XCD.
__global__ __launch_bounds__(512) void conv_glu_kernel(
    const __hip_bfloat16* __restrict__ Ain,   // convinP [16][514][1024]
    const __hip_bfloat16* __restrict__ Bw,    // wpack [2048][3072]
    const float* __restrict__ bias, __hip_bfloat16* __restrict__ Cout,
    const __hip_bfloat16* __restrict__ padrow) {
    __shared__ alignas(16) short As[2][384 * 32];      // 48 KB
    __shared__ alignas(16) short Bs[2][3 * 256 * 32];  // 96 KB
    const int tid = threadIdx.x;
    const int lane = tid & 63;
    const int wid = tid >> 6;
    const int wr = wid >> 2, wc = wid & 3;
    const int n0 = blockIdx.x * 256, m0 = blockIdx.y * 256;   // natural order (B L2-locality)
    const short* Ag = (const short*)Ain;
    const short* Bg = (const short*)Bw;
    const short* pad = (const short*)padrow;
    const int p0 = (m0 >> 9) * TP + 2 + (m0 & 511);   // padded-space base row

    f32x4 acc[8][4] = {};

    const int srow = tid >> 2;                  // row within 128-row staging round
    const int skey = (tid >> 3) & 3;            // (row>>1)&3 (round base = 0 mod 8)
    const int scol = ((tid & 3) ^ skey) * 8;    // inverse-swizzled global col (elems)
    const int sdst = tid * 8;                   // linear LDS elems per round

    auto stageA = [&](int buf, int kt) {
        const int k0 = kt * 32;
#pragma unroll
        for (int j = 0; j < 3; ++j) {           // 384 rows = 3 rounds
            int prow = p0 - 128 + j * 128 + srow;
            const short* src = (prow >= 0) ? (Ag + (long)prow * Hn + k0 + scol) : (pad + scol);
            gload_lds16(src, &As[buf][j * 4096 + sdst]);
        }
    };
    auto stageB = [&](int buf, int kt) {
        const int k0 = kt * 32;
#pragma unroll
        for (int tap = 0; tap < 3; ++tap)
#pragma unroll
            for (int j = 0; j < 2; ++j) {       // 256 rows = 2 rounds per tap
                int row = j * 128 + srow;
                const short* src = Bg + (long)(n0 + row) * 3072 + tap * 1024 + k0 + scol;
                gload_lds16(src, &Bs[buf][tap * 8192 + j * 4096 + sdst]);
            }
    };

    const int rsel = lane & 15, hi = (lane >> 4) * 8;

    stageA(0, 0); stageB(0, 0);                 // 9 loads/thread in flight
    for (int t = 0; t < 32; ++t) {
        const int cur = t & 1;
        if (t + 1 < 32) {
            stageA(cur ^ 1, t + 1); stageB(cur ^ 1, t + 1);
            asm volatile("s_waitcnt vmcnt(9)" ::: "memory");   // tile t's 9 loads done
        } else {
            asm volatile("s_waitcnt vmcnt(0)" ::: "memory");
        }
        __builtin_amdgcn_s_barrier();
        __builtin_amdgcn_sched_barrier(0);
#pragma unroll
        for (int tap = 0; tap < 3; ++tap) {
            short8 bg[4];
#pragma unroll
            for (int ni = 0; ni < 4; ++ni) {
                int row = wc * 64 + ni * 16 + rsel;
                int xk = ((row >> 1) & 3) << 3;
                bg[ni] = *(const short8*)&Bs[cur][tap * 8192 + row * 32 + (hi ^ xk)];
            }
#pragma unroll
            for (int mh = 0; mh < 2; ++mh) {
                short8 af[4];
#pragma unroll
                for (int i = 0; i < 4; ++i) {
                    int row = 126 + tap + wr * 128 + mh * 64 + i * 16 + rsel;  // tap shift
                    int xk = ((row >> 1) & 3) << 3;
                    af[i] = *(const short8*)&As[cur][row * 32 + (hi ^ xk)];
                }
                __builtin_amdgcn_s_setprio(1);
#pragma unroll
                for (int i = 0; i < 4; ++i)
#pragma unroll
                    for (int ni = 0; ni < 4; ++ni)
                        acc[mh * 4 + i][ni] = __builtin_amdgcn_mfma_f32_16x16x32_bf16(
                            af[i], bg[ni], acc[mh * 4 + i][ni], 0, 0, 0);
                __builtin_amdgcn_s_setprio(0);
                __builtin_amdgcn_sched_barrier(0);
            }
        }
        __builtin_amdgcn_s_barrier();
        __builtin_amdgcn_sched_barrier(0);
    }

    // fused GLU epilogue: ni pairs (0,1) and (2,3) are (a,g) of the same 32-col group
    const int rg = (lane >> 4) * 4;
    const int No = Hn;
#pragma unroll
    for (int p = 0; p < 2; ++p) {
        int jcol = ((n0 + wc * 64) >> 1) + p * 16 + rsel;
        float ba = bias[jcol];
        float bgv = bias[Hn + jcol];
#pragma unroll
        for (int mi = 0; mi < 8; ++mi) {
            int row = m0 + wr * 128 + mi * 16 + rg;
            f32x4 va = acc[mi][2 * p], vg = acc[mi][2 * p + 1];
#pragma unroll
            for (int q = 0; q < 4; ++q) {
                float a = va[q] + ba;
                float g = vg[q] + bgv;
                Cout[(long)(row + q) * No + jcol] = f2bf(a * (1.f / (1.f + __expf(-g))));
            }
        }
    }
}

// ---------------- 256x256 coarse deep-pipeline GEMM (fc_out) ----------------
// NO XCD swizzle: gridDim.x = 40 (40%8==0) -> natural XCD = n_blk%8, B-slice 1.3 MB L2-fit.
template <bool OUTF32, bool NBOUND>
__global__ __launch_bounds__(512) void gemm256(
    const __hip_bfloat16* __restrict__ A, const __hip_bfloat16* __restrict__ Bw,
    const float* __restrict__ bias, void* __restrict__ Cout,
    const __hip_bfloat16* __restrict__ padrow, int M, int N, int K) {
    __shared__ alignas(16) short As[2][256 * 64];
    __shared__ alignas(16) short Bs[2][256 * 64];
    const int tid = threadIdx.x;
    const int lane = tid & 63;
    const int wid = tid >> 6;
    const int wr = wid >> 2, wc = wid & 3;
    const int n0 = blockIdx.x * 256, m0 = blockIdx.y * 256;   // natural order
    const short* Ag = (const short*)A;
    const short* Bg = (const short*)Bw;
    const short* pad = (const short*)padrow;

    f32x4 acc[8][4] = {};

    const int srow_l = tid >> 3;
    const int scol = ((tid & 7) ^ (srow_l & 7)) * 8;
    const int sdst = (tid >> 3) * 64 + (tid & 7) * 8;

    auto stage = [&](int buf, int kt) {
        const int k0 = kt * 64;
#pragma unroll
        for (int j = 0; j < 4; ++j) {
            const int row = j * 64 + srow_l;
            const short* asrc = Ag + (long)(m0 + row) * K + k0 + scol;
            gload_lds16(asrc, &As[buf][j * 4096 + sdst]);
            int n = n0 + row;
            const short* bsrc = (NBOUND && n >= N) ? (pad + scol) : (Bg + (long)n * K + k0 + scol);
            gload_lds16(bsrc, &Bs[buf][j * 4096 + sdst]);
        }
    };

    const int rsel = lane & 15, hi = (lane >> 4) * 8;
    const int xorc = (rsel & 7) << 3;

    stage(0, 0);
    const int NT = K >> 6;
    for (int t = 0; t < NT; ++t) {
        const int cur = t & 1;
        if (t + 1 < NT) {
            stage(cur ^ 1, t + 1);
            asm volatile("s_waitcnt vmcnt(8)" ::: "memory");
        } else {
            asm volatile("s_waitcnt vmcnt(0)" ::: "memory");
        }
        __builtin_amdgcn_s_barrier();
        __builtin_amdgcn_sched_barrier(0);
        short8 bg[2][2][2];
#pragma unroll
        for (int nh = 0; nh < 2; ++nh)
#pragma unroll
            for (int i = 0; i < 2; ++i) {
                const int row = wc * 64 + nh * 32 + i * 16 + rsel;
#pragma unroll
                for (int ks = 0; ks < 2; ++ks)
                    bg[nh][i][ks] = *(const short8*)&Bs[cur][row * 64 + ((ks * 32 + hi) ^ xorc)];
            }
#pragma unroll
        for (int mh = 0; mh < 2; ++mh) {
            short8 af[4][2];
#pragma unroll
            for (int i = 0; i < 4; ++i) {
                const int row = wr * 128 + mh * 64 + i * 16 + rsel;
#pragma unroll
                for (int ks = 0; ks < 2; ++ks)
                    af[i][ks] = *(const short8*)&As[cur][row * 64 + ((ks * 32 + hi) ^ xorc)];
            }
            __builtin_amdgcn_s_setprio(1);
#pragma unroll
            for (int nh = 0; nh < 2; ++nh)
#pragma unroll
                for (int i = 0; i < 4; ++i)
#pragma unroll
                    for (int jn = 0; jn < 2; ++jn)
#pragma unroll
                        for (int ks = 0; ks < 2; ++ks)
                            acc[mh * 4 + i][nh * 2 + jn] = __builtin_amdgcn_mfma_f32_16x16x32_bf16(
                                af[i][ks], bg[nh][jn][ks], acc[mh * 4 + i][nh * 2 + jn], 0, 0, 0);
            __builtin_amdgcn_s_setprio(0);
            __builtin_amdgcn_sched_barrier(0);
        }
        __builtin_amdgcn_s_barrier();
        __builtin_amdgcn_sched_barrier(0);
    }

    const int rg = (lane >> 4) * 4;
    float* Cf = (float*)Cout;
    __hip_bfloat16* Cb = (__hip_bfloat16*)Cout;
#pragma unroll
    for (int ni = 0; ni < 4; ++ni) {
        int col = n0 + wc * 64 + ni * 16 + rsel;
        if (NBOUND && col >= N) continue;
        float bi = bias ? bias[col] : 0.f;
#pragma unroll
        for (int mi = 0; mi < 8; ++mi) {
            int row = m0 + wr * 128 + mi * 16 + rg;
            f32x4 v = acc[mi][ni];
#pragma unroll
            for (int q = 0; q < 4; ++q) {
                long idx = (long)(row + q) * N + col;
                float x = v[q] + bi;
                if (OUTF32) Cf[idx] = x;
                else Cb[idx] = f2bf(x);
            }
        }
    }
}

// ---------------- launcher ----------------

extern "C" void kernel_launch(void* const* d_in, const int* in_sizes, int n_in,
                              void* d_out, int out_size, void* d_ws, size_t ws_size,
                              hipStream_t stream) {
    const int* tgt = (const int*)d_in[0];
    const float* enc_conved = (const float*)d_in[1];
    const float* enc_combined = (const float*)d_in[2];
    const float* tok_emb = (const float*)d_in[3];
    const float* pos_emb = (const float*)d_in[4];
    const float* w_e2h = (const float*)d_in[5];
    const float* b_e2h = (const float*)d_in[6];
    const float* w_h2e = (const float*)d_in[7];
    const float* b_h2e = (const float*)d_in[8];
    const float* w_ah2e = (const float*)d_in[9];
    const float* b_ah2e = (const float*)d_in[10];
    const float* w_ae2h = (const float*)d_in[11];
    const float* b_ae2h = (const float*)d_in[12];
    const float* w_fc = (const float*)d_in[13];
    const float* b_fc = (const float*)d_in[14];
    const float* conv_w = (const float*)d_in[15];
    const float* conv_b = (const float*)d_in[16];

    char* ws = (char*)d_ws;
    size_t off = 0;
    auto alloc = [&](size_t bytes) { size_t r = off; off = (off + bytes + 255) & ~(size_t)255; return r; };
    __hip_bfloat16* emb    = (__hip_bfloat16*)(ws + alloc((size_t)Mn * En * 2));
    __hip_bfloat16* embA   = (__hip_bfloat16*)(ws + alloc((size_t)Mn * En * 2));
    __hip_bfloat16* convinP= (__hip_bfloat16*)(ws + alloc((size_t)Bn * TP * Hn * 2));  // padded
    __hip_bfloat16* conved = (__hip_bfloat16*)(ws + alloc((size_t)Mn * Hn * 2));
    size_t o_en = alloc((size_t)Mn * Sn * 4);
    float* energy = (float*)(ws + o_en);
    __hip_bfloat16* encm = (__hip_bfloat16*)(ws + o_en);   // overlay: prep-only bf16(enc_combined)
    __hip_bfloat16* attnbf = (__hip_bfloat16*)(ws + alloc((size_t)Mn * Sn * 2));
    __hip_bfloat16* wT_e2h = (__hip_bfloat16*)(ws + alloc((size_t)Hn * En * 2));
    __hip_bfloat16* wT_h2e = (__hip_bfloat16*)(ws + alloc((size_t)En * Hn * 2));
    __hip_bfloat16* wT_ae2h= (__hip_bfloat16*)(ws + alloc((size_t)Hn * En * 2));
    __hip_bfloat16* wbAH   = (__hip_bfloat16*)(ws + alloc((size_t)Hn * En * 2));
    __hip_bfloat16* wT_fc  = (__hip_bfloat16*)(ws + alloc((size_t)Vn * En * 2));
    __hip_bfloat16* encc   = (__hip_bfloat16*)(ws + alloc((size_t)Bn * Sn * En * 2));
    __hip_bfloat16* encAH  = (__hip_bfloat16*)(ws + alloc((size_t)Bn * Sn * Hn * 2));
    __hip_bfloat16* encCW  = (__hip_bfloat16*)(ws + alloc((size_t)Bn * Hn * Sn * 2));
    float* embE            = (float*)(ws + alloc((size_t)Mn * Sn * 4));
    __hip_bfloat16* padrow = (__hip_bfloat16*)(ws + alloc(256));
    __hip_bfloat16* wpack  = (__hip_bfloat16*)(ws + alloc((size_t)2 * Hn * 3 * Hn * 2)); // per-layer, warm
    __hip_bfloat16* tmpE = conved;  // overlay: conved dead after last update GEMM
    __hip_bfloat16* convinD = convinP + 2 * Hn;   // data rows base (skip 2 pads of batch 0)

    float* out = (float*)d_out;
    float* attn_out = out + (long)Mn * Vn;
    const long bSq = (long)Sn * Sn;
    const long bSH = (long)Sn * Hn;
    const long bTH = (long)Tn * Hn;
    const long bTE = (long)Tn * En;
    const long bPH = (long)TP * Hn;   // padded per-batch stride

    dim3 tb(32, 8);
    const __hip_bfloat16* nb = nullptr;
    const float* nf = nullptr;

    // ---- prep ----
    padfill_kernel<<<1, 128, 0, stream>>>(padrow);
    padrows_kernel<<<2 * Bn, 256, 0, stream>>>(convinP);
    embed_kernel<<<Mn, 128, 0, stream>>>(tgt, tok_emb, pos_emb, b_ah2e, emb, embA);
    transpose_f32_bf16<<<dim3(Hn / 32, En / 32, 1), tb, 0, stream>>>(w_e2h, wT_e2h, En, Hn, 0, 0);
    transpose_f32_bf16<<<dim3(En / 32, Hn / 32, 1), tb, 0, stream>>>(w_h2e, wT_h2e, Hn, En, 0, 0);
    transpose_f32_bf16<<<dim3(Hn / 32, En / 32, 1), tb, 0, stream>>>(w_ae2h, wT_ae2h, En, Hn, 0, 0);
    transpose_f32_bf16<<<dim3((Vn + 31) / 32, En / 32, 1), tb, 0, stream>>>(w_fc, wT_fc, En, Vn, 0, 0);
    convert_bf16_kernel<<<((long)Hn * En / 4 + 255) / 256, 256, 0, stream>>>(w_ah2e, wbAH, (long)Hn * En / 4);
    convert_bf16_kernel<<<((long)Bn * Sn * En / 4 + 255) / 256, 256, 0, stream>>>(enc_conved, encc, (long)Bn * Sn * En / 4);
    convert_bf16_kernel<<<((long)Bn * Sn * En / 4 + 255) / 256, 256, 0, stream>>>(enc_combined, encm, (long)Bn * Sn * En / 4);

    // encAH[b][s][h] = encc[b] @ w_ah2e^T   (layer-invariant attention factor)
    gemm_bf16<0, false, false><<<dim3(Hn / 128, Sn / 128, Bn), 256, 0, stream>>>(
        encc, wbAH, nullptr, encAH, nb, nb, nf, padrow, Sn, Hn, En, bSq, 0, bSH, 0, 1.f, 1.f);
    // encCW[b][h][s] = (enc_combined[b] @ w_ae2h)^T
    gemm_bf16<0, false, false><<<dim3(Sn / 128, Hn / 128, Bn), 256, 0, stream>>>(
        wT_ae2h, encm, nullptr, encCW, nb, nb, nf, padrow, Hn, Sn, En, 0, bSq, bSH, 0, 1.f, 1.f);
    // embE[b][t][s] = embA[b] @ encc[b]^T   (f32; kScale folded into embA)  [64-tile, 512 blocks]
    gemm64<0, true><<<dim3(Sn / 128, Tn / 64, Bn), 256, 0, stream>>>(
        embA, encc, nullptr, embE, nb, nb, nf, Sn, En, bTE, bSq, bSq, 0, 1.f, 1.f);
    // conv_input = embedded @ emb2hid + b   -> padded buffer (batched, rows +2)
    gemm_bf16<0, false, false><<<dim3(Hn / 128, Tn / 128, Bn), 256, 0, stream>>>(
        emb, wT_e2h, b_e2h, convinD, nb, nb, nf, padrow, Tn, Hn, En, bTE, 0, bPH, 0, 1.f, 1.f);

    for (int l = 0; l < Ln; ++l) {
        // pack conv weight for THIS layer just before use (keeps B-panel L2/L3-warm)
        wpack2_kernel<<<2 * Hn, 256, 0, stream>>>(conv_w, wpack, l);
        // conved = GLU(conv(convinP) + conv_b[l])   [8192,1024], tap-dedup'd staging
        conv_glu_kernel<<<dim3(2 * Hn / 256, Mn / 256), 512, 0, stream>>>(
            convinP, wpack, conv_b + (long)l * 2 * Hn, conved, padrow);
        // energy[b] = kScale * conved[b] @ encAH[b]^T + embE[b]   (f32) [64-tile, 512 blocks]
        gemm64<3, true><<<dim3(Sn / 128, Tn / 64, Bn), 256, 0, stream>>>(
            conved, encAH, nullptr, energy, nb, nb, embE, Sn, Hn, bTH, bSH, bSq, bSq, kScale, 1.f);
        // attention = softmax(energy)  (f32 out only needed from the LAST layer)
        softmax_kernel<<<Mn, 256, 0, stream>>>(energy, (l == Ln - 1) ? attn_out : nullptr, attnbf);
        // conv_input = ((attn @ encCW + b_ae2h + conved)*s + conv_input)*s  (C/R2 padded)
        gemm_bf16<2, false, false><<<dim3(Hn / 128, Tn / 128, Bn), 256, 0, stream>>>(
            attnbf, encCW, b_ae2h, convinD, conved, convinD, nf, padrow,
            Tn, Hn, Sn, bSq, bSH, bPH, bTH, kScale, kScale);
    }

    // conved = conv_input @ hid2emb + b   [8192,512]  (A padded, batched)  [64-tile, 512 blocks]
    gemm64<0, false><<<dim3(En / 128, Tn / 64, Bn), 256, 0, stream>>>(
        convinD, wT_h2e, b_h2e, tmpE, nb, nb, nf, En, Hn, bPH, 0, bTE, 0, 1.f, 1.f);
    // output = conved @ fc_out + b        [8192,10000] f32, N-bounded  (256² coarse)
    gemm256<true, true><<<dim3((Vn + 255) / 256, Mn / 256), 512, 0, stream>>>(
        tmpE, wT_fc, b_fc, out, padrow, Mn, Vn, En);
}

// Round 15
// 1221.616 us; speedup vs baseline: 1.1898x; 1.0178x over previous
//
#include <hip/hip_runtime.h>
#include <hip/hip_bf16.h>

typedef __attribute__((ext_vector_type(4))) float f32x4;
typedef __attribute__((ext_vector_type(8))) short short8;

#define DEVFN __device__ __forceinline__

static constexpr int Bn = 16, Tn = 512, Sn = 512, Vn = 10000, En = 512, Hn = 1024, Ln = 6;
static constexpr int Mn = Bn * Tn;  // 8192 token rows
static constexpr int TP = Tn + 2;   // padded sequence rows (2 causal PAD rows)
static constexpr float kScale = 0.70710678118654752440f;

DEVFN float bf2f(__hip_bfloat16 x) { return __bfloat162float(x); }
DEVFN __hip_bfloat16 f2bf(float x) { return __float2bfloat16(x); }

struct bf16x4 { __hip_bfloat16 x, y, z, w; };

// async global -> LDS, 16B per lane (wave-uniform LDS base + lane*16 layout)
DEVFN void gload_lds16(const short* g, short* l) {
    __builtin_amdgcn_global_load_lds((const __attribute__((address_space(1))) void*)g,
                                     (__attribute__((address_space(3))) void*)l, 16, 0, 0);
}

// ---------------- small prep kernels ----------------

__global__ void padfill_kernel(__hip_bfloat16* p) {
    p[threadIdx.x] = f2bf(1.0f);  // PAD_VAL as float, per torch code
}

// fill the 2 causal PAD rows of each padded sequence in convinP with 1.0
__global__ void padrows_kernel(__hip_bfloat16* convinP) {
    int row = blockIdx.x;                 // 0..31: (b, which)
    long base = ((long)(row >> 1) * TP + (row & 1)) * Hn;
    int e = threadIdx.x * 4;              // 256 threads x 4 = 1024
    bf16x4 v{f2bf(1.f), f2bf(1.f), f2bf(1.f), f2bf(1.f)};
    *(bf16x4*)(convinP + base + e) = v;
}

// embedded[b,t,:] = tok_emb[tgt[b,t],:] + pos_emb[t,:]  (bf16)
// embA = kScale*(embedded + b_ah2e)                      (bf16, for embE precompute)
__global__ void embed_kernel(const int* __restrict__ tgt, const float* __restrict__ tok,
                             const float* __restrict__ pos, const float* __restrict__ bah,
                             __hip_bfloat16* __restrict__ out, __hip_bfloat16* __restrict__ outA) {
    int row = blockIdx.x;              // 0..8191
    int t = row & (Tn - 1);
    int v = tgt[row];
    const float* tr = tok + (long)v * En;
    const float* pr = pos + (long)t * En;
    int e = threadIdx.x * 4;           // block 128 covers 512
    float4 a = *(const float4*)(tr + e);
    float4 b = *(const float4*)(pr + e);
    float4 bb = *(const float4*)(bah + e);
    bf16x4 o{f2bf(a.x + b.x), f2bf(a.y + b.y), f2bf(a.z + b.z), f2bf(a.w + b.w)};
    *(bf16x4*)(out + (long)row * En + e) = o;
    bf16x4 oa{f2bf(kScale * (a.x + b.x + bb.x)), f2bf(kScale * (a.y + b.y + bb.y)),
              f2bf(kScale * (a.z + b.z + bb.z)), f2bf(kScale * (a.w + b.w + bb.w))};
    *(bf16x4*)(outA + (long)row * En + e) = oa;
}

// dst[c][r] = bf16(src[r][c]); src is [R][C] f32. grid(ceil(C/32), ceil(R/32), Z), block(32,8)
__global__ void transpose_f32_bf16(const float* __restrict__ src, __hip_bfloat16* __restrict__ dst,
                                   int R, int C, long sZi, long sZo) {
    __shared__ float tile[32][33];
    src += (long)blockIdx.z * sZi;
    dst += (long)blockIdx.z * sZo;
    int c0 = blockIdx.x * 32, r0 = blockIdx.y * 32;
    for (int i = threadIdx.y; i < 32; i += 8) {
        int r = r0 + i, c = c0 + threadIdx.x;
        tile[i][threadIdx.x] = (r < R && c < C) ? src[(long)r * C + c] : 0.f;
    }
    __syncthreads();
    for (int i = threadIdx.y; i < 32; i += 8) {
        int c = c0 + i, r = r0 + threadIdx.x;
        if (c < C && r < R) dst[(long)c * R + r] = f2bf(tile[threadIdx.x][i]);
    }
}

// f32 -> bf16 convert (n divisible by 4)
__global__ void convert_bf16_kernel(const float* __restrict__ src, __hip_bfloat16* __restrict__ dst,
                                    long n4) {
    long i = (long)blockIdx.x * blockDim.x + threadIdx.x;
    if (i >= n4) return;
    long j = i * 4;
    float4 v = *(const float4*)(src + j);
    bf16x4 o{f2bf(v.x), f2bf(v.y), f2bf(v.z), f2bf(v.w)};
    *(bf16x4*)(dst + j) = o;
}

// Coalesced conv-weight pack for layer l, a/g interleaved in 16-col blocks for fused GLU.
__global__ __launch_bounds__(256) void wpack2_kernel(const float* __restrict__ convw,
                                                     __hip_bfloat16* __restrict__ wp, int l) {
    __shared__ float row[3 * Hn];
    int c = blockIdx.x;                        // 0..2047 packed col
    int grp = c >> 5, w = c & 31;
    int o = (w < 16) ? grp * 16 + w : Hn + grp * 16 + (w - 16);
    const float* src = convw + ((long)(l * 2 * Hn + o)) * (Hn * 3);
#pragma unroll
    for (int j = 0; j < 3; ++j) {
        int idx = (j * 256 + threadIdx.x) * 4;
        *(float4*)&row[idx] = *(const float4*)(src + idx);
    }
    __syncthreads();
    __hip_bfloat16* dst = wp + (long)c * (3 * Hn);
#pragma unroll
    for (int j = 0; j < 3; ++j) {
        int kk = (j * 256 + threadIdx.x) * 4;   // 4-chunk never crosses a tap boundary
        int tap = kk >> 10;
        int i = kk & (Hn - 1);
        bf16x4 v{f2bf(row[i * 3 + tap]), f2bf(row[(i + 1) * 3 + tap]),
                 f2bf(row[(i + 2) * 3 + tap]), f2bf(row[(i + 3) * 3 + tap])};
        *(bf16x4*)(dst + kk) = v;
    }
}

// row softmax over S=512; writes bf16 (next GEMM input) + optional f32 (final attention)
__global__ __launch_bounds__(256) void softmax_kernel(const float* __restrict__ energy,
                                                      float* __restrict__ attn_f32,
                                                      __hip_bfloat16* __restrict__ attn_bf) {
    int row = blockIdx.x;  // 0..8191
    const float* e = energy + (long)row * Sn;
    int tid = threadIdx.x;
    float v0 = e[tid], v1 = e[tid + 256];
    float m = fmaxf(v0, v1);
    for (int off = 32; off; off >>= 1) m = fmaxf(m, __shfl_xor(m, off));
    __shared__ float redm[4];
    __shared__ float reds[4];
    int lane = tid & 63, w = tid >> 6;
    if (lane == 0) redm[w] = m;
    __syncthreads();
    m = fmaxf(fmaxf(redm[0], redm[1]), fmaxf(redm[2], redm[3]));
    float x0 = __expf(v0 - m), x1 = __expf(v1 - m);
    float s = x0 + x1;
    for (int off = 32; off; off >>= 1) s += __shfl_xor(s, off);
    if (lane == 0) reds[w] = s;
    __syncthreads();
    s = reds[0] + reds[1] + reds[2] + reds[3];
    float inv = 1.f / s;
    long base = (long)row * Sn;
    if (attn_f32) {
        attn_f32[base + tid] = x0 * inv;
        attn_f32[base + tid + 256] = x1 * inv;
    }
    attn_bf[base + tid] = f2bf(x0 * inv);
    attn_bf[base + tid + 256] = f2bf(x1 * inv);
}

// ---------------- 128x128 counted-vmcnt GEMM ----------------
// C[M,N] = A[M,K] @ Bw[N,K]^T. Per K-tile {stage(nxt); vmcnt(4); s_barrier;
// frags+MFMA; s_barrier}. EPI: 0: x=acc+bias; 2: x=((acc+bias+R1)*s1+R2)*s2;
// 3: x=acc*s1+R1f[idx].
template <int EPI, bool OUTF32, bool NBOUND>
__global__ __launch_bounds__(256) void gemm_bf16(
    const __hip_bfloat16* __restrict__ A, const __hip_bfloat16* __restrict__ Bw,
    const float* __restrict__ bias, void* __restrict__ Cout,
    const __hip_bfloat16* __restrict__ R1, const __hip_bfloat16* __restrict__ R2,
    const float* __restrict__ R1f, const __hip_bfloat16* __restrict__ padrow,
    int M, int N, int K, long aZ, long bZ, long cZ, long r1Z, float s1, float s2) {
    __shared__ alignas(16) short As[2][128 * 32];
    __shared__ alignas(16) short Bs[2][128 * 32];
    const int tid = threadIdx.x;
    const int lane = tid & 63;
    const int wid = tid >> 6;
    const int wr = wid >> 1, wc = wid & 1;
    const int m0 = blockIdx.y * 128, n0 = blockIdx.x * 128;
    const short* Ag = (const short*)A + (long)blockIdx.z * aZ;
    const short* Bg = (const short*)Bw + (long)blockIdx.z * bZ;
    const short* pad = (const short*)padrow;

    f32x4 acc[4][4] = {};

    const int rc = tid >> 2;
    const int k8 = (tid & 3) * 8;

    auto stage = [&](int buf, int k0) {
#pragma unroll
        for (int j = 0; j < 2; ++j) {
            int r = rc + j * 64;
            const short* asrc = Ag + (long)(m0 + r) * K + k0 + k8;
            gload_lds16(asrc, &As[buf][r * 32 + k8]);
            int n = n0 + r;
            const short* bsrc = (NBOUND && n >= N) ? (pad + k8) : (Bg + (long)n * K + k0 + k8);
            gload_lds16(bsrc, &Bs[buf][r * 32 + k8]);
        }
    };

    const int rsel = lane & 15, hi = (lane >> 4) * 8;

    stage(0, 0);
    const int NT = K >> 5;
    for (int t = 0; t < NT; ++t) {
        const int cur = t & 1;
        if (t + 1 < NT) {
            stage(cur ^ 1, (t + 1) * 32);                       // 4 loads, stay in flight
            asm volatile("s_waitcnt vmcnt(4)" ::: "memory");    // tile t's 4 loads done
        } else {
            asm volatile("s_waitcnt vmcnt(0)" ::: "memory");
        }
        __builtin_amdgcn_s_barrier();                           // tile t visible to all waves
        __builtin_amdgcn_sched_barrier(0);
        short8 af[4], bg[4];
#pragma unroll
        for (int mi = 0; mi < 4; ++mi)
            af[mi] = *(const short8*)&As[cur][(wr * 64 + mi * 16 + rsel) * 32 + hi];
#pragma unroll
        for (int ni = 0; ni < 4; ++ni)
            bg[ni] = *(const short8*)&Bs[cur][(wc * 64 + ni * 16 + rsel) * 32 + hi];
        __builtin_amdgcn_s_setprio(1);
#pragma unroll
        for (int mi = 0; mi < 4; ++mi)
#pragma unroll
            for (int ni = 0; ni < 4; ++ni)
                acc[mi][ni] = __builtin_amdgcn_mfma_f32_16x16x32_bf16(af[mi], bg[ni], acc[mi][ni], 0, 0, 0);
        __builtin_amdgcn_s_setprio(0);
        __builtin_amdgcn_s_barrier();                           // reads of cur done before reuse
        __builtin_amdgcn_sched_barrier(0);
    }

    const int rg = (lane >> 4) * 4;
    float* Cf = (float*)Cout + (long)blockIdx.z * cZ;
    __hip_bfloat16* Cb = (__hip_bfloat16*)Cout + (long)blockIdx.z * cZ;
    const __hip_bfloat16* R1z = R1 + (long)blockIdx.z * r1Z;
    const __hip_bfloat16* R2z = R2 + (long)blockIdx.z * cZ;
    const float* R1fz = R1f + (long)blockIdx.z * r1Z;
#pragma unroll
    for (int ni = 0; ni < 4; ++ni) {
        int col = n0 + wc * 64 + ni * 16 + rsel;
        if (NBOUND && col >= N) continue;
        float bi = (EPI != 3 && bias) ? bias[col] : 0.f;
#pragma unroll
        for (int mi = 0; mi < 4; ++mi) {
            int row = m0 + wr * 64 + mi * 16 + rg;
            f32x4 v = acc[mi][ni];
#pragma unroll
            for (int q = 0; q < 4; ++q) {
                long idx = (long)(row + q) * N + col;
                float x;
                if (EPI == 3) x = v[q] * s1 + R1fz[idx];
                else {
                    x = v[q] + bi;
                    if (EPI >= 1) x = (x + bf2f(R1z[idx])) * s1;
                    if (EPI >= 2) x = (x + bf2f(R2z[idx])) * s2;
                }
                if (OUTF32) Cf[idx] = x;
                else Cb[idx] = f2bf(x);
            }
        }
    }
}

// ---------------- 64x128 high-occupancy GEMM (grid-limited batched ops) ----------------
template <int EPI, bool OUTF32>
__global__ __launch_bounds__(256) void gemm64(
    const __hip_bfloat16* __restrict__ A, const __hip_bfloat16* __restrict__ Bw,
    const float* __restrict__ bias, void* __restrict__ Cout,
    const __hip_bfloat16* __restrict__ R1, const __hip_bfloat16* __restrict__ R2,
    const float* __restrict__ R1f,
    int N, int K, long aZ, long bZ, long cZ, long r1Z, float s1, float s2) {
    __shared__ alignas(16) short As[2][64 * 32];
    __shared__ alignas(16) short Bs[2][128 * 32];
    const int tid = threadIdx.x;
    const int lane = tid & 63;
    const int wid = tid >> 6;      // wave owns N-slice wid*32
    const int m0 = blockIdx.y * 64, n0 = blockIdx.x * 128;
    const short* Ag = (const short*)A + (long)blockIdx.z * aZ;
    const short* Bg = (const short*)Bw + (long)blockIdx.z * bZ;

    f32x4 acc[4][2] = {};

    const int rc = tid >> 2;       // 0..63
    const int k8 = (tid & 3) * 8;

    auto stage = [&](int buf, int k0) {
        gload_lds16(Ag + (long)(m0 + rc) * K + k0 + k8, &As[buf][rc * 32 + k8]);
#pragma unroll
        for (int j = 0; j < 2; ++j) {
            int r = j * 64 + rc;
            gload_lds16(Bg + (long)(n0 + r) * K + k0 + k8, &Bs[buf][r * 32 + k8]);
        }
    };

    const int rsel = lane & 15, hi = (lane >> 4) * 8;

    stage(0, 0);
    const int NT = K >> 5;
    for (int t = 0; t < NT; ++t) {
        const int cur = t & 1;
        if (t + 1 < NT) {
            stage(cur ^ 1, (t + 1) * 32);                       // 3 loads, stay in flight
            asm volatile("s_waitcnt vmcnt(3)" ::: "memory");    // tile t's 3 loads done
        } else {
            asm volatile("s_waitcnt vmcnt(0)" ::: "memory");
        }
        __builtin_amdgcn_s_barrier();
        __builtin_amdgcn_sched_barrier(0);
        short8 af[4], bg[2];
#pragma unroll
        for (int mi = 0; mi < 4; ++mi)
            af[mi] = *(const short8*)&As[cur][(mi * 16 + rsel) * 32 + hi];
#pragma unroll
        for (int ni = 0; ni < 2; ++ni)
            bg[ni] = *(const short8*)&Bs[cur][(wid * 32 + ni * 16 + rsel) * 32 + hi];
        __builtin_amdgcn_s_setprio(1);
#pragma unroll
        for (int mi = 0; mi < 4; ++mi)
#pragma unroll
            for (int ni = 0; ni < 2; ++ni)
                acc[mi][ni] = __builtin_amdgcn_mfma_f32_16x16x32_bf16(af[mi], bg[ni], acc[mi][ni], 0, 0, 0);
        __builtin_amdgcn_s_setprio(0);
        __builtin_amdgcn_s_barrier();
        __builtin_amdgcn_sched_barrier(0);
    }

    const int rg = (lane >> 4) * 4;
    float* Cf = (float*)Cout + (long)blockIdx.z * cZ;
    __hip_bfloat16* Cb = (__hip_bfloat16*)Cout + (long)blockIdx.z * cZ;
    const __hip_bfloat16* R1z = R1 + (long)blockIdx.z * r1Z;
    const __hip_bfloat16* R2z = R2 + (long)blockIdx.z * cZ;
    const float* R1fz = R1f + (long)blockIdx.z * r1Z;
#pragma unroll
    for (int ni = 0; ni < 2; ++ni) {
        int col = n0 + wid * 32 + ni * 16 + rsel;
        float bi = (EPI != 3 && bias) ? bias[col] : 0.f;
#pragma unroll
        for (int mi = 0; mi < 4; ++mi) {
            int row = m0 + mi * 16 + rg;
            f32x4 v = acc[mi][ni];
#pragma unroll
            for (int q = 0; q < 4; ++q) {
                long idx = (long)(row + q) * N + col;
                float x;
                if (EPI == 3) x = v[q] * s1 + R1fz[idx];
                else {
                    x = v[q] + bi;
                    if (EPI >= 1) x = (x + bf2f(R1z[idx])) * s1;
                    if (EPI >= 2) x = (x + bf2f(R2z[idx])) * s2;
                }
                if (OUTF32) Cf[idx] = x;
                else Cb[idx] = f2bf(x);
            }
        }
    }
}

// ---------------- conv+GLU kernel: M=512 (one padded sequence) x N=128 ----------------
// C = GLU(conv(convinP) + b). 8 waves (4Mx2N), wave tile 128x64, BK=32 over H.
// A staged once per tile: 514 rows (2-row causal halo IS the padded buffer's pad rows,
// so no redirect conditional) = 4 full 128-row DMA rounds + one 2-row partial round
// (threads 0..7, wave 0 only -> per-wave counted vmcnt: wave0=8, others=7).
// B: 3 tap panels x 128 rows = 3 rounds. Staged 57.6 KB/tile vs 72 KB at 256x256 (-20%).
// acc += sum_tap A[r+tap] @ B_tap via shifted LDS read rows (LDS row r = padded row
// seq*TP + r; logical data row m + tap - 2 => LDS row local_m + tap).
// NO XCD swizzle: gridDim.x=16 -> XCD = lin%8 hosts 2 N-slices (1.5 MB, L2-fit).
__global__ __launch_bounds__(512) void conv_glu_kernel(
    const __hip_bfloat16* __restrict__ Ain,   // convinP [16][514][1024]
    const __hip_bfloat16* __restrict__ Bw,    // wpack [2048][3072]
    const float* __restrict__ bias, __hip_bfloat16* __restrict__ Cout) {
    __shared__ alignas(16) short As[2][516 * 32];      // 2 x 33 KB
    __shared__ alignas(16) short Bs[2][3 * 128 * 32];  // 2 x 24 KB
    const int tid = threadIdx.x;
    const int lane = tid & 63;
    const int wid = tid >> 6;
    const int wr = wid >> 1, wc = wid & 1;             // 4M x 2N
    const int n0 = blockIdx.x * 128;                   // 16 N-blocks
    const int m0 = blockIdx.y * 512;                   // 16 M-blocks = sequences
    const int seqbase = blockIdx.y * TP;               // padded row of LDS row 0
    const short* Ag = (const short*)Ain;
    const short* Bg = (const short*)Bw;

    f32x4 acc[8][4] = {};

    const int srow = tid >> 2;                  // row within 128-row staging round
    const int skey = (tid >> 3) & 3;            // (row>>1)&3 within round
    const int scol = ((tid & 3) ^ skey) * 8;    // inverse-swizzled global col (elems)
    const int sdst = tid * 8;                   // linear LDS elems per round

    auto stageA = [&](int buf, int kt) {
        const int k0 = kt * 32;
#pragma unroll
        for (int j = 0; j < 4; ++j) {           // rows 0..511
            int r = j * 128 + srow;
            gload_lds16(Ag + (long)(seqbase + r) * Hn + k0 + scol, &As[buf][j * 4096 + sdst]);
        }
        if (tid < 8) {                          // rows 512,513 (wave 0 only; skey==0 here)
            int r = 512 + (tid >> 2);
            gload_lds16(Ag + (long)(seqbase + r) * Hn + k0 + (tid & 3) * 8,
                        &As[buf][4 * 4096 + sdst]);
        }
    };
    auto stageB = [&](int buf, int kt) {
        const int k0 = kt * 32;
#pragma unroll
        for (int tap = 0; tap < 3; ++tap)
            gload_lds16(Bg + (long)(n0 + srow) * 3072 + tap * 1024 + k0 + scol,
                        &Bs[buf][tap * 4096 + sdst]);
    };

    const int rsel = lane & 15, hi = (lane >> 4) * 8;

    stageA(0, 0); stageB(0, 0);                 // wave0: 8 loads, others: 7
    for (int t = 0; t < 32; ++t) {
        const int cur = t & 1;
        if (t + 1 < 32) {
            stageA(cur ^ 1, t + 1); stageB(cur ^ 1, t + 1);
            if (wid == 0) asm volatile("s_waitcnt vmcnt(8)" ::: "memory");  // tile t's loads done
            else          asm volatile("s_waitcnt vmcnt(7)" ::: "memory");
        } else {
            asm volatile("s_waitcnt vmcnt(0)" ::: "memory");
        }
        __builtin_amdgcn_s_barrier();
        __builtin_amdgcn_sched_barrier(0);
#pragma unroll
        for (int tap = 0; tap < 3; ++tap) {
            short8 bg[4];
#pragma unroll
            for (int ni = 0; ni < 4; ++ni) {
                int row = wc * 64 + ni * 16 + rsel;
                int xk = ((row >> 1) & 3) << 3;
                bg[ni] = *(const short8*)&Bs[cur][tap * 4096 + row * 32 + (hi ^ xk)];
            }
#pragma unroll
            for (int mh = 0; mh < 2; ++mh) {
                short8 af[4];
#pragma unroll
                for (int i = 0; i < 4; ++i) {
                    int row = wr * 128 + mh * 64 + i * 16 + rsel + tap;  // LDS row = local_m + tap
                    int xk = ((row >> 1) & 3) << 3;
                    af[i] = *(const short8*)&As[cur][row * 32 + (hi ^ xk)];
                }
                __builtin_amdgcn_s_setprio(1);
#pragma unroll
                for (int i = 0; i < 4; ++i)
#pragma unroll
                    for (int ni = 0; ni < 4; ++ni)
                        acc[mh * 4 + i][ni] = __builtin_amdgcn_mfma_f32_16x16x32_bf16(
                            af[i], bg[ni], acc[mh * 4 + i][ni], 0, 0, 0);
                __builtin_amdgcn_s_setprio(0);
                __builtin_amdgcn_sched_barrier(0);
            }
        }
        __builtin_amdgcn_s_barrier();
        __builtin_amdgcn_sched_barrier(0);
    }

    // fused GLU epilogue: ni pairs (0,1) and (2,3) are (a,g) of the same 32-col group
    const int rg = (lane >> 4) * 4;
    const int No = Hn;
#pragma unroll
    for (int p = 0; p < 2; ++p) {
        int jcol = ((n0 + wc * 64) >> 1) + p * 16 + rsel;
        float ba = bias[jcol];
        float bgv = bias[Hn + jcol];
#pragma unroll
        for (int mi = 0; mi < 8; ++mi) {
            int row = m0 + wr * 128 + mi * 16 + rg;
            f32x4 va = acc[mi][2 * p], vg = acc[mi][2 * p + 1];
#pragma unroll
            for (int q = 0; q < 4; ++q) {
                float a = va[q] + ba;
                float g = vg[q] + bgv;
                Cout[(long)(row + q) * No + jcol] = f2bf(a * (1.f / (1.f + __expf(-g))));
            }
        }
    }
}

// ---------------- 256x256 coarse deep-pipeline GEMM (fc_out) ----------------
template <bool OUTF32, bool NBOUND>
__global__ __launch_bounds__(512) void gemm256(
    const __hip_bfloat16* __restrict__ A, const __hip_bfloat16* __restrict__ Bw,
    const float* __restrict__ bias, void* __restrict__ Cout,
    const __hip_bfloat16* __restrict__ padrow, int M, int N, int K) {
    __shared__ alignas(16) short As[2][256 * 64];
    __shared__ alignas(16) short Bs[2][256 * 64];
    const int tid = threadIdx.x;
    const int lane = tid & 63;
    const int wid = tid >> 6;
    const int wr = wid >> 2, wc = wid & 3;
    const int n0 = blockIdx.x * 256, m0 = blockIdx.y * 256;   // natural order
    const short* Ag = (const short*)A;
    const short* Bg = (const short*)Bw;
    const short* pad = (const short*)padrow;

    f32x4 acc[8][4] = {};

    const int srow_l = tid >> 3;
    const int scol = ((tid & 7) ^ (srow_l & 7)) * 8;
    const int sdst = (tid >> 3) * 64 + (tid & 7) * 8;

    auto stage = [&](int buf, int kt) {
        const int k0 = kt * 64;
#pragma unroll
        for (int j = 0; j < 4; ++j) {
            const int row = j * 64 + srow_l;
            const short* asrc = Ag + (long)(m0 + row) * K + k0 + scol;
            gload_lds16(asrc, &As[buf][j * 4096 + sdst]);
            int n = n0 + row;
            const short* bsrc = (NBOUND && n >= N) ? (pad + scol) : (Bg + (long)n * K + k0 + scol);
            gload_lds16(bsrc, &Bs[buf][j * 4096 + sdst]);
        }
    };

    const int rsel = lane & 15, hi = (lane >> 4) * 8;
    const int xorc = (rsel & 7) << 3;

    stage(0, 0);
    const int NT = K >> 6;
    for (int t = 0; t < NT; ++t) {
        const int cur = t & 1;
        if (t + 1 < NT) {
            stage(cur ^ 1, t + 1);
            asm volatile("s_waitcnt vmcnt(8)" ::: "memory");
        } else {
            asm volatile("s_waitcnt vmcnt(0)" ::: "memory");
        }
        __builtin_amdgcn_s_barrier();
        __builtin_amdgcn_sched_barrier(0);
        short8 bg[2][2][2];
#pragma unroll
        for (int nh = 0; nh < 2; ++nh)
#pragma unroll
            for (int i = 0; i < 2; ++i) {
                const int row = wc * 64 + nh * 32 + i * 16 + rsel;
#pragma unroll
                for (int ks = 0; ks < 2; ++ks)
                    bg[nh][i][ks] = *(const short8*)&Bs[cur][row * 64 + ((ks * 32 + hi) ^ xorc)];
            }
#pragma unroll
        for (int mh = 0; mh < 2; ++mh) {
            short8 af[4][2];
#pragma unroll
            for (int i = 0; i < 4; ++i) {
                const int row = wr * 128 + mh * 64 + i * 16 + rsel;
#pragma unroll
                for (int ks = 0; ks < 2; ++ks)
                    af[i][ks] = *(const short8*)&As[cur][row * 64 + ((ks * 32 + hi) ^ xorc)];
            }
            __builtin_amdgcn_s_setprio(1);
#pragma unroll
            for (int nh = 0; nh < 2; ++nh)
#pragma unroll
                for (int i = 0; i < 4; ++i)
#pragma unroll
                    for (int jn = 0; jn < 2; ++jn)
#pragma unroll
                        for (int ks = 0; ks < 2; ++ks)
                            acc[mh * 4 + i][nh * 2 + jn] = __builtin_amdgcn_mfma_f32_16x16x32_bf16(
                                af[i][ks], bg[nh][jn][ks], acc[mh * 4 + i][nh * 2 + jn], 0, 0, 0);
            __builtin_amdgcn_s_setprio(0);
            __builtin_amdgcn_sched_barrier(0);
        }
        __builtin_amdgcn_s_barrier();
        __builtin_amdgcn_sched_barrier(0);
    }

    const int rg = (lane >> 4) * 4;
    float* Cf = (float*)Cout;
    __hip_bfloat16* Cb = (__hip_bfloat16*)Cout;
#pragma unroll
    for (int ni = 0; ni < 4; ++ni) {
        int col = n0 + wc * 64 + ni * 16 + rsel;
        if (NBOUND && col >= N) continue;
        float bi = bias ? bias[col] : 0.f;
#pragma unroll
        for (int mi = 0; mi < 8; ++mi) {
            int row = m0 + wr * 128 + mi * 16 + rg;
            f32x4 v = acc[mi][ni];
#pragma unroll
            for (int q = 0; q < 4; ++q) {
                long idx = (long)(row + q) * N + col;
                float x = v[q] + bi;
                if (OUTF32) Cf[idx] = x;
                else Cb[idx] = f2bf(x);
            }
        }
    }
}

// ---------------- launcher ----------------

extern "C" void kernel_launch(void* const* d_in, const int* in_sizes, int n_in,
                              void* d_out, int out_size, void* d_ws, size_t ws_size,
                              hipStream_t stream) {
    const int* tgt = (const int*)d_in[0];
    const float* enc_conved = (const float*)d_in[1];
    const float* enc_combined = (const float*)d_in[2];
    const float* tok_emb = (const float*)d_in[3];
    const float* pos_emb = (const float*)d_in[4];
    const float* w_e2h = (const float*)d_in[5];
    const float* b_e2h = (const float*)d_in[6];
    const float* w_h2e = (const float*)d_in[7];
    const float* b_h2e = (const float*)d_in[8];
    const float* w_ah2e = (const float*)d_in[9];
    const float* b_ah2e = (const float*)d_in[10];
    const float* w_ae2h = (const float*)d_in[11];
    const float* b_ae2h = (const float*)d_in[12];
    const float* w_fc = (const float*)d_in[13];
    const float* b_fc = (const float*)d_in[14];
    const float* conv_w = (const float*)d_in[15];
    const float* conv_b = (const float*)d_in[16];

    char* ws = (char*)d_ws;
    size_t off = 0;
    auto alloc = [&](size_t bytes) { size_t r = off; off = (off + bytes + 255) & ~(size_t)255; return r; };
    __hip_bfloat16* emb    = (__hip_bfloat16*)(ws + alloc((size_t)Mn * En * 2));
    __hip_bfloat16* embA   = (__hip_bfloat16*)(ws + alloc((size_t)Mn * En * 2));
    __hip_bfloat16* convinP= (__hip_bfloat16*)(ws + alloc((size_t)Bn * TP * Hn * 2));  // padded
    __hip_bfloat16* conved = (__hip_bfloat16*)(ws + alloc((size_t)Mn * Hn * 2));
    size_t o_en = alloc((size_t)Mn * Sn * 4);
    float* energy = (float*)(ws + o_en);
    __hip_bfloat16* encm = (__hip_bfloat16*)(ws + o_en);   // overlay: prep-only bf16(enc_combined)
    __hip_bfloat16* attnbf = (__hip_bfloat16*)(ws + alloc((size_t)Mn * Sn * 2));
    __hip_bfloat16* wT_e2h = (__hip_bfloat16*)(ws + alloc((size_t)Hn * En * 2));
    __hip_bfloat16* wT_h2e = (__hip_bfloat16*)(ws + alloc((size_t)En * Hn * 2));
    __hip_bfloat16* wT_ae2h= (__hip_bfloat16*)(ws + alloc((size_t)Hn * En * 2));
    __hip_bfloat16* wbAH   = (__hip_bfloat16*)(ws + alloc((size_t)Hn * En * 2));
    __hip_bfloat16* wT_fc  = (__hip_bfloat16*)(ws + alloc((size_t)Vn * En * 2));
    __hip_bfloat16* encc   = (__hip_bfloat16*)(ws + alloc((size_t)Bn * Sn * En * 2));
    __hip_bfloat16* encAH  = (__hip_bfloat16*)(ws + alloc((size_t)Bn * Sn * Hn * 2));
    __hip_bfloat16* encCW  = (__hip_bfloat16*)(ws + alloc((size_t)Bn * Hn * Sn * 2));
    float* embE            = (float*)(ws + alloc((size_t)Mn * Sn * 4));
    __hip_bfloat16* padrow = (__hip_bfloat16*)(ws + alloc(256));
    __hip_bfloat16* wpack  = (__hip_bfloat16*)(ws + alloc((size_t)2 * Hn * 3 * Hn * 2)); // per-layer, warm
    __hip_bfloat16* tmpE = conved;  // overlay: conved dead after last update GEMM
    __hip_bfloat16* convinD = convinP + 2 * Hn;   // data rows base (skip 2 pads of batch 0)

    float* out = (float*)d_out;
    float* attn_out = out + (long)Mn * Vn;
    const long bSq = (long)Sn * Sn;
    const long bSH = (long)Sn * Hn;
    const long bTH = (long)Tn * Hn;
    const long bTE = (long)Tn * En;
    const long bPH = (long)TP * Hn;   // padded per-batch stride

    dim3 tb(32, 8);
    const __hip_bfloat16* nb = nullptr;
    const float* nf = nullptr;

    // ---- prep ----
    padfill_kernel<<<1, 128, 0, stream>>>(padrow);
    padrows_kernel<<<2 * Bn, 256, 0, stream>>>(convinP);
    embed_kernel<<<Mn, 128, 0, stream>>>(tgt, tok_emb, pos_emb, b_ah2e, emb, embA);
    transpose_f32_bf16<<<dim3(Hn / 32, En / 32, 1), tb, 0, stream>>>(w_e2h, wT_e2h, En, Hn, 0, 0);
    transpose_f32_bf16<<<dim3(En / 32, Hn / 32, 1), tb, 0, stream>>>(w_h2e, wT_h2e, Hn, En, 0, 0);
    transpose_f32_bf16<<<dim3(Hn / 32, En / 32, 1), tb, 0, stream>>>(w_ae2h, wT_ae2h, En, Hn, 0, 0);
    transpose_f32_bf16<<<dim3((Vn + 31) / 32, En / 32, 1), tb, 0, stream>>>(w_fc, wT_fc, En, Vn, 0, 0);
    convert_bf16_kernel<<<((long)Hn * En / 4 + 255) / 256, 256, 0, stream>>>(w_ah2e, wbAH, (long)Hn * En / 4);
    convert_bf16_kernel<<<((long)Bn * Sn * En / 4 + 255) / 256, 256, 0, stream>>>(enc_conved, encc, (long)Bn * Sn * En / 4);
    convert_bf16_kernel<<<((long)Bn * Sn * En / 4 + 255) / 256, 256, 0, stream>>>(enc_combined, encm, (long)Bn * Sn * En / 4);

    // encAH[b][s][h] = encc[b] @ w_ah2e^T   (layer-invariant attention factor)
    gemm_bf16<0, false, false><<<dim3(Hn / 128, Sn / 128, Bn), 256, 0, stream>>>(
        encc, wbAH, nullptr, encAH, nb, nb, nf, padrow, Sn, Hn, En, bSq, 0, bSH, 0, 1.f, 1.f);
    // encCW[b][h][s] = (enc_combined[b] @ w_ae2h)^T
    gemm_bf16<0, false, false><<<dim3(Sn / 128, Hn / 128, Bn), 256, 0, stream>>>(
        wT_ae2h, encm, nullptr, encCW, nb, nb, nf, padrow, Hn, Sn, En, 0, bSq, bSH, 0, 1.f, 1.f);
    // embE[b][t][s] = embA[b] @ encc[b]^T   (f32; kScale folded into embA)  [64-tile]
    gemm64<0, true><<<dim3(Sn / 128, Tn / 64, Bn), 256, 0, stream>>>(
        embA, encc, nullptr, embE, nb, nb, nf, Sn, En, bTE, bSq, bSq, 0, 1.f, 1.f);
    // conv_input = embedded @ emb2hid + b   -> padded buffer (batched, rows +2)
    gemm_bf16<0, false, false><<<dim3(Hn / 128, Tn / 128, Bn), 256, 0, stream>>>(
        emb, wT_e2h, b_e2h, convinD, nb, nb, nf, padrow, Tn, Hn, En, bTE, 0, bPH, 0, 1.f, 1.f);

    for (int l = 0; l < Ln; ++l) {
        // pack conv weight for THIS layer just before use (keeps B-panel L2/L3-warm)
        wpack2_kernel<<<2 * Hn, 256, 0, stream>>>(conv_w, wpack, l);
        // conved = GLU(conv(convinP) + conv_b[l])   [8192,1024], 512x128 tiles, 2-row halo
        conv_glu_kernel<<<dim3(2 * Hn / 128, Mn / 512), 512, 0, stream>>>(
            convinP, wpack, conv_b + (long)l * 2 * Hn, conved);
        // energy[b] = kScale * conved[b] @ encAH[b]^T + embE[b]   (f32) [64-tile]
        gemm64<3, true><<<dim3(Sn / 128, Tn / 64, Bn), 256, 0, stream>>>(
            conved, encAH, nullptr, energy, nb, nb, embE, Sn, Hn, bTH, bSH, bSq, bSq, kScale, 1.f);
        // attention = softmax(energy)  (f32 out only needed from the LAST layer)
        softmax_kernel<<<Mn, 256, 0, stream>>>(energy, (l == Ln - 1) ? attn_out : nullptr, attnbf);
        // conv_input = ((attn @ encCW + b_ae2h + conved)*s + conv_input)*s  (C/R2 padded)
        gemm_bf16<2, false, false><<<dim3(Hn / 128, Tn / 128, Bn), 256, 0, stream>>>(
            attnbf, encCW, b_ae2h, convinD, conved, convinD, nf, padrow,
            Tn, Hn, Sn, bSq, bSH, bPH, bTH, kScale, kScale);
    }

    // conved = conv_input @ hid2emb + b   [8192,512]  (A padded, batched)  [64-tile]
    gemm64<0, false><<<dim3(En / 128, Tn / 64, Bn), 256, 0, stream>>>(
        convinD, wT_h2e, b_h2e, tmpE, nb, nb, nf, En, Hn, bPH, 0, bTE, 0, 1.f, 1.f);
    // output = conved @ fc_out + b        [8192,10000] f32, N-bounded  (256² coarse)
    gemm256<true, true><<<dim3((Vn + 255) / 256, Mn / 256), 512, 0, stream>>>(
        tmpE, wT_fc, b_fc, out, padrow, Mn, Vn, En);
}

// Round 16
// 1213.101 us; speedup vs baseline: 1.1981x; 1.0070x over previous
//
#include <hip/hip_runtime.h>
#include <hip/hip_bf16.h>

typedef __attribute__((ext_vector_type(4))) float f32x4;
typedef __attribute__((ext_vector_type(8))) short short8;

#define DEVFN __device__ __forceinline__

static constexpr int Bn = 16, Tn = 512, Sn = 512, Vn = 10000, En = 512, Hn = 1024, Ln = 6;
static constexpr int Mn = Bn * Tn;  // 8192 token rows
static constexpr int TP = Tn + 2;   // padded sequence rows (2 causal PAD rows)
static constexpr float kScale = 0.70710678118654752440f;

DEVFN float bf2f(__hip_bfloat16 x) { return __bfloat162float(x); }
DEVFN __hip_bfloat16 f2bf(float x) { return __float2bfloat16(x); }

struct bf16x4 { __hip_bfloat16 x, y, z, w; };

// async global -> LDS, 16B per lane (wave-uniform LDS base + lane*16 layout)
DEVFN void gload_lds16(const short* g, short* l) {
    __builtin_amdgcn_global_load_lds((const __attribute__((address_space(1))) void*)g,
                                     (__attribute__((address_space(3))) void*)l, 16, 0, 0);
}

// ---------------- prep kernels ----------------

// embedded[b,t,:] = tok_emb[tgt[b,t],:] + pos_emb[t,:]  (bf16)
// embA = embedded + b_ah2e  (bf16, UNSCALED; kScale applied in energy epilogue)
// blocks 0..31 also fill one causal PAD row of convinP; block 32 fills padrow.
__global__ void embed_kernel(const int* __restrict__ tgt, const float* __restrict__ tok,
                             const float* __restrict__ pos, const float* __restrict__ bah,
                             __hip_bfloat16* __restrict__ out, __hip_bfloat16* __restrict__ outA,
                             __hip_bfloat16* __restrict__ convinP, __hip_bfloat16* __restrict__ padrow) {
    int row = blockIdx.x;              // 0..8191
    int t = row & (Tn - 1);
    int v = tgt[row];
    const float* tr = tok + (long)v * En;
    const float* pr = pos + (long)t * En;
    int e = threadIdx.x * 4;           // block 128 covers 512
    float4 a = *(const float4*)(tr + e);
    float4 b = *(const float4*)(pr + e);
    float4 bb = *(const float4*)(bah + e);
    bf16x4 o{f2bf(a.x + b.x), f2bf(a.y + b.y), f2bf(a.z + b.z), f2bf(a.w + b.w)};
    *(bf16x4*)(out + (long)row * En + e) = o;
    bf16x4 oa{f2bf(a.x + b.x + bb.x), f2bf(a.y + b.y + bb.y),
              f2bf(a.z + b.z + bb.z), f2bf(a.w + b.w + bb.w)};
    *(bf16x4*)(outA + (long)row * En + e) = oa;
    if (row < 32) {                    // fill one PAD row of convinP with 1.0
        long base = ((long)(row >> 1) * TP + (row & 1)) * Hn;
        int e8 = threadIdx.x * 8;
        bf16x4 vv{f2bf(1.f), f2bf(1.f), f2bf(1.f), f2bf(1.f)};
        *(bf16x4*)(convinP + base + e8) = vv;
        *(bf16x4*)(convinP + base + e8 + 4) = vv;
    } else if (row == 32) {
        padrow[threadIdx.x] = f2bf(1.f);   // 128-entry PAD row for NBOUND fallbacks
    }
}

// dst[c][r] = bf16(src[r][c]); src is [R][C] f32. grid(ceil(C/32), ceil(R/32), Z), block(32,8)
__global__ void transpose_f32_bf16(const float* __restrict__ src, __hip_bfloat16* __restrict__ dst,
                                   int R, int C, long sZi, long sZo) {
    __shared__ float tile[32][33];
    src += (long)blockIdx.z * sZi;
    dst += (long)blockIdx.z * sZo;
    int c0 = blockIdx.x * 32, r0 = blockIdx.y * 32;
    for (int i = threadIdx.y; i < 32; i += 8) {
        int r = r0 + i, c = c0 + threadIdx.x;
        tile[i][threadIdx.x] = (r < R && c < C) ? src[(long)r * C + c] : 0.f;
    }
    __syncthreads();
    for (int i = threadIdx.y; i < 32; i += 8) {
        int c = c0 + i, r = r0 + threadIdx.x;
        if (c < C && r < R) dst[(long)c * R + r] = f2bf(tile[threadIdx.x][i]);
    }
}

// three f32->bf16 converts in one dispatch (each n4 = element_count/4)
__global__ void convert3_kernel(const float* __restrict__ s0, __hip_bfloat16* __restrict__ d0, long a0,
                                const float* __restrict__ s1, __hip_bfloat16* __restrict__ d1, long a1,
                                const float* __restrict__ s2, __hip_bfloat16* __restrict__ d2, long a2) {
    long i = (long)blockIdx.x * blockDim.x + threadIdx.x;
    const float* s; __hip_bfloat16* d; long off;
    if (i < a0) { s = s0; d = d0; off = i; }
    else if (i < a0 + a1) { s = s1; d = d1; off = i - a0; }
    else if (i < a0 + a1 + a2) { s = s2; d = d2; off = i - a0 - a1; }
    else return;
    long j = off * 4;
    float4 v = *(const float4*)(s + j);
    bf16x4 o{f2bf(v.x), f2bf(v.y), f2bf(v.z), f2bf(v.w)};
    *(bf16x4*)(d + j) = o;
}

// Coalesced conv-weight pack for layer l, a/g interleaved in 16-col blocks for fused GLU.
__global__ __launch_bounds__(256) void wpack2_kernel(const float* __restrict__ convw,
                                                     __hip_bfloat16* __restrict__ wp, int l) {
    __shared__ float row[3 * Hn];
    int c = blockIdx.x;                        // 0..2047 packed col
    int grp = c >> 5, w = c & 31;
    int o = (w < 16) ? grp * 16 + w : Hn + grp * 16 + (w - 16);
    const float* src = convw + ((long)(l * 2 * Hn + o)) * (Hn * 3);
#pragma unroll
    for (int j = 0; j < 3; ++j) {
        int idx = (j * 256 + threadIdx.x) * 4;
        *(float4*)&row[idx] = *(const float4*)(src + idx);
    }
    __syncthreads();
    __hip_bfloat16* dst = wp + (long)c * (3 * Hn);
#pragma unroll
    for (int j = 0; j < 3; ++j) {
        int kk = (j * 256 + threadIdx.x) * 4;   // 4-chunk never crosses a tap boundary
        int tap = kk >> 10;
        int i = kk & (Hn - 1);
        bf16x4 v{f2bf(row[i * 3 + tap]), f2bf(row[(i + 1) * 3 + tap]),
                 f2bf(row[(i + 2) * 3 + tap]), f2bf(row[(i + 3) * 3 + tap])};
        *(bf16x4*)(dst + kk) = v;
    }
}

// row softmax over S=512; writes bf16 (next GEMM input) + optional f32 (final attention)
__global__ __launch_bounds__(256) void softmax_kernel(const float* __restrict__ energy,
                                                      float* __restrict__ attn_f32,
                                                      __hip_bfloat16* __restrict__ attn_bf) {
    int row = blockIdx.x;  // 0..8191
    const float* e = energy + (long)row * Sn;
    int tid = threadIdx.x;
    float v0 = e[tid], v1 = e[tid + 256];
    float m = fmaxf(v0, v1);
    for (int off = 32; off; off >>= 1) m = fmaxf(m, __shfl_xor(m, off));
    __shared__ float redm[4];
    __shared__ float reds[4];
    int lane = tid & 63, w = tid >> 6;
    if (lane == 0) redm[w] = m;
    __syncthreads();
    m = fmaxf(fmaxf(redm[0], redm[1]), fmaxf(redm[2], redm[3]));
    float x0 = __expf(v0 - m), x1 = __expf(v1 - m);
    float s = x0 + x1;
    for (int off = 32; off; off >>= 1) s += __shfl_xor(s, off);
    if (lane == 0) reds[w] = s;
    __syncthreads();
    s = reds[0] + reds[1] + reds[2] + reds[3];
    float inv = 1.f / s;
    long base = (long)row * Sn;
    if (attn_f32) {
        attn_f32[base + tid] = x0 * inv;
        attn_f32[base + tid + 256] = x1 * inv;
    }
    attn_bf[base + tid] = f2bf(x0 * inv);
    attn_bf[base + tid + 256] = f2bf(x1 * inv);
}

// ---------------- 128x128 counted-vmcnt GEMM ----------------
// C[M,N] = A[M,K] @ Bw[N,K]^T. Per K-tile {stage(nxt); vmcnt(4); s_barrier;
// frags+MFMA; s_barrier}. EPI: 0: x=acc+bias; 1: x=(acc+bias+R1)*s1;
// 2: x=((acc+bias+R1)*s1+R2)*s2.
template <int EPI, bool OUTF32, bool NBOUND>
__global__ __launch_bounds__(256) void gemm_bf16(
    const __hip_bfloat16* __restrict__ A, const __hip_bfloat16* __restrict__ Bw,
    const float* __restrict__ bias, void* __restrict__ Cout,
    const __hip_bfloat16* __restrict__ R1, const __hip_bfloat16* __restrict__ R2,
    const __hip_bfloat16* __restrict__ padrow,
    int M, int N, int K, long aZ, long bZ, long cZ, long r1Z, float s1, float s2) {
    __shared__ alignas(16) short As[2][128 * 32];
    __shared__ alignas(16) short Bs[2][128 * 32];
    const int tid = threadIdx.x;
    const int lane = tid & 63;
    const int wid = tid >> 6;
    const int wr = wid >> 1, wc = wid & 1;
    const int m0 = blockIdx.y * 128, n0 = blockIdx.x * 128;
    const short* Ag = (const short*)A + (long)blockIdx.z * aZ;
    const short* Bg = (const short*)Bw + (long)blockIdx.z * bZ;
    const short* pad = (const short*)padrow;

    f32x4 acc[4][4] = {};

    const int rc = tid >> 2;
    const int k8 = (tid & 3) * 8;

    auto stage = [&](int buf, int k0) {
#pragma unroll
        for (int j = 0; j < 2; ++j) {
            int r = rc + j * 64;
            const short* asrc = Ag + (long)(m0 + r) * K + k0 + k8;
            gload_lds16(asrc, &As[buf][r * 32 + k8]);
            int n = n0 + r;
            const short* bsrc = (NBOUND && n >= N) ? (pad + k8) : (Bg + (long)n * K + k0 + k8);
            gload_lds16(bsrc, &Bs[buf][r * 32 + k8]);
        }
    };

    const int rsel = lane & 15, hi = (lane >> 4) * 8;

    stage(0, 0);
    const int NT = K >> 5;
    for (int t = 0; t < NT; ++t) {
        const int cur = t & 1;
        if (t + 1 < NT) {
            stage(cur ^ 1, (t + 1) * 32);                       // 4 loads, stay in flight
            asm volatile("s_waitcnt vmcnt(4)" ::: "memory");    // tile t's 4 loads done
        } else {
            asm volatile("s_waitcnt vmcnt(0)" ::: "memory");
        }
        __builtin_amdgcn_s_barrier();                           // tile t visible to all waves
        __builtin_amdgcn_sched_barrier(0);
        short8 af[4], bg[4];
#pragma unroll
        for (int mi = 0; mi < 4; ++mi)
            af[mi] = *(const short8*)&As[cur][(wr * 64 + mi * 16 + rsel) * 32 + hi];
#pragma unroll
        for (int ni = 0; ni < 4; ++ni)
            bg[ni] = *(const short8*)&Bs[cur][(wc * 64 + ni * 16 + rsel) * 32 + hi];
        __builtin_amdgcn_s_setprio(1);
#pragma unroll
        for (int mi = 0; mi < 4; ++mi)
#pragma unroll
            for (int ni = 0; ni < 4; ++ni)
                acc[mi][ni] = __builtin_amdgcn_mfma_f32_16x16x32_bf16(af[mi], bg[ni], acc[mi][ni], 0, 0, 0);
        __builtin_amdgcn_s_setprio(0);
        __builtin_amdgcn_s_barrier();                           // reads of cur done before reuse
        __builtin_amdgcn_sched_barrier(0);
    }

    const int rg = (lane >> 4) * 4;
    float* Cf = (float*)Cout + (long)blockIdx.z * cZ;
    __hip_bfloat16* Cb = (__hip_bfloat16*)Cout + (long)blockIdx.z * cZ;
    const __hip_bfloat16* R1z = R1 + (long)blockIdx.z * r1Z;
    const __hip_bfloat16* R2z = R2 + (long)blockIdx.z * cZ;
#pragma unroll
    for (int ni = 0; ni < 4; ++ni) {
        int col = n0 + wc * 64 + ni * 16 + rsel;
        if (NBOUND && col >= N) continue;
        float bi = bias ? bias[col] : 0.f;
#pragma unroll
        for (int mi = 0; mi < 4; ++mi) {
            int row = m0 + wr * 64 + mi * 16 + rg;
            f32x4 v = acc[mi][ni];
#pragma unroll
            for (int q = 0; q < 4; ++q) {
                long idx = (long)(row + q) * N + col;
                float x = v[q] + bi;
                if (EPI >= 1) x = (x + bf2f(R1z[idx])) * s1;
                if (EPI >= 2) x = (x + bf2f(R2z[idx])) * s2;
                if (OUTF32) Cf[idx] = x;
                else Cb[idx] = f2bf(x);
            }
        }
    }
}

// ---------------- 64x128 high-occupancy GEMM (grid-limited batched ops) ----------------
// EPI: 0: x=acc+bias; 1: x=(acc+bias+R1)*s1.
template <int EPI, bool OUTF32>
__global__ __launch_bounds__(256) void gemm64(
    const __hip_bfloat16* __restrict__ A, const __hip_bfloat16* __restrict__ Bw,
    const float* __restrict__ bias, void* __restrict__ Cout,
    const __hip_bfloat16* __restrict__ R1,
    int N, int K, long aZ, long bZ, long cZ, long r1Z, float s1) {
    __shared__ alignas(16) short As[2][64 * 32];
    __shared__ alignas(16) short Bs[2][128 * 32];
    const int tid = threadIdx.x;
    const int lane = tid & 63;
    const int wid = tid >> 6;      // wave owns N-slice wid*32
    const int m0 = blockIdx.y * 64, n0 = blockIdx.x * 128;
    const short* Ag = (const short*)A + (long)blockIdx.z * aZ;
    const short* Bg = (const short*)Bw + (long)blockIdx.z * bZ;

    f32x4 acc[4][2] = {};

    const int rc = tid >> 2;       // 0..63
    const int k8 = (tid & 3) * 8;

    auto stage = [&](int buf, int k0) {
        gload_lds16(Ag + (long)(m0 + rc) * K + k0 + k8, &As[buf][rc * 32 + k8]);
#pragma unroll
        for (int j = 0; j < 2; ++j) {
            int r = j * 64 + rc;
            gload_lds16(Bg + (long)(n0 + r) * K + k0 + k8, &Bs[buf][r * 32 + k8]);
        }
    };

    const int rsel = lane & 15, hi = (lane >> 4) * 8;

    stage(0, 0);
    const int NT = K >> 5;
    for (int t = 0; t < NT; ++t) {
        const int cur = t & 1;
        if (t + 1 < NT) {
            stage(cur ^ 1, (t + 1) * 32);                       // 3 loads, stay in flight
            asm volatile("s_waitcnt vmcnt(3)" ::: "memory");    // tile t's 3 loads done
        } else {
            asm volatile("s_waitcnt vmcnt(0)" ::: "memory");
        }
        __builtin_amdgcn_s_barrier();
        __builtin_amdgcn_sched_barrier(0);
        short8 af[4], bg[2];
#pragma unroll
        for (int mi = 0; mi < 4; ++mi)
            af[mi] = *(const short8*)&As[cur][(mi * 16 + rsel) * 32 + hi];
#pragma unroll
        for (int ni = 0; ni < 2; ++ni)
            bg[ni] = *(const short8*)&Bs[cur][(wid * 32 + ni * 16 + rsel) * 32 + hi];
        __builtin_amdgcn_s_setprio(1);
#pragma unroll
        for (int mi = 0; mi < 4; ++mi)
#pragma unroll
            for (int ni = 0; ni < 2; ++ni)
                acc[mi][ni] = __builtin_amdgcn_mfma_f32_16x16x32_bf16(af[mi], bg[ni], acc[mi][ni], 0, 0, 0);
        __builtin_amdgcn_s_setprio(0);
        __builtin_amdgcn_s_barrier();
        __builtin_amdgcn_sched_barrier(0);
    }

    const int rg = (lane >> 4) * 4;
    float* Cf = (float*)Cout + (long)blockIdx.z * cZ;
    __hip_bfloat16* Cb = (__hip_bfloat16*)Cout + (long)blockIdx.z * cZ;
    const __hip_bfloat16* R1z = R1 + (long)blockIdx.z * r1Z;
#pragma unroll
    for (int ni = 0; ni < 2; ++ni) {
        int col = n0 + wid * 32 + ni * 16 + rsel;
        float bi = bias ? bias[col] : 0.f;
#pragma unroll
        for (int mi = 0; mi < 4; ++mi) {
            int row = m0 + mi * 16 + rg;
            f32x4 v = acc[mi][ni];
#pragma unroll
            for (int q = 0; q < 4; ++q) {
                long idx = (long)(row + q) * N + col;
                float x = v[q] + bi;
                if (EPI >= 1) x = (x + bf2f(R1z[idx])) * s1;
                if (OUTF32) Cf[idx] = x;
                else Cb[idx] = f2bf(x);
            }
        }
    }
}

// ---------------- conv+GLU kernel: M=512 (one padded sequence) x N=128 ----------------
// C = GLU(conv(convinP) + b). 8 waves (4Mx2N), wave tile 128x64, BK=32 over H.
// A staged once per tile (514 rows incl. 2-row causal halo = real pad rows);
// per-wave counted vmcnt: wave0=8 (extra partial round), others=7.
__global__ __launch_bounds__(512) void conv_glu_kernel(
    const __hip_bfloat16* __restrict__ Ain,   // convinP [16][514][1024]
    const __hip_bfloat16* __restrict__ Bw,    // wpack [2048][3072]
    const float* __restrict__ bias, __hip_bfloat16* __restrict__ Cout) {
    __shared__ alignas(16) short As[2][516 * 32];      // 2 x 33 KB
    __shared__ alignas(16) short Bs[2][3 * 128 * 32];  // 2 x 24 KB
    const int tid = threadIdx.x;
    const int lane = tid & 63;
    const int wid = tid >> 6;
    const int wr = wid >> 1, wc = wid & 1;             // 4M x 2N
    const int n0 = blockIdx.x * 128;                   // 16 N-blocks
    const int m0 = blockIdx.y * 512;                   // 16 M-blocks = sequences
    const int seqbase = blockIdx.y * TP;               // padded row of LDS row 0
    const short* Ag = (const short*)Ain;
    const short* Bg = (const short*)Bw;

    f32x4 acc[8][4] = {};

    const int srow = tid >> 2;                  // row within 128-row staging round
    const int skey = (tid >> 3) & 3;            // (row>>1)&3 within round
    const int scol = ((tid & 3) ^ skey) * 8;    // inverse-swizzled global col (elems)
    const int sdst = tid * 8;                   // linear LDS elems per round

    auto stageA = [&](int buf, int kt) {
        const int k0 = kt * 32;
#pragma unroll
        for (int j = 0; j < 4; ++j) {           // rows 0..511
            int r = j * 128 + srow;
            gload_lds16(Ag + (long)(seqbase + r) * Hn + k0 + scol, &As[buf][j * 4096 + sdst]);
        }
        if (tid < 8) {                          // rows 512,513 (wave 0 only; skey==0 here)
            int r = 512 + (tid >> 2);
            gload_lds16(Ag + (long)(seqbase + r) * Hn + k0 + (tid & 3) * 8,
                        &As[buf][4 * 4096 + sdst]);
        }
    };
    auto stageB = [&](int buf, int kt) {
        const int k0 = kt * 32;
#pragma unroll
        for (int tap = 0; tap < 3; ++tap)
            gload_lds16(Bg + (long)(n0 + srow) * 3072 + tap * 1024 + k0 + scol,
                        &Bs[buf][tap * 4096 + sdst]);
    };

    const int rsel = lane & 15, hi = (lane >> 4) * 8;

    stageA(0, 0); stageB(0, 0);                 // wave0: 8 loads, others: 7
    for (int t = 0; t < 32; ++t) {
        const int cur = t & 1;
        if (t + 1 < 32) {
            stageA(cur ^ 1, t + 1); stageB(cur ^ 1, t + 1);
            if (wid == 0) asm volatile("s_waitcnt vmcnt(8)" ::: "memory");  // tile t's loads done
            else          asm volatile("s_waitcnt vmcnt(7)" ::: "memory");
        } else {
            asm volatile("s_waitcnt vmcnt(0)" ::: "memory");
        }
        __builtin_amdgcn_s_barrier();
        __builtin_amdgcn_sched_barrier(0);
#pragma unroll
        for (int tap = 0; tap < 3; ++tap) {
            short8 bg[4];
#pragma unroll
            for (int ni = 0; ni < 4; ++ni) {
                int row = wc * 64 + ni * 16 + rsel;
                int xk = ((row >> 1) & 3) << 3;
                bg[ni] = *(const short8*)&Bs[cur][tap * 4096 + row * 32 + (hi ^ xk)];
            }
#pragma unroll
            for (int mh = 0; mh < 2; ++mh) {
                short8 af[4];
#pragma unroll
                for (int i = 0; i < 4; ++i) {
                    int row = wr * 128 + mh * 64 + i * 16 + rsel + tap;  // LDS row = local_m + tap
                    int xk = ((row >> 1) & 3) << 3;
                    af[i] = *(const short8*)&As[cur][row * 32 + (hi ^ xk)];
                }
                __builtin_amdgcn_s_setprio(1);
#pragma unroll
                for (int i = 0; i < 4; ++i)
#pragma unroll
                    for (int ni = 0; ni < 4; ++ni)
                        acc[mh * 4 + i][ni] = __builtin_amdgcn_mfma_f32_16x16x32_bf16(
                            af[i], bg[ni], acc[mh * 4 + i][ni], 0, 0, 0);
                __builtin_amdgcn_s_setprio(0);
                __builtin_amdgcn_sched_barrier(0);
            }
        }
        __builtin_amdgcn_s_barrier();
        __builtin_amdgcn_sched_barrier(0);
    }

    // fused GLU epilogue: ni pairs (0,1) and (2,3) are (a,g) of the same 32-col group
    const int rg = (lane >> 4) * 4;
    const int No = Hn;
#pragma unroll
    for (int p = 0; p < 2; ++p) {
        int jcol = ((n0 + wc * 64) >> 1) + p * 16 + rsel;
        float ba = bias[jcol];
        float bgv = bias[Hn + jcol];
#pragma unroll
        for (int mi = 0; mi < 8; ++mi) {
            int row = m0 + wr * 128 + mi * 16 + rg;
            f32x4 va = acc[mi][2 * p], vg = acc[mi][2 * p + 1];
#pragma unroll
            for (int q = 0; q < 4; ++q) {
                float a = va[q] + ba;
                float g = vg[q] + bgv;
                Cout[(long)(row + q) * No + jcol] = f2bf(a * (1.f / (1.f + __expf(-g))));
            }
        }
    }
}

// ---------------- 256x256 coarse deep-pipeline GEMM (fc_out) ----------------
template <bool OUTF32, bool NBOUND>
__global__ __launch_bounds__(512) void gemm256(
    const __hip_bfloat16* __restrict__ A, const __hip_bfloat16* __restrict__ Bw,
    const float* __restrict__ bias, void* __restrict__ Cout,
    const __hip_bfloat16* __restrict__ padrow, int M, int N, int K) {
    __shared__ alignas(16) short As[2][256 * 64];
    __shared__ alignas(16) short Bs[2][256 * 64];
    const int tid = threadIdx.x;
    const int lane = tid & 63;
    const int wid = tid >> 6;
    const int wr = wid >> 2, wc = wid & 3;
    const int n0 = blockIdx.x * 256, m0 = blockIdx.y * 256;   // natural order
    const short* Ag = (const short*)A;
    const short* Bg = (const short*)Bw;
    const short* pad = (const short*)padrow;

    f32x4 acc[8][4] = {};

    const int srow_l = tid >> 3;
    const int scol = ((tid & 7) ^ (srow_l & 7)) * 8;
    const int sdst = (tid >> 3) * 64 + (tid & 7) * 8;

    auto stage = [&](int buf, int kt) {
        const int k0 = kt * 64;
#pragma unroll
        for (int j = 0; j < 4; ++j) {
            const int row = j * 64 + srow_l;
            const short* asrc = Ag + (long)(m0 + row) * K + k0 + scol;
            gload_lds16(asrc, &As[buf][j * 4096 + sdst]);
            int n = n0 + row;
            const short* bsrc = (NBOUND && n >= N) ? (pad + scol) : (Bg + (long)n * K + k0 + scol);
            gload_lds16(bsrc, &Bs[buf][j * 4096 + sdst]);
        }
    };

    const int rsel = lane & 15, hi = (lane >> 4) * 8;
    const int xorc = (rsel & 7) << 3;

    stage(0, 0);
    const int NT = K >> 6;
    for (int t = 0; t < NT; ++t) {
        const int cur = t & 1;
        if (t + 1 < NT) {
            stage(cur ^ 1, t + 1);
            asm volatile("s_waitcnt vmcnt(8)" ::: "memory");
        } else {
            asm volatile("s_waitcnt vmcnt(0)" ::: "memory");
        }
        __builtin_amdgcn_s_barrier();
        __builtin_amdgcn_sched_barrier(0);
        short8 bg[2][2][2];
#pragma unroll
        for (int nh = 0; nh < 2; ++nh)
#pragma unroll
            for (int i = 0; i < 2; ++i) {
                const int row = wc * 64 + nh * 32 + i * 16 + rsel;
#pragma unroll
                for (int ks = 0; ks < 2; ++ks)
                    bg[nh][i][ks] = *(const short8*)&Bs[cur][row * 64 + ((ks * 32 + hi) ^ xorc)];
            }
#pragma unroll
        for (int mh = 0; mh < 2; ++mh) {
            short8 af[4][2];
#pragma unroll
            for (int i = 0; i < 4; ++i) {
                const int row = wr * 128 + mh * 64 + i * 16 + rsel;
#pragma unroll
                for (int ks = 0; ks < 2; ++ks)
                    af[i][ks] = *(const short8*)&As[cur][row * 64 + ((ks * 32 + hi) ^ xorc)];
            }
            __builtin_amdgcn_s_setprio(1);
#pragma unroll
            for (int nh = 0; nh < 2; ++nh)
#pragma unroll
                for (int i = 0; i < 4; ++i)
#pragma unroll
                    for (int jn = 0; jn < 2; ++jn)
#pragma unroll
                        for (int ks = 0; ks < 2; ++ks)
                            acc[mh * 4 + i][nh * 2 + jn] = __builtin_amdgcn_mfma_f32_16x16x32_bf16(
                                af[i][ks], bg[nh][jn][ks], acc[mh * 4 + i][nh * 2 + jn], 0, 0, 0);
            __builtin_amdgcn_s_setprio(0);
            __builtin_amdgcn_sched_barrier(0);
        }
        __builtin_amdgcn_s_barrier();
        __builtin_amdgcn_sched_barrier(0);
    }

    const int rg = (lane >> 4) * 4;
    float* Cf = (float*)Cout;
    __hip_bfloat16* Cb = (__hip_bfloat16*)Cout;
#pragma unroll
    for (int ni = 0; ni < 4; ++ni) {
        int col = n0 + wc * 64 + ni * 16 + rsel;
        if (NBOUND && col >= N) continue;
        float bi = bias ? bias[col] : 0.f;
#pragma unroll
        for (int mi = 0; mi < 8; ++mi) {
            int row = m0 + wr * 128 + mi * 16 + rg;
            f32x4 v = acc[mi][ni];
#pragma unroll
            for (int q = 0; q < 4; ++q) {
                long idx = (long)(row + q) * N + col;
                float x = v[q] + bi;
                if (OUTF32) Cf[idx] = x;
                else Cb[idx] = f2bf(x);
            }
        }
    }
}

// ---------------- launcher ----------------

extern "C" void kernel_launch(void* const* d_in, const int* in_sizes, int n_in,
                              void* d_out, int out_size, void* d_ws, size_t ws_size,
                              hipStream_t stream) {
    const int* tgt = (const int*)d_in[0];
    const float* enc_conved = (const float*)d_in[1];
    const float* enc_combined = (const float*)d_in[2];
    const float* tok_emb = (const float*)d_in[3];
    const float* pos_emb = (const float*)d_in[4];
    const float* w_e2h = (const float*)d_in[5];
    const float* b_e2h = (const float*)d_in[6];
    const float* w_h2e = (const float*)d_in[7];
    const float* b_h2e = (const float*)d_in[8];
    const float* w_ah2e = (const float*)d_in[9];
    const float* b_ah2e = (const float*)d_in[10];
    const float* w_ae2h = (const float*)d_in[11];
    const float* b_ae2h = (const float*)d_in[12];
    const float* w_fc = (const float*)d_in[13];
    const float* b_fc = (const float*)d_in[14];
    const float* conv_w = (const float*)d_in[15];
    const float* conv_b = (const float*)d_in[16];

    char* ws = (char*)d_ws;
    size_t off = 0;
    auto alloc = [&](size_t bytes) { size_t r = off; off = (off + bytes + 255) & ~(size_t)255; return r; };
    __hip_bfloat16* emb    = (__hip_bfloat16*)(ws + alloc((size_t)Mn * En * 2));
    __hip_bfloat16* embA   = (__hip_bfloat16*)(ws + alloc((size_t)Mn * En * 2));
    __hip_bfloat16* convinP= (__hip_bfloat16*)(ws + alloc((size_t)Bn * TP * Hn * 2));  // padded
    __hip_bfloat16* conved = (__hip_bfloat16*)(ws + alloc((size_t)Mn * Hn * 2));
    size_t o_en = alloc((size_t)Mn * Sn * 4);
    float* energy = (float*)(ws + o_en);
    __hip_bfloat16* encm = (__hip_bfloat16*)(ws + o_en);   // overlay: prep-only bf16(enc_combined)
    __hip_bfloat16* attnbf = (__hip_bfloat16*)(ws + alloc((size_t)Mn * Sn * 2));
    __hip_bfloat16* wT_e2h = (__hip_bfloat16*)(ws + alloc((size_t)Hn * En * 2));
    __hip_bfloat16* wT_h2e = (__hip_bfloat16*)(ws + alloc((size_t)En * Hn * 2));
    __hip_bfloat16* wT_ae2h= (__hip_bfloat16*)(ws + alloc((size_t)Hn * En * 2));
    __hip_bfloat16* wbAH   = (__hip_bfloat16*)(ws + alloc((size_t)Hn * En * 2));
    __hip_bfloat16* wT_fc  = (__hip_bfloat16*)(ws + alloc((size_t)Vn * En * 2));
    __hip_bfloat16* encc   = (__hip_bfloat16*)(ws + alloc((size_t)Bn * Sn * En * 2));
    __hip_bfloat16* encAH  = (__hip_bfloat16*)(ws + alloc((size_t)Bn * Sn * Hn * 2));
    __hip_bfloat16* encCW  = (__hip_bfloat16*)(ws + alloc((size_t)Bn * Hn * Sn * 2));
    __hip_bfloat16* embEb  = (__hip_bfloat16*)(ws + alloc((size_t)Mn * Sn * 2));   // bf16 now
    __hip_bfloat16* padrow = (__hip_bfloat16*)(ws + alloc(256));
    __hip_bfloat16* wpack  = (__hip_bfloat16*)(ws + alloc((size_t)2 * Hn * 3 * Hn * 2)); // per-layer, warm
    __hip_bfloat16* tmpE = conved;  // overlay: conved dead after last update GEMM
    __hip_bfloat16* convinD = convinP + 2 * Hn;   // data rows base (skip 2 pads of batch 0)

    float* out = (float*)d_out;
    float* attn_out = out + (long)Mn * Vn;
    const long bSq = (long)Sn * Sn;
    const long bSH = (long)Sn * Hn;
    const long bTH = (long)Tn * Hn;
    const long bTE = (long)Tn * En;
    const long bPH = (long)TP * Hn;   // padded per-batch stride

    dim3 tb(32, 8);
    const __hip_bfloat16* nb = nullptr;

    // ---- prep ----
    embed_kernel<<<Mn, 128, 0, stream>>>(tgt, tok_emb, pos_emb, b_ah2e, emb, embA, convinP, padrow);
    transpose_f32_bf16<<<dim3(Hn / 32, En / 32, 1), tb, 0, stream>>>(w_e2h, wT_e2h, En, Hn, 0, 0);
    transpose_f32_bf16<<<dim3(En / 32, Hn / 32, 1), tb, 0, stream>>>(w_h2e, wT_h2e, Hn, En, 0, 0);
    transpose_f32_bf16<<<dim3(Hn / 32, En / 32, 1), tb, 0, stream>>>(w_ae2h, wT_ae2h, En, Hn, 0, 0);
    transpose_f32_bf16<<<dim3((Vn + 31) / 32, En / 32, 1), tb, 0, stream>>>(w_fc, wT_fc, En, Vn, 0, 0);
    {
        long a0 = (long)Hn * En / 4, a1 = (long)Bn * Sn * En / 4, a2 = a1;
        convert3_kernel<<<(int)((a0 + a1 + a2 + 255) / 256), 256, 0, stream>>>(
            w_ah2e, wbAH, a0, enc_conved, encc, a1, enc_combined, encm, a2);
    }

    // encAH[b][s][h] = encc[b] @ w_ah2e^T   (layer-invariant attention factor)
    gemm_bf16<0, false, false><<<dim3(Hn / 128, Sn / 128, Bn), 256, 0, stream>>>(
        encc, wbAH, nullptr, encAH, nb, nb, padrow, Sn, Hn, En, bSq, 0, bSH, 0, 1.f, 1.f);
    // encCW[b][h][s] = (enc_combined[b] @ w_ae2h)^T
    gemm_bf16<0, false, false><<<dim3(Sn / 128, Hn / 128, Bn), 256, 0, stream>>>(
        wT_ae2h, encm, nullptr, encCW, nb, nb, padrow, Hn, Sn, En, 0, bSq, bSH, 0, 1.f, 1.f);
    // embE[b][t][s] = (emb + b_ah2e) @ encc[b]^T   (bf16; kScale applied in energy)  [64-tile]
    gemm64<0, false><<<dim3(Sn / 128, Tn / 64, Bn), 256, 0, stream>>>(
        embA, encc, nullptr, embEb, nb, Sn, En, bTE, bSq, bSq, 0, 1.f);
    // conv_input = embedded @ emb2hid + b   -> padded buffer (batched, rows +2)
    gemm_bf16<0, false, false><<<dim3(Hn / 128, Tn / 128, Bn), 256, 0, stream>>>(
        emb, wT_e2h, b_e2h, convinD, nb, nb, padrow, Tn, Hn, En, bTE, 0, bPH, 0, 1.f, 1.f);

    for (int l = 0; l < Ln; ++l) {
        // pack conv weight for THIS layer just before use (keeps B-panel L2/L3-warm)
        wpack2_kernel<<<2 * Hn, 256, 0, stream>>>(conv_w, wpack, l);
        // conved = GLU(conv(convinP) + conv_b[l])   [8192,1024], 512x128 tiles, 2-row halo
        conv_glu_kernel<<<dim3(2 * Hn / 128, Mn / 512), 512, 0, stream>>>(
            convinP, wpack, conv_b + (long)l * 2 * Hn, conved);
        // energy[b] = kScale * (conved[b] @ encAH[b]^T + embE[b])   (f32) [64-tile, EPI1]
        gemm64<1, true><<<dim3(Sn / 128, Tn / 64, Bn), 256, 0, stream>>>(
            conved, encAH, nullptr, energy, embEb, Sn, Hn, bTH, bSH, bSq, bSq, kScale);
        // attention = softmax(energy)  (f32 out only needed from the LAST layer)
        softmax_kernel<<<Mn, 256, 0, stream>>>(energy, (l == Ln - 1) ? attn_out : nullptr, attnbf);
        // conv_input = ((attn @ encCW + b_ae2h + conved)*s + conv_input)*s  (C/R2 padded)
        gemm_bf16<2, false, false><<<dim3(Hn / 128, Tn / 128, Bn), 256, 0, stream>>>(
            attnbf, encCW, b_ae2h, convinD, conved, convinD, padrow,
            Tn, Hn, Sn, bSq, bSH, bPH, bTH, kScale, kScale);
    }

    // conved = conv_input @ hid2emb + b   [8192,512]  (A padded, batched)  [64-tile]
    gemm64<0, false><<<dim3(En / 128, Tn / 64, Bn), 256, 0, stream>>>(
        convinD, wT_h2e, b_h2e, tmpE, nb, En, Hn, bPH, 0, bTE, 0, 1.f);
    // output = conved @ fc_out + b        [8192,10000] f32, N-bounded  (256² coarse)
    gemm256<true, true><<<dim3((Vn + 255) / 256, Mn / 256), 512, 0, stream>>>(
        tmpE, wT_fc, b_fc, out, padrow, Mn, Vn, En);
}